// Round 4
// baseline (916.031 us; speedup 1.0000x reference)
//
#include <hip/hip_runtime.h>
#include <hip/hip_bf16.h>

#define NN 50000
#define NE 400000
#define IND 64
#define HID 128
#define H3 384
#define FDIM 960
#define NSEL 4096
#define EPSF 0.3f
#define SLOPEF 0.3f
#define SCHUNK 2048
#define NCHUNK 25          // ceil(NN/SCHUNK)
#define KS2 10             // t2 split-K
#define KCH2 96            // 960/10
#define KS3 3              // hw2 split-K
#define KCH3 128           // 384/3
#define NBK 196            // ceil(NN/256) dst-buckets per relation

typedef __attribute__((ext_vector_type(8))) short bfrag;   // 8 bf16 (4 VGPR)
typedef __attribute__((ext_vector_type(4))) float f4;
typedef __attribute__((ext_vector_type(8))) unsigned short us8;

__device__ __forceinline__ float leaky1(float v){ return v>=0.f? v : SLOPEF*v; }

// ---------- degree ----------
__global__ void k_deg(const int* __restrict__ d0, const int* __restrict__ d1,
                      const int* __restrict__ d2, int* __restrict__ deg){
  int t = blockIdx.x*256 + threadIdx.x;
  if (t >= 3*NE) return;
  int r = t / NE, e = t - r*NE;
  const int* D = (r==0)?d0:((r==1)?d1:d2);
  atomicAdd(&deg[r*NN + D[e]], 1);
}

// ---------- 3-phase parallel scan (75 blocks), fused dnorm ----------
__global__ __launch_bounds__(256) void k_scan_a(const int* __restrict__ deg,
    int* __restrict__ off, int* __restrict__ bsum, float* __restrict__ dnv){
  int b = blockIdx.x;
  int r = b / NCHUNK, c = b - r*NCHUNK;
  const int* dg = deg + r*NN;
  int* o = off + r*(NN+1);
  int t = threadIdx.x;
  int base = c*SCHUNK + t*8;
  int v[8];
  #pragma unroll
  for (int j=0;j<8;j++){
    int i = base+j;
    int g = (i<NN)? dg[i] : 0;
    v[j] = g;
    if (i<NN) dnv[r*NN+i] = (g>0)? rsqrtf((float)g) : 0.f;
  }
  int s=0;
  #pragma unroll
  for (int j=0;j<8;j++){ s += v[j]; v[j] = s; }   // local inclusive
  int lane = t & 63, wid = t >> 6;
  int x = s;
  #pragma unroll
  for (int d=1; d<64; d<<=1){ int y=__shfl_up(x,(unsigned)d); if(lane>=d) x+=y; }
  __shared__ int ws[4];
  if (lane==63) ws[wid]=x;
  __syncthreads();
  int wpre = 0;
  if (wid>0) wpre += ws[0];
  if (wid>1) wpre += ws[1];
  if (wid>2) wpre += ws[2];
  int excl = wpre + x - s;
  #pragma unroll
  for (int j=0;j<8;j++){ int i=base+j; if (i<NN) o[i+1] = excl + v[j]; }
  if (t==255) bsum[b] = wpre + x;
}

__global__ void k_scan_b(int* __restrict__ bsum){
  int r = threadIdx.x;
  if (r < 3){
    int run = 0;
    for (int c=0;c<NCHUNK;c++){
      int t = bsum[r*NCHUNK+c];
      bsum[r*NCHUNK+c] = run;
      run += t;
    }
  }
}

__global__ __launch_bounds__(256) void k_scan_c(int* __restrict__ off,
                                                const int* __restrict__ bsum){
  int b = blockIdx.x;
  int r = b / NCHUNK, c = b - r*NCHUNK;
  int add = bsum[b];
  int* o = off + r*(NN+1);
  if (threadIdx.x==0 && c==0) o[0]=0;
  int base = c*SCHUNK;
  for (int j=threadIdx.x; j<SCHUNK; j+=256){
    int i = base+j;
    if (i<NN) o[i+1] += add;
  }
}

// ---------- bucketed two-phase CSR fill ----------
// Phase A: append (src,dst) into per-(rel,bucket) regions. Bucket = 256 dst
// nodes; region base = off[bucket_first_node] (exact sizes, no slack needed).
// Appends are address-dense -> ~1x line write amplification.
__global__ void k_bfill(const int* __restrict__ s0,const int* __restrict__ d0,
                        const int* __restrict__ s1,const int* __restrict__ d1,
                        const int* __restrict__ s2,const int* __restrict__ d2,
                        const int* __restrict__ off, int* __restrict__ bcur,
                        int2* __restrict__ pairbuf){
  int t = blockIdx.x*256 + threadIdx.x;
  if (t >= 3*NE) return;
  int r = t/NE, e = t - r*NE;
  const int* S = (r==0)?s0:((r==1)?s1:s2);
  const int* D = (r==0)?d0:((r==1)?d1:d2);
  int dv = D[e], sv = S[e];
  int b = dv >> 8;
  int base = off[r*(NN+1) + (b<<8)];
  int pos = base + atomicAdd(&bcur[r*NBK + b], 1);
  pairbuf[(size_t)r*NE + pos] = make_int2(sv, dv);
}

// Phase B: one block per (bucket, rel); LDS per-node counters; scatter confined
// to the bucket's ~8KB L2-resident window.
__global__ __launch_bounds__(256) void k_bsort(const int2* __restrict__ pairbuf,
                                               const int* __restrict__ off,
                                               int* __restrict__ csrc){
  __shared__ int cur2[256];
  int r = blockIdx.y, b = blockIdx.x;
  int nb0 = b << 8;
  int nb1 = min(nb0 + 256, NN);
  const int* offr = off + r*(NN+1);
  cur2[threadIdx.x] = 0;
  __syncthreads();
  int e0 = offr[nb0], e1 = offr[nb1];
  for (int e = e0 + (int)threadIdx.x; e < e1; e += 256){
    int2 p = pairbuf[(size_t)r*NE + e];
    int slot = atomicAdd(&cur2[p.y - nb0], 1);
    csrc[(size_t)r*NE + offr[p.y] + slot] = p.x;
  }
}

// ---------- vectorized tiled f32 GEMM with leaky epilogue (t1) ----------
template<int BM,int BN,int BK,int TM,int TN,bool WT,bool BIAS>
__global__ __launch_bounds__(256) void k_gemm(
    const float* __restrict__ A, int lda, int M, int K,
    const float* __restrict__ B, int ldb,
    const float* __restrict__ bias,
    float* __restrict__ C, int ldc)
{
  constexpr int TX = BN/TN;
  constexpr int TY = BM/TM;
  static_assert(TX*TY==256, "256 threads");
  static_assert(BK%4==0 && BN%4==0 && TN%4==0, "vec4");
  __shared__ float As[BK][BM+4];
  __shared__ float Bs[BK][BN+4];
  const int tid = threadIdx.x;
  const int tx = tid % TX, ty = tid / TX;
  const int bm = blockIdx.y*BM, bn = blockIdx.x*BN;
  float acc[TM][TN];
  #pragma unroll
  for (int i=0;i<TM;i++)
    #pragma unroll
    for (int j=0;j<TN;j++) acc[i][j]=0.f;

  for (int k0=0;k0<K;k0+=BK){
    #pragma unroll
    for (int q=tid; q<BM*BK/4; q+=256){
      int m = q/(BK/4), kq = q - m*(BK/4);
      int row = bm+m; row = (row<M)? row : (M-1);
      const float4 v = *(const float4*)&A[(size_t)row*lda + k0 + kq*4];
      As[kq*4+0][m]=v.x; As[kq*4+1][m]=v.y; As[kq*4+2][m]=v.z; As[kq*4+3][m]=v.w;
    }
    if (WT){
      #pragma unroll
      for (int q=tid; q<BN*BK/4; q+=256){
        int nj = q/(BK/4), kq = q - nj*(BK/4);
        const float4 v = *(const float4*)&B[(size_t)(bn+nj)*ldb + k0 + kq*4];
        Bs[kq*4+0][nj]=v.x; Bs[kq*4+1][nj]=v.y; Bs[kq*4+2][nj]=v.z; Bs[kq*4+3][nj]=v.w;
      }
    } else {
      #pragma unroll
      for (int q=tid; q<BN*BK/4; q+=256){
        int kk = q/(BN/4), nq = q - kk*(BN/4);
        const float4 v = *(const float4*)&B[(size_t)(k0+kk)*ldb + bn + nq*4];
        *(float4*)&Bs[kk][nq*4] = v;
      }
    }
    __syncthreads();
    #pragma unroll
    for (int kk=0;kk<BK;kk++){
      float a[TM], b[TN];
      #pragma unroll
      for (int i=0;i<TM;i++) a[i]=As[kk][ty*TM+i];
      #pragma unroll
      for (int j=0;j<TN;j++) b[j]=Bs[kk][tx*TN+j];
      #pragma unroll
      for (int i=0;i<TM;i++)
        #pragma unroll
        for (int j=0;j<TN;j++) acc[i][j] = fmaf(a[i], b[j], acc[i][j]);
    }
    __syncthreads();
  }
  #pragma unroll
  for (int i=0;i<TM;i++){
    int row = bm+ty*TM+i;
    if (row<M){
      #pragma unroll
      for (int j4=0;j4<TN/4;j4++){
        float o[4];
        #pragma unroll
        for (int u=0;u<4;u++){
          int j = j4*4+u;
          float v = acc[i][j];
          if (BIAS) v += bias[bn+tx*TN+j];
          o[u] = leaky1(v);
        }
        *(float4*)&C[(size_t)row*ldc + bn + tx*TN + j4*4] = make_float4(o[0],o[1],o[2],o[3]);
      }
    }
  }
}

// ---------- bf16 weight prep: hw1[r] (K=128 x N=128 row-major f32) -> wt[r][n][k] bf16 ----------
__global__ void k_wprep(const float* __restrict__ w0, const float* __restrict__ w1,
                        const float* __restrict__ w2, __hip_bfloat16* __restrict__ wt){
  int t = blockIdx.x*256 + threadIdx.x;
  if (t >= 3*HID*HID) return;
  int r = t / (HID*HID), e = t - r*(HID*HID);
  int n = e >> 7, k = e & 127;
  const float* W = (r==0)?w0:((r==1)?w1:w2);
  wt[t] = __float2bfloat16(W[k*HID + n]);
}

// ---------- batched bf16 MFMA GEMM: raw2[:, r*128 ..] = leaky(pre1b[r] @ hw1[r]) ----------
// A: [3][M][128] bf16, Wt: [3][128 n][128 k] bf16, C: [M][384] f32
__global__ __launch_bounds__(256) void k_mfma128(
    const __hip_bfloat16* __restrict__ Abf, const __hip_bfloat16* __restrict__ Wt,
    float* __restrict__ C, int M)
{
  __shared__ short As[64][136];    // 272B rows: 16B-aligned, 2-way max bank alias
  __shared__ short Bs[128][136];
  const int r = blockIdx.y;
  const unsigned short* Ar = (const unsigned short*)Abf + (size_t)r*M*HID;
  const unsigned short* W  = (const unsigned short*)Wt + (size_t)r*HID*HID;
  const int tid = threadIdx.x;
  const int bm = blockIdx.x*64;

  for (int q = tid; q < 64*16; q += 256){
    int row = q >> 4, c8 = q & 15;
    int grow = bm + row; grow = (grow < M) ? grow : (M-1);
    us8 v = *(const us8*)&Ar[(size_t)grow*HID + c8*8];
    *(us8*)&As[row][c8*8] = v;
  }
  for (int q = tid; q < 128*16; q += 256){
    int n = q >> 4, c8 = q & 15;
    us8 v = *(const us8*)&W[n*HID + c8*8];
    *(us8*)&Bs[n][c8*8] = v;
  }
  __syncthreads();

  const int wid = tid >> 6, lane = tid & 63;
  const int wrow = (wid & 1)*32, wcol = (wid >> 1)*64;
  const int fr = lane & 15, fq = lane >> 4;
  f4 acc[2][4];
  #pragma unroll
  for (int mi=0;mi<2;mi++)
    #pragma unroll
    for (int ni=0;ni<4;ni++) acc[mi][ni] = (f4){0.f,0.f,0.f,0.f};

  #pragma unroll
  for (int ks=0; ks<4; ks++){
    int kb = ks*32 + fq*8;
    bfrag a[2], b[4];
    #pragma unroll
    for (int mi=0;mi<2;mi++) a[mi] = *(const bfrag*)&As[wrow + mi*16 + fr][kb];
    #pragma unroll
    for (int ni=0;ni<4;ni++) b[ni] = *(const bfrag*)&Bs[wcol + ni*16 + fr][kb];
    #pragma unroll
    for (int mi=0;mi<2;mi++)
      #pragma unroll
      for (int ni=0;ni<4;ni++)
        acc[mi][ni] = __builtin_amdgcn_mfma_f32_16x16x32_bf16(a[mi], b[ni], acc[mi][ni], 0, 0, 0);
  }

  const int coff = r*HID;
  #pragma unroll
  for (int mi=0;mi<2;mi++){
    int row0 = bm + wrow + mi*16 + fq*4;
    #pragma unroll
    for (int j=0;j<4;j++){
      int row = row0 + j;
      if (row < M){
        #pragma unroll
        for (int ni=0;ni<4;ni++){
          C[(size_t)row*H3 + coff + wcol + ni*16 + fr] = leaky1(acc[mi][ni][j]);
        }
      }
    }
  }
}

// ---------- split-K (optionally z-batched) GEMM, raw partials ----------
template<int BM,int BN,int BK,int TM,int TN,bool WT,int NKS>
__global__ __launch_bounds__(256) void k_sk(
    const float* __restrict__ A0, int lda, int M, int kch, size_t strideA,
    const float* __restrict__ B0, const float* __restrict__ B1, const float* __restrict__ B2,
    int ldb, float* __restrict__ part)
{
  constexpr int TX = BN/TN;
  constexpr int TY = BM/TM;
  static_assert(TX*TY==256, "256 threads");
  __shared__ float As[BK][BM+4];
  __shared__ float Bs[BK][BN+4];
  const int z = blockIdx.z;
  const float* A = A0 + (size_t)z*strideA;
  const float* B = (z==0)?B0:((z==1)?B1:B2);
  const int ks = blockIdx.x;
  const int tid = threadIdx.x;
  const int tx = tid % TX, ty = tid / TX;
  const int bm = blockIdx.y*BM;
  float acc[TM][TN];
  #pragma unroll
  for (int i=0;i<TM;i++)
    #pragma unroll
    for (int j=0;j<TN;j++) acc[i][j]=0.f;

  const int kbeg = ks*kch;
  for (int k0=kbeg; k0<kbeg+kch; k0+=BK){
    #pragma unroll
    for (int q=tid; q<BM*BK/4; q+=256){
      int m = q/(BK/4), kq = q - m*(BK/4);
      const float4 v = *(const float4*)&A[(size_t)(bm+m)*lda + k0 + kq*4];
      As[kq*4+0][m]=v.x; As[kq*4+1][m]=v.y; As[kq*4+2][m]=v.z; As[kq*4+3][m]=v.w;
    }
    if (WT){
      #pragma unroll
      for (int q=tid; q<BN*BK/4; q+=256){
        int nj = q/(BK/4), kq = q - nj*(BK/4);
        const float4 v = *(const float4*)&B[(size_t)nj*ldb + k0 + kq*4];
        Bs[kq*4+0][nj]=v.x; Bs[kq*4+1][nj]=v.y; Bs[kq*4+2][nj]=v.z; Bs[kq*4+3][nj]=v.w;
      }
    } else {
      #pragma unroll
      for (int q=tid; q<BN*BK/4; q+=256){
        int kk = q/(BN/4), nq = q - kk*(BN/4);
        const float4 v = *(const float4*)&B[(size_t)(k0+kk)*ldb + nq*4];
        *(float4*)&Bs[kk][nq*4] = v;
      }
    }
    __syncthreads();
    #pragma unroll
    for (int kk=0;kk<BK;kk++){
      float a[TM], b[TN];
      #pragma unroll
      for (int i=0;i<TM;i++) a[i]=As[kk][ty*TM+i];
      #pragma unroll
      for (int j=0;j<TN;j++) b[j]=Bs[kk][tx*TN+j];
      #pragma unroll
      for (int i=0;i<TM;i++)
        #pragma unroll
        for (int j=0;j<TN;j++) acc[i][j] = fmaf(a[i], b[j], acc[i][j]);
    }
    __syncthreads();
  }
  #pragma unroll
  for (int i=0;i<TM;i++){
    int row = bm+ty*TM+i;
    #pragma unroll
    for (int j4=0;j4<TN/4;j4++){
      float4 v = make_float4(acc[i][j4*4+0],acc[i][j4*4+1],acc[i][j4*4+2],acc[i][j4*4+3]);
      *(float4*)&part[(((size_t)(z*NKS+ks))*M + row)*BN + tx*TN + j4*4] = v;
    }
  }
}

// reduce hw2 partials -> nf columns with leaky
__global__ __launch_bounds__(256) void k_hw2_red(const float* __restrict__ part,
                                                 float* __restrict__ nf){
  int t = blockIdx.x*256 + threadIdx.x;
  const int TOT = 3*NSEL*HID/4;
  if (t >= TOT) return;
  int rel = t / (NSEL*HID/4);
  int rem = t - rel*(NSEL*HID/4);
  int i = rem / (HID/4);
  int c4 = rem - i*(HID/4);
  float4 s = make_float4(0,0,0,0);
  #pragma unroll
  for (int ks=0; ks<KS3; ks++){
    const float4 v = *(const float4*)&part[(((size_t)(rel*KS3+ks))*NSEL + i)*HID + c4*4];
    s.x+=v.x; s.y+=v.y; s.z+=v.z; s.w+=v.w;
  }
  s.x=leaky1(s.x); s.y=leaky1(s.y); s.z=leaky1(s.z); s.w=leaky1(s.w);
  *(float4*)&nf[(size_t)i*FDIM + rel*HID + c4*4] = s;
}

// partial-reduce + bias + leaky + t3 projection, one wave per selected row
__global__ __launch_bounds__(256) void k_final_wave(
    const float* __restrict__ part, const float* __restrict__ t2b,
    const float* __restrict__ t3w, const float* __restrict__ t3b,
    float* __restrict__ outp)
{
  int w = (blockIdx.x*256 + threadIdx.x) >> 6;
  int j = threadIdx.x & 63;
  if (w >= NSEL) return;
  float v = 0.f;
  #pragma unroll
  for (int s=0;s<KS2;s++) v += part[((size_t)s*NSEL + w)*64 + j];
  v += t2b[j];
  v = leaky1(v);
  float a0 = v*t3w[j], a1 = v*t3w[64+j];
  #pragma unroll
  for (int sft=32;sft>0;sft>>=1){
    a0 += __shfl_down(a0,(unsigned)sft);
    a1 += __shfl_down(a1,(unsigned)sft);
  }
  if (j==0){
    outp[2*w+0] = a0 + t3b[0];
    outp[2*w+1] = a1 + t3b[1];
  }
}

// ---------- per-node gate scores ----------
template<int D>
__global__ __launch_bounds__(256) void k_scores(const float* __restrict__ X,
    const float* __restrict__ g0, const float* __restrict__ g1, const float* __restrict__ g2,
    float* __restrict__ sd, float* __restrict__ ss){
  int w = (blockIdx.x*256 + threadIdx.x) >> 6;
  int lane = threadIdx.x & 63;
  if (w >= NN) return;
  const float* x = X + (size_t)w*D;
  float a0=0,a1=0,a2=0,a3=0,a4=0,a5=0;
  for (int k=lane; k<D; k+=64){
    float v = x[k];
    a0 = fmaf(v, g0[k],   a0);  a1 = fmaf(v, g0[D+k], a1);
    a2 = fmaf(v, g1[k],   a2);  a3 = fmaf(v, g1[D+k], a3);
    a4 = fmaf(v, g2[k],   a4);  a5 = fmaf(v, g2[D+k], a5);
  }
  #pragma unroll
  for (int s=32;s>0;s>>=1){
    a0 += __shfl_down(a0,(unsigned)s); a1 += __shfl_down(a1,(unsigned)s);
    a2 += __shfl_down(a2,(unsigned)s); a3 += __shfl_down(a3,(unsigned)s);
    a4 += __shfl_down(a4,(unsigned)s); a5 += __shfl_down(a5,(unsigned)s);
  }
  if (lane==0){
    sd[0*NN+w]=a0; ss[0*NN+w]=a1;
    sd[1*NN+w]=a2; ss[1*NN+w]=a3;
    sd[2*NN+w]=a4; ss[2*NN+w]=a5;
  }
}

// ---------- layer-1 aggregation (3 relations batched), bf16 output ----------
template<int D,int CH>
__global__ __launch_bounds__(D) void k_gather_f3(const float* __restrict__ X,
    const int* __restrict__ off, const int* __restrict__ csrc,
    const float* __restrict__ sd, const float* __restrict__ ss,
    const float* __restrict__ dnv,
    const float* __restrict__ gb0, const float* __restrict__ gb1, const float* __restrict__ gb2,
    __hip_bfloat16* __restrict__ outp){
  __shared__ float sc[CH];
  __shared__ int ssrc[CH];
  int r = blockIdx.y;
  int n = blockIdx.x;
  int k = threadIdx.x;
  const int* offr = off + r*(NN+1);
  const int* csr  = csrc + (size_t)r*NE;
  const float* sdr = sd + r*NN;
  const float* ssr = ss + r*NN;
  const float* dnr = dnv + r*NN;
  float gbv = ((r==0)?gb0:((r==1)?gb1:gb2))[0];
  float sd_n = sdr[n], dn_n = dnr[n];
  float acc = EPSF * X[(size_t)n*D + k];
  int p0 = offr[n], p1 = offr[n+1];
  for (int pc=p0; pc<p1; pc+=CH){
    int m = min(CH, p1-pc);
    if (k < m){
      int s = csr[pc+k];
      ssrc[k] = s;
      sc[k] = tanhf(sd_n + ssr[s] + gbv) * dn_n * dnr[s];
    }
    __syncthreads();
    for (int j=0;j<m;j++){
      acc = fmaf(sc[j], X[(size_t)ssrc[j]*D + k], acc);
    }
    __syncthreads();
  }
  outp[((size_t)r*NN + n)*D + k] = __float2bfloat16(acc);
}

// layer-2: batched over 3 relations, only selected destinations (f32 out)
template<int D,int CH>
__global__ __launch_bounds__(D) void k_gather_sel3(const float* __restrict__ X,
    const int* __restrict__ nodes,
    const int* __restrict__ off, const int* __restrict__ csrc,
    const float* __restrict__ sd, const float* __restrict__ ss,
    const float* __restrict__ dnv,
    const float* __restrict__ gb0, const float* __restrict__ gb1, const float* __restrict__ gb2,
    float* __restrict__ outp){
  __shared__ float sc[CH];
  __shared__ int ssrc[CH];
  int r = blockIdx.y;
  int i = blockIdx.x;
  int n = nodes[i];
  int k = threadIdx.x;
  const int* offr = off + r*(NN+1);
  const int* csr  = csrc + (size_t)r*NE;
  const float* sdr = sd + r*NN;
  const float* ssr = ss + r*NN;
  const float* dnr = dnv + r*NN;
  float gbv = ((r==0)?gb0:((r==1)?gb1:gb2))[0];
  float sd_n = sdr[n], dn_n = dnr[n];
  float acc = EPSF * X[(size_t)n*D + k];
  int p0 = offr[n], p1 = offr[n+1];
  for (int pc=p0; pc<p1; pc+=CH){
    int m = min(CH, p1-pc);
    if (k < m){
      int s = csr[pc+k];
      ssrc[k] = s;
      sc[k] = tanhf(sd_n + ssr[s] + gbv) * dn_n * dnr[s];
    }
    __syncthreads();
    for (int j=0;j<m;j++){
      acc = fmaf(sc[j], X[(size_t)ssrc[j]*D + k], acc);
    }
    __syncthreads();
  }
  outp[((size_t)r*NSEL + i)*D + k] = acc;
}

// ---------- gather raw0/raw1/raw2 rows into nf ----------
__global__ __launch_bounds__(192) void k_nf_fill(const float* __restrict__ h,
    const float* __restrict__ raw1, const float* __restrict__ raw2,
    const int* __restrict__ nodes, float* __restrict__ nf){
  int i = blockIdx.x;
  int n = nodes[i];
  for (int c=threadIdx.x; c<576; c+=192){
    float v; int col;
    if (c < 64)       { v = h[(size_t)n*IND + c];            col = 384 + c; }
    else if (c < 192) { int q=c-64;  v = raw1[(size_t)n*HID + q]; col = 448 + q; }
    else              { int q=c-192; v = raw2[(size_t)n*H3  + q]; col = 576 + q; }
    nf[(size_t)i*FDIM + col] = v;
  }
}

extern "C" void kernel_launch(void* const* d_in, const int* in_sizes, int n_in,
                              void* d_out, int out_size, void* d_ws, size_t ws_size,
                              hipStream_t stream){
  if (n_in < 32) return;
  const float* h = (const float*)d_in[0];
  const int* src[3] = {(const int*)d_in[1], (const int*)d_in[3], (const int*)d_in[5]};
  const int* dst[3] = {(const int*)d_in[2], (const int*)d_in[4], (const int*)d_in[6]};
  const int* nodes = (const int*)d_in[7];
  const float* t1w = (const float*)d_in[8];
  const float* t1b = (const float*)d_in[9];

  bool dictOrder = (in_sizes[12] == 768);
  const float *g1w[3],*g1b[3],*g2w[3],*g2b[3],*hw1[3],*hw2[3];
  for (int r=0;r<3;r++){
    if (dictOrder){
      int base = 10 + r*6;
      g1w[r]=(const float*)d_in[base+0]; g1b[r]=(const float*)d_in[base+1];
      g2w[r]=(const float*)d_in[base+2]; g2b[r]=(const float*)d_in[base+3];
      hw1[r]=(const float*)d_in[base+4]; hw2[r]=(const float*)d_in[base+5];
    } else {
      g1w[r]=(const float*)d_in[10+2*r]; g1b[r]=(const float*)d_in[11+2*r];
      g2w[r]=(const float*)d_in[16+2*r]; g2b[r]=(const float*)d_in[17+2*r];
      hw1[r]=(const float*)d_in[22+r];   hw2[r]=(const float*)d_in[25+r];
    }
  }
  const float* t2w = (const float*)d_in[28];
  const float* t2b = (const float*)d_in[29];
  const float* t3w = (const float*)d_in[30];
  const float* t3b = (const float*)d_in[31];
  float* outp = (float*)d_out;

  // workspace carve (~165.6 MB)
  char* w = (char*)d_ws;
  auto carve = [&](size_t bytes)->void*{
    void* p = (void*)w;
    w += ((bytes + 255) & ~size_t(255));
    return p;
  };
  int*   deg  = (int*)  carve((size_t)(3*NN+1024)*4);  // deg[3N] + bcur[3*NBK], one memset
  int*   bcur = deg + 3*NN;
  int*   off  = (int*)  carve((size_t)3*(NN+1)*4);
  float* dnv  = (float*)carve((size_t)3*NN*4);
  int*   bsum = (int*)  carve((size_t)128*4);
  int*   csrc = (int*)  carve((size_t)3*NE*4);
  float* sd1  = (float*)carve((size_t)3*NN*4);
  float* ss1  = (float*)carve((size_t)3*NN*4);
  float* sd2  = (float*)carve((size_t)3*NN*4);
  float* ss2  = (float*)carve((size_t)3*NN*4);
  __hip_bfloat16* w1t = (__hip_bfloat16*)carve((size_t)3*HID*HID*2);
  float* raw1 = (float*)carve((size_t)NN*HID*4);
  float* raw2 = (float*)carve((size_t)NN*H3*4);
  // union region: pre1b bf16 [3][NN][HID] | pre2[3*NSEL*H3]+hw2part[9*NSEL*HID] | t2part
  size_t ubytes = (size_t)3*NN*HID*2;
  size_t u2 = ((size_t)3*NSEL*H3 + (size_t)3*KS3*NSEL*HID)*4;
  if (u2 > ubytes) ubytes = u2;
  float* ureg = (float*)carve(ubytes);
  __hip_bfloat16* pre1b = (__hip_bfloat16*)ureg;
  float* pre2  = ureg;
  float* hw2p  = ureg + (size_t)3*NSEL*H3;
  float* t2p   = ureg;
  float* nf   = (float*)carve((size_t)NSEL*FDIM*4);
  // pairbuf aliases raw2 (dead until k_mfma128)
  int2* pairbuf = (int2*)raw2;

  hipMemsetAsync(deg, 0, (size_t)(3*NN+1024)*4, stream);
  k_deg   <<<(3*NE+255)/256, 256, 0, stream>>>(dst[0], dst[1], dst[2], deg);
  k_scan_a<<<3*NCHUNK, 256, 0, stream>>>(deg, off, bsum, dnv);
  k_scan_b<<<1, 64, 0, stream>>>(bsum);
  k_scan_c<<<3*NCHUNK, 256, 0, stream>>>(off, bsum);
  k_bfill <<<(3*NE+255)/256, 256, 0, stream>>>(src[0],dst[0],src[1],dst[1],src[2],dst[2],
                                               off, bcur, pairbuf);
  k_bsort <<<dim3(NBK,3), 256, 0, stream>>>(pairbuf, off, csrc);

  // raw1 = leaky(h @ t1_w^T + t1_b)   (f32)
  k_gemm<64,128,32,4,8,true,true><<<dim3(1,(NN+63)/64), 256, 0, stream>>>(
      h, IND, NN, IND, t1w, IND, t1b, raw1, HID);

  k_scores<HID><<<(NN+3)/4, 256, 0, stream>>>(raw1, g1w[0], g1w[1], g1w[2], sd1, ss1);

  // layer-1 gathers (3 relations batched, bf16 out) + bf16 MFMA hw1 GEMMs
  k_wprep<<<(3*HID*HID+255)/256, 256, 0, stream>>>(hw1[0], hw1[1], hw1[2], w1t);
  k_gather_f3<HID,128><<<dim3(NN,3), HID, 0, stream>>>(raw1, off, csrc,
      sd1, ss1, dnv, g1b[0], g1b[1], g1b[2], pre1b);
  k_mfma128<<<dim3((NN+63)/64, 3), 256, 0, stream>>>(pre1b, w1t, raw2, NN);

  k_scores<H3><<<(NN+3)/4, 256, 0, stream>>>(raw2, g2w[0], g2w[1], g2w[2], sd2, ss2);

  // batched selected gather over 3 relations
  k_gather_sel3<H3,128><<<dim3(NSEL,3), H3, 0, stream>>>(raw2, nodes, off, csrc,
      sd2, ss2, dnv, g2b[0], g2b[1], g2b[2], pre2);

  // hw2: split-K x3, z-batched over relations -> partials -> reduce into nf
  k_sk<32,128,32,2,8,false,KS3><<<dim3(KS3, NSEL/32, 3), 256, 0, stream>>>(
      pre2, H3, NSEL, KCH3, (size_t)NSEL*H3, hw2[0], hw2[1], hw2[2], HID, hw2p);
  k_hw2_red<<<(3*NSEL*HID/4 + 255)/256, 256, 0, stream>>>(hw2p, nf);

  k_nf_fill<<<NSEL, 192, 0, stream>>>(h, raw1, raw2, nodes, nf);

  // t2 split-K x10 partials then fused reduce + leaky + t3
  k_sk<64,64,32,4,4,true,1><<<dim3(KS2, NSEL/64, 1), 256, 0, stream>>>(
      nf, FDIM, NSEL, KCH2, 0, t2w, t2w, t2w, FDIM, t2p);
  k_final_wave<<<(NSEL*64+255)/256, 256, 0, stream>>>(t2p, t2b, t3w, t3b, outp);
}

// Round 5
// 408.420 us; speedup vs baseline: 2.2429x; 2.2429x over previous
//
#include <hip/hip_runtime.h>
#include <hip/hip_bf16.h>

#define NN 50000
#define NE 400000
#define IND 64
#define HID 128
#define H3 384
#define FDIM 960
#define NSEL 4096
#define EPSF 0.3f
#define SLOPEF 0.3f
#define SCHUNK 2048
#define NCHUNK 25          // ceil(NN/SCHUNK)
#define KS2 10             // t2 split-K
#define KCH2 96            // 960/10
#define KS3 3              // hw2 split-K
#define KCH3 128           // 384/3
#define NBK 196            // ceil(NN/256) dst-buckets per relation
#define EPB 8192           // edges per block in k_bfill_lds

typedef __attribute__((ext_vector_type(8))) short bfrag;   // 8 bf16 (4 VGPR)
typedef __attribute__((ext_vector_type(4))) float f4;
typedef __attribute__((ext_vector_type(8))) unsigned short us8;

__device__ __forceinline__ float leaky1(float v){ return v>=0.f? v : SLOPEF*v; }
__device__ __forceinline__ float b2f(unsigned short u){
  return __uint_as_float(((unsigned)u)<<16);
}
__device__ __forceinline__ unsigned short f2b(float v){
  __hip_bfloat16 b = __float2bfloat16(v);
  return *(unsigned short*)&b;
}

// ---------- degree ----------
__global__ void k_deg(const int* __restrict__ d0, const int* __restrict__ d1,
                      const int* __restrict__ d2, int* __restrict__ deg){
  int t = blockIdx.x*256 + threadIdx.x;
  if (t >= 3*NE) return;
  int r = t / NE, e = t - r*NE;
  const int* D = (r==0)?d0:((r==1)?d1:d2);
  atomicAdd(&deg[r*NN + D[e]], 1);
}

// ---------- 3-phase parallel scan (75 blocks), fused dnorm ----------
__global__ __launch_bounds__(256) void k_scan_a(const int* __restrict__ deg,
    int* __restrict__ off, int* __restrict__ bsum, float* __restrict__ dnv){
  int b = blockIdx.x;
  int r = b / NCHUNK, c = b - r*NCHUNK;
  const int* dg = deg + r*NN;
  int* o = off + r*(NN+1);
  int t = threadIdx.x;
  int base = c*SCHUNK + t*8;
  int v[8];
  #pragma unroll
  for (int j=0;j<8;j++){
    int i = base+j;
    int g = (i<NN)? dg[i] : 0;
    v[j] = g;
    if (i<NN) dnv[r*NN+i] = (g>0)? rsqrtf((float)g) : 0.f;
  }
  int s=0;
  #pragma unroll
  for (int j=0;j<8;j++){ s += v[j]; v[j] = s; }   // local inclusive
  int lane = t & 63, wid = t >> 6;
  int x = s;
  #pragma unroll
  for (int d=1; d<64; d<<=1){ int y=__shfl_up(x,(unsigned)d); if(lane>=d) x+=y; }
  __shared__ int ws[4];
  if (lane==63) ws[wid]=x;
  __syncthreads();
  int wpre = 0;
  if (wid>0) wpre += ws[0];
  if (wid>1) wpre += ws[1];
  if (wid>2) wpre += ws[2];
  int excl = wpre + x - s;
  #pragma unroll
  for (int j=0;j<8;j++){ int i=base+j; if (i<NN) o[i+1] = excl + v[j]; }
  if (t==255) bsum[b] = wpre + x;
}

__global__ void k_scan_b(int* __restrict__ bsum){
  int r = threadIdx.x;
  if (r < 3){
    int run = 0;
    for (int c=0;c<NCHUNK;c++){
      int t = bsum[r*NCHUNK+c];
      bsum[r*NCHUNK+c] = run;
      run += t;
    }
  }
}

__global__ __launch_bounds__(256) void k_scan_c(int* __restrict__ off,
                                                const int* __restrict__ bsum){
  int b = blockIdx.x;
  int r = b / NCHUNK, c = b - r*NCHUNK;
  int add = bsum[b];
  int* o = off + r*(NN+1);
  if (threadIdx.x==0 && c==0) o[0]=0;
  int base = c*SCHUNK;
  for (int j=threadIdx.x; j<SCHUNK; j+=256){
    int i = base+j;
    if (i<NN) o[i+1] += add;
  }
}

// ---------- bucketed CSR fill, LDS-histogram (low atomic contention) ----------
// Phase A: per-block LDS histogram over 196 buckets; ONE global atomic per
// (block,bucket) to reserve a run; edges held in registers; scatter into
// per-run dense regions of pairbuf.
__global__ __launch_bounds__(256) void k_bfill_lds(
    const int* __restrict__ s0,const int* __restrict__ d0,
    const int* __restrict__ s1,const int* __restrict__ d1,
    const int* __restrict__ s2,const int* __restrict__ d2,
    const int* __restrict__ off, int* __restrict__ bcur,
    int2* __restrict__ pairbuf)
{
  __shared__ int hist[NBK];
  __shared__ int cur[NBK];
  __shared__ int gbase[NBK];
  const int r = blockIdx.y;
  const int* S = (r==0)?s0:((r==1)?s1:s2);
  const int* D = (r==0)?d0:((r==1)?d1:d2);
  const int e0 = blockIdx.x*EPB;
  const int t = threadIdx.x;
  for (int i=t; i<NBK; i+=256){ hist[i]=0; cur[i]=0; }
  __syncthreads();
  int sv[EPB/256], dv[EPB/256];
  #pragma unroll
  for (int j=0;j<EPB/256;j++){
    int e = e0 + j*256 + t;
    if (e < NE){
      sv[j] = S[e];
      int d = D[e];
      dv[j] = d;
      atomicAdd(&hist[d>>8], 1);
    }
  }
  __syncthreads();
  if (t < NBK){
    int h = hist[t];
    int base = off[r*(NN+1) + (t<<8)];
    gbase[t] = base + ((h>0) ? atomicAdd(&bcur[r*NBK+t], h) : 0);
  }
  __syncthreads();
  #pragma unroll
  for (int j=0;j<EPB/256;j++){
    int e = e0 + j*256 + t;
    if (e < NE){
      int b = dv[j] >> 8;
      int pos = gbase[b] + atomicAdd(&cur[b], 1);
      pairbuf[(size_t)r*NE + pos] = make_int2(sv[j], dv[j]);
    }
  }
}

// Phase B: one block per (bucket, rel); LDS per-node counters; scatter confined
// to the bucket's ~8KB L2-resident window.
__global__ __launch_bounds__(256) void k_bsort(const int2* __restrict__ pairbuf,
                                               const int* __restrict__ off,
                                               int* __restrict__ csrc){
  __shared__ int cur2[256];
  int r = blockIdx.y, b = blockIdx.x;
  int nb0 = b << 8;
  int nb1 = min(nb0 + 256, NN);
  const int* offr = off + r*(NN+1);
  cur2[threadIdx.x] = 0;
  __syncthreads();
  int e0 = offr[nb0], e1 = offr[nb1];
  for (int e = e0 + (int)threadIdx.x; e < e1; e += 256){
    int2 p = pairbuf[(size_t)r*NE + e];
    int slot = atomicAdd(&cur2[p.y - nb0], 1);
    csrc[(size_t)r*NE + offr[p.y] + slot] = p.x;
  }
}

// ---------- vectorized tiled f32 GEMM with leaky epilogue (t1) ----------
template<int BM,int BN,int BK,int TM,int TN,bool WT,bool BIAS,bool BOUT>
__global__ __launch_bounds__(256) void k_gemm(
    const float* __restrict__ A, int lda, int M, int K,
    const float* __restrict__ B, int ldb,
    const float* __restrict__ bias,
    float* __restrict__ C, int ldc, unsigned short* __restrict__ Cb)
{
  constexpr int TX = BN/TN;
  constexpr int TY = BM/TM;
  static_assert(TX*TY==256, "256 threads");
  static_assert(BK%4==0 && BN%4==0 && TN%4==0, "vec4");
  __shared__ float As[BK][BM+4];
  __shared__ float Bs[BK][BN+4];
  const int tid = threadIdx.x;
  const int tx = tid % TX, ty = tid / TX;
  const int bm = blockIdx.y*BM, bn = blockIdx.x*BN;
  float acc[TM][TN];
  #pragma unroll
  for (int i=0;i<TM;i++)
    #pragma unroll
    for (int j=0;j<TN;j++) acc[i][j]=0.f;

  for (int k0=0;k0<K;k0+=BK){
    #pragma unroll
    for (int q=tid; q<BM*BK/4; q+=256){
      int m = q/(BK/4), kq = q - m*(BK/4);
      int row = bm+m; row = (row<M)? row : (M-1);
      const float4 v = *(const float4*)&A[(size_t)row*lda + k0 + kq*4];
      As[kq*4+0][m]=v.x; As[kq*4+1][m]=v.y; As[kq*4+2][m]=v.z; As[kq*4+3][m]=v.w;
    }
    if (WT){
      #pragma unroll
      for (int q=tid; q<BN*BK/4; q+=256){
        int nj = q/(BK/4), kq = q - nj*(BK/4);
        const float4 v = *(const float4*)&B[(size_t)(bn+nj)*ldb + k0 + kq*4];
        Bs[kq*4+0][nj]=v.x; Bs[kq*4+1][nj]=v.y; Bs[kq*4+2][nj]=v.z; Bs[kq*4+3][nj]=v.w;
      }
    } else {
      #pragma unroll
      for (int q=tid; q<BN*BK/4; q+=256){
        int kk = q/(BN/4), nq = q - kk*(BN/4);
        const float4 v = *(const float4*)&B[(size_t)(k0+kk)*ldb + bn + nq*4];
        *(float4*)&Bs[kk][nq*4] = v;
      }
    }
    __syncthreads();
    #pragma unroll
    for (int kk=0;kk<BK;kk++){
      float a[TM], b[TN];
      #pragma unroll
      for (int i=0;i<TM;i++) a[i]=As[kk][ty*TM+i];
      #pragma unroll
      for (int j=0;j<TN;j++) b[j]=Bs[kk][tx*TN+j];
      #pragma unroll
      for (int i=0;i<TM;i++)
        #pragma unroll
        for (int j=0;j<TN;j++) acc[i][j] = fmaf(a[i], b[j], acc[i][j]);
    }
    __syncthreads();
  }
  #pragma unroll
  for (int i=0;i<TM;i++){
    int row = bm+ty*TM+i;
    if (row<M){
      #pragma unroll
      for (int j4=0;j4<TN/4;j4++){
        float o[4];
        #pragma unroll
        for (int u=0;u<4;u++){
          int j = j4*4+u;
          float v = acc[i][j];
          if (BIAS) v += bias[bn+tx*TN+j];
          o[u] = leaky1(v);
        }
        *(float4*)&C[(size_t)row*ldc + bn + tx*TN + j4*4] = make_float4(o[0],o[1],o[2],o[3]);
        if (BOUT){
          #pragma unroll
          for (int u=0;u<4;u++)
            Cb[(size_t)row*ldc + bn + tx*TN + j4*4 + u] = f2b(o[u]);
        }
      }
    }
  }
}

// ---------- bf16 weight prep: hw1[r] (K=128 x N=128 row-major f32) -> wt[r][n][k] bf16 ----------
__global__ void k_wprep(const float* __restrict__ w0, const float* __restrict__ w1,
                        const float* __restrict__ w2, __hip_bfloat16* __restrict__ wt){
  int t = blockIdx.x*256 + threadIdx.x;
  if (t >= 3*HID*HID) return;
  int r = t / (HID*HID), e = t - r*(HID*HID);
  int n = e >> 7, k = e & 127;
  const float* W = (r==0)?w0:((r==1)?w1:w2);
  wt[t] = __float2bfloat16(W[k*HID + n]);
}

// ---------- batched bf16 MFMA GEMM: raw2b[:, r*128 ..] = leaky(pre1b[r] @ hw1[r]) ----------
__global__ __launch_bounds__(256) void k_mfma128(
    const __hip_bfloat16* __restrict__ Abf, const __hip_bfloat16* __restrict__ Wt,
    unsigned short* __restrict__ Cb, int M)
{
  __shared__ short As[64][136];
  __shared__ short Bs[128][136];
  const int r = blockIdx.y;
  const unsigned short* Ar = (const unsigned short*)Abf + (size_t)r*M*HID;
  const unsigned short* W  = (const unsigned short*)Wt + (size_t)r*HID*HID;
  const int tid = threadIdx.x;
  const int bm = blockIdx.x*64;

  for (int q = tid; q < 64*16; q += 256){
    int row = q >> 4, c8 = q & 15;
    int grow = bm + row; grow = (grow < M) ? grow : (M-1);
    us8 v = *(const us8*)&Ar[(size_t)grow*HID + c8*8];
    *(us8*)&As[row][c8*8] = v;
  }
  for (int q = tid; q < 128*16; q += 256){
    int n = q >> 4, c8 = q & 15;
    us8 v = *(const us8*)&W[n*HID + c8*8];
    *(us8*)&Bs[n][c8*8] = v;
  }
  __syncthreads();

  const int wid = tid >> 6, lane = tid & 63;
  const int wrow = (wid & 1)*32, wcol = (wid >> 1)*64;
  const int fr = lane & 15, fq = lane >> 4;
  f4 acc[2][4];
  #pragma unroll
  for (int mi=0;mi<2;mi++)
    #pragma unroll
    for (int ni=0;ni<4;ni++) acc[mi][ni] = (f4){0.f,0.f,0.f,0.f};

  #pragma unroll
  for (int ks=0; ks<4; ks++){
    int kb = ks*32 + fq*8;
    bfrag a[2], b[4];
    #pragma unroll
    for (int mi=0;mi<2;mi++) a[mi] = *(const bfrag*)&As[wrow + mi*16 + fr][kb];
    #pragma unroll
    for (int ni=0;ni<4;ni++) b[ni] = *(const bfrag*)&Bs[wcol + ni*16 + fr][kb];
    #pragma unroll
    for (int mi=0;mi<2;mi++)
      #pragma unroll
      for (int ni=0;ni<4;ni++)
        acc[mi][ni] = __builtin_amdgcn_mfma_f32_16x16x32_bf16(a[mi], b[ni], acc[mi][ni], 0, 0, 0);
  }

  const int coff = r*HID;
  #pragma unroll
  for (int mi=0;mi<2;mi++){
    int row0 = bm + wrow + mi*16 + fq*4;
    #pragma unroll
    for (int j=0;j<4;j++){
      int row = row0 + j;
      if (row < M){
        #pragma unroll
        for (int ni=0;ni<4;ni++){
          Cb[(size_t)row*H3 + coff + wcol + ni*16 + fr] = f2b(leaky1(acc[mi][ni][j]));
        }
      }
    }
  }
}

// ---------- split-K (optionally z-batched) GEMM, raw partials ----------
template<int BM,int BN,int BK,int TM,int TN,bool WT,int NKS>
__global__ __launch_bounds__(256) void k_sk(
    const float* __restrict__ A0, int lda, int M, int kch, size_t strideA,
    const float* __restrict__ B0, const float* __restrict__ B1, const float* __restrict__ B2,
    int ldb, float* __restrict__ part)
{
  constexpr int TX = BN/TN;
  constexpr int TY = BM/TM;
  static_assert(TX*TY==256, "256 threads");
  __shared__ float As[BK][BM+4];
  __shared__ float Bs[BK][BN+4];
  const int z = blockIdx.z;
  const float* A = A0 + (size_t)z*strideA;
  const float* B = (z==0)?B0:((z==1)?B1:B2);
  const int ks = blockIdx.x;
  const int tid = threadIdx.x;
  const int tx = tid % TX, ty = tid / TX;
  const int bm = blockIdx.y*BM;
  float acc[TM][TN];
  #pragma unroll
  for (int i=0;i<TM;i++)
    #pragma unroll
    for (int j=0;j<TN;j++) acc[i][j]=0.f;

  const int kbeg = ks*kch;
  for (int k0=kbeg; k0<kbeg+kch; k0+=BK){
    #pragma unroll
    for (int q=tid; q<BM*BK/4; q+=256){
      int m = q/(BK/4), kq = q - m*(BK/4);
      const float4 v = *(const float4*)&A[(size_t)(bm+m)*lda + k0 + kq*4];
      As[kq*4+0][m]=v.x; As[kq*4+1][m]=v.y; As[kq*4+2][m]=v.z; As[kq*4+3][m]=v.w;
    }
    if (WT){
      #pragma unroll
      for (int q=tid; q<BN*BK/4; q+=256){
        int nj = q/(BK/4), kq = q - nj*(BK/4);
        const float4 v = *(const float4*)&B[(size_t)nj*ldb + k0 + kq*4];
        Bs[kq*4+0][nj]=v.x; Bs[kq*4+1][nj]=v.y; Bs[kq*4+2][nj]=v.z; Bs[kq*4+3][nj]=v.w;
      }
    } else {
      #pragma unroll
      for (int q=tid; q<BN*BK/4; q+=256){
        int kk = q/(BN/4), nq = q - kk*(BN/4);
        const float4 v = *(const float4*)&B[(size_t)(k0+kk)*ldb + nq*4];
        *(float4*)&Bs[kk][nq*4] = v;
      }
    }
    __syncthreads();
    #pragma unroll
    for (int kk=0;kk<BK;kk++){
      float a[TM], b[TN];
      #pragma unroll
      for (int i=0;i<TM;i++) a[i]=As[kk][ty*TM+i];
      #pragma unroll
      for (int j=0;j<TN;j++) b[j]=Bs[kk][tx*TN+j];
      #pragma unroll
      for (int i=0;i<TM;i++)
        #pragma unroll
        for (int j=0;j<TN;j++) acc[i][j] = fmaf(a[i], b[j], acc[i][j]);
    }
    __syncthreads();
  }
  #pragma unroll
  for (int i=0;i<TM;i++){
    int row = bm+ty*TM+i;
    #pragma unroll
    for (int j4=0;j4<TN/4;j4++){
      float4 v = make_float4(acc[i][j4*4+0],acc[i][j4*4+1],acc[i][j4*4+2],acc[i][j4*4+3]);
      *(float4*)&part[(((size_t)(z*NKS+ks))*M + row)*BN + tx*TN + j4*4] = v;
    }
  }
}

// reduce hw2 partials -> nf columns with leaky
__global__ __launch_bounds__(256) void k_hw2_red(const float* __restrict__ part,
                                                 float* __restrict__ nf){
  int t = blockIdx.x*256 + threadIdx.x;
  const int TOT = 3*NSEL*HID/4;
  if (t >= TOT) return;
  int rel = t / (NSEL*HID/4);
  int rem = t - rel*(NSEL*HID/4);
  int i = rem / (HID/4);
  int c4 = rem - i*(HID/4);
  float4 s = make_float4(0,0,0,0);
  #pragma unroll
  for (int ks=0; ks<KS3; ks++){
    const float4 v = *(const float4*)&part[(((size_t)(rel*KS3+ks))*NSEL + i)*HID + c4*4];
    s.x+=v.x; s.y+=v.y; s.z+=v.z; s.w+=v.w;
  }
  s.x=leaky1(s.x); s.y=leaky1(s.y); s.z=leaky1(s.z); s.w=leaky1(s.w);
  *(float4*)&nf[(size_t)i*FDIM + rel*HID + c4*4] = s;
}

// partial-reduce + bias + leaky + t3 projection, one wave per selected row
__global__ __launch_bounds__(256) void k_final_wave(
    const float* __restrict__ part, const float* __restrict__ t2b,
    const float* __restrict__ t3w, const float* __restrict__ t3b,
    float* __restrict__ outp)
{
  int w = (blockIdx.x*256 + threadIdx.x) >> 6;
  int j = threadIdx.x & 63;
  if (w >= NSEL) return;
  float v = 0.f;
  #pragma unroll
  for (int s=0;s<KS2;s++) v += part[((size_t)s*NSEL + w)*64 + j];
  v += t2b[j];
  v = leaky1(v);
  float a0 = v*t3w[j], a1 = v*t3w[64+j];
  #pragma unroll
  for (int sft=32;sft>0;sft>>=1){
    a0 += __shfl_down(a0,(unsigned)sft);
    a1 += __shfl_down(a1,(unsigned)sft);
  }
  if (j==0){
    outp[2*w+0] = a0 + t3b[0];
    outp[2*w+1] = a1 + t3b[1];
  }
}

// ---------- per-node gate scores (f32 input) ----------
template<int D>
__global__ __launch_bounds__(256) void k_scores(const float* __restrict__ X,
    const float* __restrict__ g0, const float* __restrict__ g1, const float* __restrict__ g2,
    float* __restrict__ sd, float* __restrict__ ss){
  int w = (blockIdx.x*256 + threadIdx.x) >> 6;
  int lane = threadIdx.x & 63;
  if (w >= NN) return;
  const float* x = X + (size_t)w*D;
  float a0=0,a1=0,a2=0,a3=0,a4=0,a5=0;
  for (int k=lane; k<D; k+=64){
    float v = x[k];
    a0 = fmaf(v, g0[k],   a0);  a1 = fmaf(v, g0[D+k], a1);
    a2 = fmaf(v, g1[k],   a2);  a3 = fmaf(v, g1[D+k], a3);
    a4 = fmaf(v, g2[k],   a4);  a5 = fmaf(v, g2[D+k], a5);
  }
  #pragma unroll
  for (int s=32;s>0;s>>=1){
    a0 += __shfl_down(a0,(unsigned)s); a1 += __shfl_down(a1,(unsigned)s);
    a2 += __shfl_down(a2,(unsigned)s); a3 += __shfl_down(a3,(unsigned)s);
    a4 += __shfl_down(a4,(unsigned)s); a5 += __shfl_down(a5,(unsigned)s);
  }
  if (lane==0){
    sd[0*NN+w]=a0; ss[0*NN+w]=a1;
    sd[1*NN+w]=a2; ss[1*NN+w]=a3;
    sd[2*NN+w]=a4; ss[2*NN+w]=a5;
  }
}

// ---------- per-node gate scores (bf16 input) ----------
template<int D>
__global__ __launch_bounds__(256) void k_scores_bf(const unsigned short* __restrict__ X,
    const float* __restrict__ g0, const float* __restrict__ g1, const float* __restrict__ g2,
    float* __restrict__ sd, float* __restrict__ ss){
  int w = (blockIdx.x*256 + threadIdx.x) >> 6;
  int lane = threadIdx.x & 63;
  if (w >= NN) return;
  const unsigned short* x = X + (size_t)w*D;
  float a0=0,a1=0,a2=0,a3=0,a4=0,a5=0;
  for (int k=lane; k<D; k+=64){
    float v = b2f(x[k]);
    a0 = fmaf(v, g0[k],   a0);  a1 = fmaf(v, g0[D+k], a1);
    a2 = fmaf(v, g1[k],   a2);  a3 = fmaf(v, g1[D+k], a3);
    a4 = fmaf(v, g2[k],   a4);  a5 = fmaf(v, g2[D+k], a5);
  }
  #pragma unroll
  for (int s=32;s>0;s>>=1){
    a0 += __shfl_down(a0,(unsigned)s); a1 += __shfl_down(a1,(unsigned)s);
    a2 += __shfl_down(a2,(unsigned)s); a3 += __shfl_down(a3,(unsigned)s);
    a4 += __shfl_down(a4,(unsigned)s); a5 += __shfl_down(a5,(unsigned)s);
  }
  if (lane==0){
    sd[0*NN+w]=a0; ss[0*NN+w]=a1;
    sd[1*NN+w]=a2; ss[1*NN+w]=a3;
    sd[2*NN+w]=a4; ss[2*NN+w]=a5;
  }
}

// ---------- layer-1 aggregation (3 relations batched), bf16 messages, bf16 out ----------
template<int D,int CH>
__global__ __launch_bounds__(D) void k_gather_f3(const float* __restrict__ Xf,
    const unsigned short* __restrict__ Xb,
    const int* __restrict__ off, const int* __restrict__ csrc,
    const float* __restrict__ sd, const float* __restrict__ ss,
    const float* __restrict__ dnv,
    const float* __restrict__ gb0, const float* __restrict__ gb1, const float* __restrict__ gb2,
    __hip_bfloat16* __restrict__ outp){
  __shared__ float sc[CH];
  __shared__ int ssrc[CH];
  int r = blockIdx.y;
  int n = blockIdx.x;
  int k = threadIdx.x;
  const int* offr = off + r*(NN+1);
  const int* csr  = csrc + (size_t)r*NE;
  const float* sdr = sd + r*NN;
  const float* ssr = ss + r*NN;
  const float* dnr = dnv + r*NN;
  float gbv = ((r==0)?gb0:((r==1)?gb1:gb2))[0];
  float sd_n = sdr[n], dn_n = dnr[n];
  float acc = EPSF * Xf[(size_t)n*D + k];     // exact residual
  int p0 = offr[n], p1 = offr[n+1];
  for (int pc=p0; pc<p1; pc+=CH){
    int m = min(CH, p1-pc);
    if (k < m){
      int s = csr[pc+k];
      ssrc[k] = s;
      sc[k] = tanhf(sd_n + ssr[s] + gbv) * dn_n * dnr[s];
    }
    __syncthreads();
    for (int j=0;j<m;j++){
      acc = fmaf(sc[j], b2f(Xb[(size_t)ssrc[j]*D + k]), acc);
    }
    __syncthreads();
  }
  outp[((size_t)r*NN + n)*D + k] = __float2bfloat16(acc);
}

// layer-2: batched over 3 relations, only selected destinations; bf16 input, f32 out
template<int D,int CH>
__global__ __launch_bounds__(D) void k_gather_sel3(const unsigned short* __restrict__ Xb,
    const int* __restrict__ nodes,
    const int* __restrict__ off, const int* __restrict__ csrc,
    const float* __restrict__ sd, const float* __restrict__ ss,
    const float* __restrict__ dnv,
    const float* __restrict__ gb0, const float* __restrict__ gb1, const float* __restrict__ gb2,
    float* __restrict__ outp){
  __shared__ float sc[CH];
  __shared__ int ssrc[CH];
  int r = blockIdx.y;
  int i = blockIdx.x;
  int n = nodes[i];
  int k = threadIdx.x;
  const int* offr = off + r*(NN+1);
  const int* csr  = csrc + (size_t)r*NE;
  const float* sdr = sd + r*NN;
  const float* ssr = ss + r*NN;
  const float* dnr = dnv + r*NN;
  float gbv = ((r==0)?gb0:((r==1)?gb1:gb2))[0];
  float sd_n = sdr[n], dn_n = dnr[n];
  float acc = EPSF * b2f(Xb[(size_t)n*D + k]);
  int p0 = offr[n], p1 = offr[n+1];
  for (int pc=p0; pc<p1; pc+=CH){
    int m = min(CH, p1-pc);
    if (k < m){
      int s = csr[pc+k];
      ssrc[k] = s;
      sc[k] = tanhf(sd_n + ssr[s] + gbv) * dn_n * dnr[s];
    }
    __syncthreads();
    for (int j=0;j<m;j++){
      acc = fmaf(sc[j], b2f(Xb[(size_t)ssrc[j]*D + k]), acc);
    }
    __syncthreads();
  }
  outp[((size_t)r*NSEL + i)*D + k] = acc;
}

// ---------- gather raw0/raw1/raw2 rows into nf ----------
__global__ __launch_bounds__(192) void k_nf_fill(const float* __restrict__ h,
    const float* __restrict__ raw1, const unsigned short* __restrict__ raw2b,
    const int* __restrict__ nodes, float* __restrict__ nf){
  int i = blockIdx.x;
  int n = nodes[i];
  for (int c=threadIdx.x; c<576; c+=192){
    float v; int col;
    if (c < 64)       { v = h[(size_t)n*IND + c];            col = 384 + c; }
    else if (c < 192) { int q=c-64;  v = raw1[(size_t)n*HID + q]; col = 448 + q; }
    else              { int q=c-192; v = b2f(raw2b[(size_t)n*H3 + q]); col = 576 + q; }
    nf[(size_t)i*FDIM + col] = v;
  }
}

extern "C" void kernel_launch(void* const* d_in, const int* in_sizes, int n_in,
                              void* d_out, int out_size, void* d_ws, size_t ws_size,
                              hipStream_t stream){
  if (n_in < 32) return;
  const float* h = (const float*)d_in[0];
  const int* src[3] = {(const int*)d_in[1], (const int*)d_in[3], (const int*)d_in[5]};
  const int* dst[3] = {(const int*)d_in[2], (const int*)d_in[4], (const int*)d_in[6]};
  const int* nodes = (const int*)d_in[7];
  const float* t1w = (const float*)d_in[8];
  const float* t1b = (const float*)d_in[9];

  bool dictOrder = (in_sizes[12] == 768);
  const float *g1w[3],*g1b[3],*g2w[3],*g2b[3],*hw1[3],*hw2[3];
  for (int r=0;r<3;r++){
    if (dictOrder){
      int base = 10 + r*6;
      g1w[r]=(const float*)d_in[base+0]; g1b[r]=(const float*)d_in[base+1];
      g2w[r]=(const float*)d_in[base+2]; g2b[r]=(const float*)d_in[base+3];
      hw1[r]=(const float*)d_in[base+4]; hw2[r]=(const float*)d_in[base+5];
    } else {
      g1w[r]=(const float*)d_in[10+2*r]; g1b[r]=(const float*)d_in[11+2*r];
      g2w[r]=(const float*)d_in[16+2*r]; g2b[r]=(const float*)d_in[17+2*r];
      hw1[r]=(const float*)d_in[22+r];   hw2[r]=(const float*)d_in[25+r];
    }
  }
  const float* t2w = (const float*)d_in[28];
  const float* t2b = (const float*)d_in[29];
  const float* t3w = (const float*)d_in[30];
  const float* t3b = (const float*)d_in[31];
  float* outp = (float*)d_out;

  // workspace carve (~140 MB)
  char* w = (char*)d_ws;
  auto carve = [&](size_t bytes)->void*{
    void* p = (void*)w;
    w += ((bytes + 255) & ~size_t(255));
    return p;
  };
  int*   deg  = (int*)  carve((size_t)(3*NN+1024)*4);  // deg[3N] + bcur[3*NBK], one memset
  int*   bcur = deg + 3*NN;
  int*   off  = (int*)  carve((size_t)3*(NN+1)*4);
  float* dnv  = (float*)carve((size_t)3*NN*4);
  int*   bsum = (int*)  carve((size_t)128*4);
  int*   csrc = (int*)  carve((size_t)3*NE*4);
  float* sd1  = (float*)carve((size_t)3*NN*4);
  float* ss1  = (float*)carve((size_t)3*NN*4);
  float* sd2  = (float*)carve((size_t)3*NN*4);
  float* ss2  = (float*)carve((size_t)3*NN*4);
  __hip_bfloat16* w1t = (__hip_bfloat16*)carve((size_t)3*HID*HID*2);
  float* raw1 = (float*)carve((size_t)NN*HID*4);
  unsigned short* raw1b = (unsigned short*)carve((size_t)NN*HID*2);
  unsigned short* raw2b = (unsigned short*)carve((size_t)NN*H3*2);
  // union region: pairbuf[3*NE int2] | pre1b bf16 [3][NN][HID] |
  //               pre2[3*NSEL*H3]+hw2part[9*NSEL*HID] | t2part[KS2*NSEL*64]
  size_t ubytes = (size_t)3*NN*HID*2;                                // 38.4 MB
  size_t u2 = ((size_t)3*NSEL*H3 + (size_t)3*KS3*NSEL*HID)*4;        // 37.7 MB
  size_t u3 = (size_t)3*NE*8;                                        //  9.6 MB
  if (u2 > ubytes) ubytes = u2;
  if (u3 > ubytes) ubytes = u3;
  float* ureg = (float*)carve(ubytes);
  int2* pairbuf = (int2*)ureg;
  __hip_bfloat16* pre1b = (__hip_bfloat16*)ureg;
  float* pre2  = ureg;
  float* hw2p  = ureg + (size_t)3*NSEL*H3;
  float* t2p   = ureg;
  float* nf   = (float*)carve((size_t)NSEL*FDIM*4);

  hipMemsetAsync(deg, 0, (size_t)(3*NN+1024)*4, stream);
  k_deg   <<<(3*NE+255)/256, 256, 0, stream>>>(dst[0], dst[1], dst[2], deg);
  k_scan_a<<<3*NCHUNK, 256, 0, stream>>>(deg, off, bsum, dnv);
  k_scan_b<<<1, 64, 0, stream>>>(bsum);
  k_scan_c<<<3*NCHUNK, 256, 0, stream>>>(off, bsum);
  k_bfill_lds<<<dim3((NE+EPB-1)/EPB, 3), 256, 0, stream>>>(
      src[0],dst[0],src[1],dst[1],src[2],dst[2], off, bcur, pairbuf);
  k_bsort <<<dim3(NBK,3), 256, 0, stream>>>(pairbuf, off, csrc);

  // raw1 = leaky(h @ t1_w^T + t1_b)   (f32 + bf16 mirror)
  k_gemm<64,128,32,4,8,true,true,true><<<dim3(1,(NN+63)/64), 256, 0, stream>>>(
      h, IND, NN, IND, t1w, IND, t1b, raw1, HID, raw1b);

  k_scores<HID><<<(NN+3)/4, 256, 0, stream>>>(raw1, g1w[0], g1w[1], g1w[2], sd1, ss1);

  // layer-1 gathers (3 relations batched, bf16 msgs/out) + bf16 MFMA hw1 GEMMs
  k_wprep<<<(3*HID*HID+255)/256, 256, 0, stream>>>(hw1[0], hw1[1], hw1[2], w1t);
  k_gather_f3<HID,128><<<dim3(NN,3), HID, 0, stream>>>(raw1, raw1b, off, csrc,
      sd1, ss1, dnv, g1b[0], g1b[1], g1b[2], pre1b);
  k_mfma128<<<dim3((NN+63)/64, 3), 256, 0, stream>>>(pre1b, w1t, raw2b, NN);

  k_scores_bf<H3><<<(NN+3)/4, 256, 0, stream>>>(raw2b, g2w[0], g2w[1], g2w[2], sd2, ss2);

  // batched selected gather over 3 relations
  k_gather_sel3<H3,128><<<dim3(NSEL,3), H3, 0, stream>>>(raw2b, nodes, off, csrc,
      sd2, ss2, dnv, g2b[0], g2b[1], g2b[2], pre2);

  // hw2: split-K x3, z-batched over relations -> partials -> reduce into nf
  k_sk<32,128,32,2,8,false,KS3><<<dim3(KS3, NSEL/32, 3), 256, 0, stream>>>(
      pre2, H3, NSEL, KCH3, (size_t)NSEL*H3, hw2[0], hw2[1], hw2[2], HID, hw2p);
  k_hw2_red<<<(3*NSEL*HID/4 + 255)/256, 256, 0, stream>>>(hw2p, nf);

  k_nf_fill<<<NSEL, 192, 0, stream>>>(h, raw1, raw2b, nodes, nf);

  // t2 split-K x10 partials then fused reduce + leaky + t3
  k_sk<64,64,32,4,4,true,1><<<dim3(KS2, NSEL/64, 1), 256, 0, stream>>>(
      nf, FDIM, NSEL, KCH2, 0, t2w, t2w, t2w, FDIM, t2p);
  k_final_wave<<<(NSEL*64+255)/256, 256, 0, stream>>>(t2p, t2b, t3w, t3b, outp);
}

// Round 6
// 341.447 us; speedup vs baseline: 2.6828x; 1.1961x over previous
//
#include <hip/hip_runtime.h>
#include <hip/hip_bf16.h>

#define NN 50000
#define NE 400000
#define IND 64
#define HID 128
#define H3 384
#define FDIM 960
#define NSEL 4096
#define EPSF 0.3f
#define SLOPEF 0.3f
#define SCHUNK 2048
#define NCHUNK 25          // ceil(NN/SCHUNK)
#define KS2 10             // t2 split-K
#define KCH2 96            // 960/10
#define KS3 3              // hw2 split-K
#define KCH3 128           // 384/3
#define NBK 196            // ceil(NN/256) dst-buckets per relation
#define EPB 8192           // edges per block in k_bfill_lds

typedef __attribute__((ext_vector_type(8))) short bfrag;   // 8 bf16 (4 VGPR)
typedef __attribute__((ext_vector_type(4))) float f4;
typedef __attribute__((ext_vector_type(8))) unsigned short us8;

__device__ __forceinline__ float leaky1(float v){ return v>=0.f? v : SLOPEF*v; }
__device__ __forceinline__ float b2f(unsigned short u){
  return __uint_as_float(((unsigned)u)<<16);
}
__device__ __forceinline__ unsigned short f2b(float v){
  __hip_bfloat16 b = __float2bfloat16(v);
  return *(unsigned short*)&b;
}

// ---------- degree ----------
__global__ void k_deg(const int* __restrict__ d0, const int* __restrict__ d1,
                      const int* __restrict__ d2, int* __restrict__ deg){
  int t = blockIdx.x*256 + threadIdx.x;
  if (t >= 3*NE) return;
  int r = t / NE, e = t - r*NE;
  const int* D = (r==0)?d0:((r==1)?d1:d2);
  atomicAdd(&deg[r*NN + D[e]], 1);
}

// ---------- 3-phase parallel scan (75 blocks), fused dnorm ----------
__global__ __launch_bounds__(256) void k_scan_a(const int* __restrict__ deg,
    int* __restrict__ off, int* __restrict__ bsum, float* __restrict__ dnv){
  int b = blockIdx.x;
  int r = b / NCHUNK, c = b - r*NCHUNK;
  const int* dg = deg + r*NN;
  int* o = off + r*(NN+1);
  int t = threadIdx.x;
  int base = c*SCHUNK + t*8;
  int v[8];
  #pragma unroll
  for (int j=0;j<8;j++){
    int i = base+j;
    int g = (i<NN)? dg[i] : 0;
    v[j] = g;
    if (i<NN) dnv[r*NN+i] = (g>0)? rsqrtf((float)g) : 0.f;
  }
  int s=0;
  #pragma unroll
  for (int j=0;j<8;j++){ s += v[j]; v[j] = s; }   // local inclusive
  int lane = t & 63, wid = t >> 6;
  int x = s;
  #pragma unroll
  for (int d=1; d<64; d<<=1){ int y=__shfl_up(x,(unsigned)d); if(lane>=d) x+=y; }
  __shared__ int ws[4];
  if (lane==63) ws[wid]=x;
  __syncthreads();
  int wpre = 0;
  if (wid>0) wpre += ws[0];
  if (wid>1) wpre += ws[1];
  if (wid>2) wpre += ws[2];
  int excl = wpre + x - s;
  #pragma unroll
  for (int j=0;j<8;j++){ int i=base+j; if (i<NN) o[i+1] = excl + v[j]; }
  if (t==255) bsum[b] = wpre + x;
}

__global__ void k_scan_b(int* __restrict__ bsum){
  int r = threadIdx.x;
  if (r < 3){
    int run = 0;
    for (int c=0;c<NCHUNK;c++){
      int t = bsum[r*NCHUNK+c];
      bsum[r*NCHUNK+c] = run;
      run += t;
    }
  }
}

__global__ __launch_bounds__(256) void k_scan_c(int* __restrict__ off,
                                                const int* __restrict__ bsum){
  int b = blockIdx.x;
  int r = b / NCHUNK, c = b - r*NCHUNK;
  int add = bsum[b];
  int* o = off + r*(NN+1);
  if (threadIdx.x==0 && c==0) o[0]=0;
  int base = c*SCHUNK;
  for (int j=threadIdx.x; j<SCHUNK; j+=256){
    int i = base+j;
    if (i<NN) o[i+1] += add;
  }
}

// ---------- bucketed CSR fill, LDS-histogram (low atomic contention) ----------
__global__ __launch_bounds__(256) void k_bfill_lds(
    const int* __restrict__ s0,const int* __restrict__ d0,
    const int* __restrict__ s1,const int* __restrict__ d1,
    const int* __restrict__ s2,const int* __restrict__ d2,
    const int* __restrict__ off, int* __restrict__ bcur,
    int2* __restrict__ pairbuf)
{
  __shared__ int hist[NBK];
  __shared__ int cur[NBK];
  __shared__ int gbase[NBK];
  const int r = blockIdx.y;
  const int* S = (r==0)?s0:((r==1)?s1:s2);
  const int* D = (r==0)?d0:((r==1)?d1:d2);
  const int e0 = blockIdx.x*EPB;
  const int t = threadIdx.x;
  for (int i=t; i<NBK; i+=256){ hist[i]=0; cur[i]=0; }
  __syncthreads();
  int sv[EPB/256], dv[EPB/256];
  #pragma unroll
  for (int j=0;j<EPB/256;j++){
    int e = e0 + j*256 + t;
    if (e < NE){
      sv[j] = S[e];
      int d = D[e];
      dv[j] = d;
      atomicAdd(&hist[d>>8], 1);
    }
  }
  __syncthreads();
  if (t < NBK){
    int h = hist[t];
    int base = off[r*(NN+1) + (t<<8)];
    gbase[t] = base + ((h>0) ? atomicAdd(&bcur[r*NBK+t], h) : 0);
  }
  __syncthreads();
  #pragma unroll
  for (int j=0;j<EPB/256;j++){
    int e = e0 + j*256 + t;
    if (e < NE){
      int b = dv[j] >> 8;
      int pos = gbase[b] + atomicAdd(&cur[b], 1);
      pairbuf[(size_t)r*NE + pos] = make_int2(sv[j], dv[j]);
    }
  }
}

// Phase B: per-(bucket, rel) block; scatter confined to L2-resident window.
__global__ __launch_bounds__(256) void k_bsort(const int2* __restrict__ pairbuf,
                                               const int* __restrict__ off,
                                               int* __restrict__ csrc){
  __shared__ int cur2[256];
  int r = blockIdx.y, b = blockIdx.x;
  int nb0 = b << 8;
  int nb1 = min(nb0 + 256, NN);
  const int* offr = off + r*(NN+1);
  cur2[threadIdx.x] = 0;
  __syncthreads();
  int e0 = offr[nb0], e1 = offr[nb1];
  for (int e = e0 + (int)threadIdx.x; e < e1; e += 256){
    int2 p = pairbuf[(size_t)r*NE + e];
    int slot = atomicAdd(&cur2[p.y - nb0], 1);
    csrc[(size_t)r*NE + offr[p.y] + slot] = p.x;
  }
}

// ---------- vectorized tiled f32 GEMM with leaky epilogue (t1) ----------
template<int BM,int BN,int BK,int TM,int TN,bool WT,bool BIAS,bool BOUT>
__global__ __launch_bounds__(256) void k_gemm(
    const float* __restrict__ A, int lda, int M, int K,
    const float* __restrict__ B, int ldb,
    const float* __restrict__ bias,
    float* __restrict__ C, int ldc, unsigned short* __restrict__ Cb)
{
  constexpr int TX = BN/TN;
  constexpr int TY = BM/TM;
  static_assert(TX*TY==256, "256 threads");
  static_assert(BK%4==0 && BN%4==0 && TN%4==0, "vec4");
  __shared__ float As[BK][BM+4];
  __shared__ float Bs[BK][BN+4];
  const int tid = threadIdx.x;
  const int tx = tid % TX, ty = tid / TX;
  const int bm = blockIdx.y*BM, bn = blockIdx.x*BN;
  float acc[TM][TN];
  #pragma unroll
  for (int i=0;i<TM;i++)
    #pragma unroll
    for (int j=0;j<TN;j++) acc[i][j]=0.f;

  for (int k0=0;k0<K;k0+=BK){
    #pragma unroll
    for (int q=tid; q<BM*BK/4; q+=256){
      int m = q/(BK/4), kq = q - m*(BK/4);
      int row = bm+m; row = (row<M)? row : (M-1);
      const float4 v = *(const float4*)&A[(size_t)row*lda + k0 + kq*4];
      As[kq*4+0][m]=v.x; As[kq*4+1][m]=v.y; As[kq*4+2][m]=v.z; As[kq*4+3][m]=v.w;
    }
    if (WT){
      #pragma unroll
      for (int q=tid; q<BN*BK/4; q+=256){
        int nj = q/(BK/4), kq = q - nj*(BK/4);
        const float4 v = *(const float4*)&B[(size_t)(bn+nj)*ldb + k0 + kq*4];
        Bs[kq*4+0][nj]=v.x; Bs[kq*4+1][nj]=v.y; Bs[kq*4+2][nj]=v.z; Bs[kq*4+3][nj]=v.w;
      }
    } else {
      #pragma unroll
      for (int q=tid; q<BN*BK/4; q+=256){
        int kk = q/(BN/4), nq = q - kk*(BN/4);
        const float4 v = *(const float4*)&B[(size_t)(k0+kk)*ldb + bn + nq*4];
        *(float4*)&Bs[kk][nq*4] = v;
      }
    }
    __syncthreads();
    #pragma unroll
    for (int kk=0;kk<BK;kk++){
      float a[TM], b[TN];
      #pragma unroll
      for (int i=0;i<TM;i++) a[i]=As[kk][ty*TM+i];
      #pragma unroll
      for (int j=0;j<TN;j++) b[j]=Bs[kk][tx*TN+j];
      #pragma unroll
      for (int i=0;i<TM;i++)
        #pragma unroll
        for (int j=0;j<TN;j++) acc[i][j] = fmaf(a[i], b[j], acc[i][j]);
    }
    __syncthreads();
  }
  #pragma unroll
  for (int i=0;i<TM;i++){
    int row = bm+ty*TM+i;
    if (row<M){
      #pragma unroll
      for (int j4=0;j4<TN/4;j4++){
        float o[4];
        #pragma unroll
        for (int u=0;u<4;u++){
          int j = j4*4+u;
          float v = acc[i][j];
          if (BIAS) v += bias[bn+tx*TN+j];
          o[u] = leaky1(v);
        }
        *(float4*)&C[(size_t)row*ldc + bn + tx*TN + j4*4] = make_float4(o[0],o[1],o[2],o[3]);
        if (BOUT){
          #pragma unroll
          for (int u=0;u<4;u++)
            Cb[(size_t)row*ldc + bn + tx*TN + j4*4 + u] = f2b(o[u]);
        }
      }
    }
  }
}

// ---------- bf16 weight prep ----------
__global__ void k_wprep(const float* __restrict__ w0, const float* __restrict__ w1,
                        const float* __restrict__ w2, __hip_bfloat16* __restrict__ wt){
  int t = blockIdx.x*256 + threadIdx.x;
  if (t >= 3*HID*HID) return;
  int r = t / (HID*HID), e = t - r*(HID*HID);
  int n = e >> 7, k = e & 127;
  const float* W = (r==0)?w0:((r==1)?w1:w2);
  wt[t] = __float2bfloat16(W[k*HID + n]);
}

// ---------- batched bf16 MFMA GEMM: raw2b[:, r*128 ..] = leaky(pre1b[r] @ hw1[r]) ----------
__global__ __launch_bounds__(256) void k_mfma128(
    const __hip_bfloat16* __restrict__ Abf, const __hip_bfloat16* __restrict__ Wt,
    unsigned short* __restrict__ Cb, int M)
{
  __shared__ short As[64][136];
  __shared__ short Bs[128][136];
  const int r = blockIdx.y;
  const unsigned short* Ar = (const unsigned short*)Abf + (size_t)r*M*HID;
  const unsigned short* W  = (const unsigned short*)Wt + (size_t)r*HID*HID;
  const int tid = threadIdx.x;
  const int bm = blockIdx.x*64;

  for (int q = tid; q < 64*16; q += 256){
    int row = q >> 4, c8 = q & 15;
    int grow = bm + row; grow = (grow < M) ? grow : (M-1);
    us8 v = *(const us8*)&Ar[(size_t)grow*HID + c8*8];
    *(us8*)&As[row][c8*8] = v;
  }
  for (int q = tid; q < 128*16; q += 256){
    int n = q >> 4, c8 = q & 15;
    us8 v = *(const us8*)&W[n*HID + c8*8];
    *(us8*)&Bs[n][c8*8] = v;
  }
  __syncthreads();

  const int wid = tid >> 6, lane = tid & 63;
  const int wrow = (wid & 1)*32, wcol = (wid >> 1)*64;
  const int fr = lane & 15, fq = lane >> 4;
  f4 acc[2][4];
  #pragma unroll
  for (int mi=0;mi<2;mi++)
    #pragma unroll
    for (int ni=0;ni<4;ni++) acc[mi][ni] = (f4){0.f,0.f,0.f,0.f};

  #pragma unroll
  for (int ks=0; ks<4; ks++){
    int kb = ks*32 + fq*8;
    bfrag a[2], b[4];
    #pragma unroll
    for (int mi=0;mi<2;mi++) a[mi] = *(const bfrag*)&As[wrow + mi*16 + fr][kb];
    #pragma unroll
    for (int ni=0;ni<4;ni++) b[ni] = *(const bfrag*)&Bs[wcol + ni*16 + fr][kb];
    #pragma unroll
    for (int mi=0;mi<2;mi++)
      #pragma unroll
      for (int ni=0;ni<4;ni++)
        acc[mi][ni] = __builtin_amdgcn_mfma_f32_16x16x32_bf16(a[mi], b[ni], acc[mi][ni], 0, 0, 0);
  }

  const int coff = r*HID;
  #pragma unroll
  for (int mi=0;mi<2;mi++){
    int row0 = bm + wrow + mi*16 + fq*4;
    #pragma unroll
    for (int j=0;j<4;j++){
      int row = row0 + j;
      if (row < M){
        #pragma unroll
        for (int ni=0;ni<4;ni++){
          Cb[(size_t)row*H3 + coff + wcol + ni*16 + fr] = f2b(leaky1(acc[mi][ni][j]));
        }
      }
    }
  }
}

// ---------- split-K (optionally z-batched) GEMM, raw partials ----------
template<int BM,int BN,int BK,int TM,int TN,bool WT,int NKS>
__global__ __launch_bounds__(256) void k_sk(
    const float* __restrict__ A0, int lda, int M, int kch, size_t strideA,
    const float* __restrict__ B0, const float* __restrict__ B1, const float* __restrict__ B2,
    int ldb, float* __restrict__ part)
{
  constexpr int TX = BN/TN;
  constexpr int TY = BM/TM;
  static_assert(TX*TY==256, "256 threads");
  __shared__ float As[BK][BM+4];
  __shared__ float Bs[BK][BN+4];
  const int z = blockIdx.z;
  const float* A = A0 + (size_t)z*strideA;
  const float* B = (z==0)?B0:((z==1)?B1:B2);
  const int ks = blockIdx.x;
  const int tid = threadIdx.x;
  const int tx = tid % TX, ty = tid / TX;
  const int bm = blockIdx.y*BM;
  float acc[TM][TN];
  #pragma unroll
  for (int i=0;i<TM;i++)
    #pragma unroll
    for (int j=0;j<TN;j++) acc[i][j]=0.f;

  const int kbeg = ks*kch;
  for (int k0=kbeg; k0<kbeg+kch; k0+=BK){
    #pragma unroll
    for (int q=tid; q<BM*BK/4; q+=256){
      int m = q/(BK/4), kq = q - m*(BK/4);
      const float4 v = *(const float4*)&A[(size_t)(bm+m)*lda + k0 + kq*4];
      As[kq*4+0][m]=v.x; As[kq*4+1][m]=v.y; As[kq*4+2][m]=v.z; As[kq*4+3][m]=v.w;
    }
    if (WT){
      #pragma unroll
      for (int q=tid; q<BN*BK/4; q+=256){
        int nj = q/(BK/4), kq = q - nj*(BK/4);
        const float4 v = *(const float4*)&B[(size_t)nj*ldb + k0 + kq*4];
        Bs[kq*4+0][nj]=v.x; Bs[kq*4+1][nj]=v.y; Bs[kq*4+2][nj]=v.z; Bs[kq*4+3][nj]=v.w;
      }
    } else {
      #pragma unroll
      for (int q=tid; q<BN*BK/4; q+=256){
        int kk = q/(BN/4), nq = q - kk*(BN/4);
        const float4 v = *(const float4*)&B[(size_t)(k0+kk)*ldb + nq*4];
        *(float4*)&Bs[kk][nq*4] = v;
      }
    }
    __syncthreads();
    #pragma unroll
    for (int kk=0;kk<BK;kk++){
      float a[TM], b[TN];
      #pragma unroll
      for (int i=0;i<TM;i++) a[i]=As[kk][ty*TM+i];
      #pragma unroll
      for (int j=0;j<TN;j++) b[j]=Bs[kk][tx*TN+j];
      #pragma unroll
      for (int i=0;i<TM;i++)
        #pragma unroll
        for (int j=0;j<TN;j++) acc[i][j] = fmaf(a[i], b[j], acc[i][j]);
    }
    __syncthreads();
  }
  #pragma unroll
  for (int i=0;i<TM;i++){
    int row = bm+ty*TM+i;
    #pragma unroll
    for (int j4=0;j4<TN/4;j4++){
      float4 v = make_float4(acc[i][j4*4+0],acc[i][j4*4+1],acc[i][j4*4+2],acc[i][j4*4+3]);
      *(float4*)&part[(((size_t)(z*NKS+ks))*M + row)*BN + tx*TN + j4*4] = v;
    }
  }
}

// reduce hw2 partials -> nf columns with leaky
__global__ __launch_bounds__(256) void k_hw2_red(const float* __restrict__ part,
                                                 float* __restrict__ nf){
  int t = blockIdx.x*256 + threadIdx.x;
  const int TOT = 3*NSEL*HID/4;
  if (t >= TOT) return;
  int rel = t / (NSEL*HID/4);
  int rem = t - rel*(NSEL*HID/4);
  int i = rem / (HID/4);
  int c4 = rem - i*(HID/4);
  float4 s = make_float4(0,0,0,0);
  #pragma unroll
  for (int ks=0; ks<KS3; ks++){
    const float4 v = *(const float4*)&part[(((size_t)(rel*KS3+ks))*NSEL + i)*HID + c4*4];
    s.x+=v.x; s.y+=v.y; s.z+=v.z; s.w+=v.w;
  }
  s.x=leaky1(s.x); s.y=leaky1(s.y); s.z=leaky1(s.z); s.w=leaky1(s.w);
  *(float4*)&nf[(size_t)i*FDIM + rel*HID + c4*4] = s;
}

// partial-reduce + bias + leaky + t3 projection, one wave per selected row
__global__ __launch_bounds__(256) void k_final_wave(
    const float* __restrict__ part, const float* __restrict__ t2b,
    const float* __restrict__ t3w, const float* __restrict__ t3b,
    float* __restrict__ outp)
{
  int w = (blockIdx.x*256 + threadIdx.x) >> 6;
  int j = threadIdx.x & 63;
  if (w >= NSEL) return;
  float v = 0.f;
  #pragma unroll
  for (int s=0;s<KS2;s++) v += part[((size_t)s*NSEL + w)*64 + j];
  v += t2b[j];
  v = leaky1(v);
  float a0 = v*t3w[j], a1 = v*t3w[64+j];
  #pragma unroll
  for (int sft=32;sft>0;sft>>=1){
    a0 += __shfl_down(a0,(unsigned)sft);
    a1 += __shfl_down(a1,(unsigned)sft);
  }
  if (j==0){
    outp[2*w+0] = a0 + t3b[0];
    outp[2*w+1] = a1 + t3b[1];
  }
}

// ---------- per-node gate scores (f32 input) ----------
template<int D>
__global__ __launch_bounds__(256) void k_scores(const float* __restrict__ X,
    const float* __restrict__ g0, const float* __restrict__ g1, const float* __restrict__ g2,
    float* __restrict__ sd, float* __restrict__ ss){
  int w = (blockIdx.x*256 + threadIdx.x) >> 6;
  int lane = threadIdx.x & 63;
  if (w >= NN) return;
  const float* x = X + (size_t)w*D;
  float a0=0,a1=0,a2=0,a3=0,a4=0,a5=0;
  for (int k=lane; k<D; k+=64){
    float v = x[k];
    a0 = fmaf(v, g0[k],   a0);  a1 = fmaf(v, g0[D+k], a1);
    a2 = fmaf(v, g1[k],   a2);  a3 = fmaf(v, g1[D+k], a3);
    a4 = fmaf(v, g2[k],   a4);  a5 = fmaf(v, g2[D+k], a5);
  }
  #pragma unroll
  for (int s=32;s>0;s>>=1){
    a0 += __shfl_down(a0,(unsigned)s); a1 += __shfl_down(a1,(unsigned)s);
    a2 += __shfl_down(a2,(unsigned)s); a3 += __shfl_down(a3,(unsigned)s);
    a4 += __shfl_down(a4,(unsigned)s); a5 += __shfl_down(a5,(unsigned)s);
  }
  if (lane==0){
    sd[0*NN+w]=a0; ss[0*NN+w]=a1;
    sd[1*NN+w]=a2; ss[1*NN+w]=a3;
    sd[2*NN+w]=a4; ss[2*NN+w]=a5;
  }
}

// ---------- per-node gate scores (bf16 input) ----------
template<int D>
__global__ __launch_bounds__(256) void k_scores_bf(const unsigned short* __restrict__ X,
    const float* __restrict__ g0, const float* __restrict__ g1, const float* __restrict__ g2,
    float* __restrict__ sd, float* __restrict__ ss){
  int w = (blockIdx.x*256 + threadIdx.x) >> 6;
  int lane = threadIdx.x & 63;
  if (w >= NN) return;
  const unsigned short* x = X + (size_t)w*D;
  float a0=0,a1=0,a2=0,a3=0,a4=0,a5=0;
  for (int k=lane; k<D; k+=64){
    float v = b2f(x[k]);
    a0 = fmaf(v, g0[k],   a0);  a1 = fmaf(v, g0[D+k], a1);
    a2 = fmaf(v, g1[k],   a2);  a3 = fmaf(v, g1[D+k], a3);
    a4 = fmaf(v, g2[k],   a4);  a5 = fmaf(v, g2[D+k], a5);
  }
  #pragma unroll
  for (int s=32;s>0;s>>=1){
    a0 += __shfl_down(a0,(unsigned)s); a1 += __shfl_down(a1,(unsigned)s);
    a2 += __shfl_down(a2,(unsigned)s); a3 += __shfl_down(a3,(unsigned)s);
    a4 += __shfl_down(a4,(unsigned)s); a5 += __shfl_down(a5,(unsigned)s);
  }
  if (lane==0){
    sd[0*NN+w]=a0; ss[0*NN+w]=a1;
    sd[1*NN+w]=a2; ss[1*NN+w]=a3;
    sd[2*NN+w]=a4; ss[2*NN+w]=a5;
  }
}

// ---------- layer-1 aggregation: WAVE-PER-NODE, edge-parallel 16B loads ----------
// One wave per (node, rel). 4 edge-groups of 16 lanes; each group streams one
// 256B bf16 row via us8; coeffs via __shfl; column-reduce via __shfl_xor.
__global__ __launch_bounds__(256) void k_gather_f3w(const float* __restrict__ Xf,
    const unsigned short* __restrict__ Xb,
    const int* __restrict__ off, const int* __restrict__ csrc,
    const float* __restrict__ sd, const float* __restrict__ ss,
    const float* __restrict__ dnv,
    const float* __restrict__ gb0, const float* __restrict__ gb1, const float* __restrict__ gb2,
    unsigned short* __restrict__ outp){
  int wv = threadIdx.x >> 6, lane = threadIdx.x & 63;
  int n = blockIdx.x*4 + wv;
  int r = blockIdx.y;
  if (n >= NN) return;
  const int* offr = off + r*(NN+1);
  const int* csr  = csrc + (size_t)r*NE;
  const float* ssr = ss + r*NN;
  const float* dnr = dnv + r*NN;
  float gbv = ((r==0)?gb0:((r==1)?gb1:gb2))[0];
  float sd_n = sd[r*NN + n], dn_n = dnr[n];
  const int g = lane >> 4, p = lane & 15;
  float acc[8];
  #pragma unroll
  for (int i=0;i<8;i++) acc[i]=0.f;
  int p0 = offr[n], p1 = offr[n+1];
  for (int pc=p0; pc<p1; pc+=64){
    int m = min(64, p1-pc);
    int s = 0; float c = 0.f;
    if (lane < m){
      s = csr[pc+lane];
      c = tanhf(sd_n + ssr[s] + gbv) * dn_n * dnr[s];
    }
    for (int j=g; j<m; j+=4){
      int   sj = __shfl(s, j);
      float cj = __shfl(c, j);
      us8 v = *(const us8*)&Xb[(size_t)sj*HID + p*8];
      #pragma unroll
      for (int i=0;i<8;i++) acc[i] = fmaf(cj, b2f(v[i]), acc[i]);
    }
  }
  #pragma unroll
  for (int i=0;i<8;i++){
    acc[i] += __shfl_xor(acc[i], 16);
    acc[i] += __shfl_xor(acc[i], 32);
  }
  if (g == 0){
    const float4 r0 = *(const float4*)&Xf[(size_t)n*HID + p*8];
    const float4 r1 = *(const float4*)&Xf[(size_t)n*HID + p*8 + 4];
    acc[0] = fmaf(EPSF, r0.x, acc[0]); acc[1] = fmaf(EPSF, r0.y, acc[1]);
    acc[2] = fmaf(EPSF, r0.z, acc[2]); acc[3] = fmaf(EPSF, r0.w, acc[3]);
    acc[4] = fmaf(EPSF, r1.x, acc[4]); acc[5] = fmaf(EPSF, r1.y, acc[5]);
    acc[6] = fmaf(EPSF, r1.z, acc[6]); acc[7] = fmaf(EPSF, r1.w, acc[7]);
    us8 o;
    #pragma unroll
    for (int i=0;i<8;i++) o[i] = f2b(acc[i]);
    *(us8*)&outp[((size_t)r*NN + n)*HID + p*8] = o;
  }
}

// ---------- layer-2 selected aggregation: wave-per-(sel,rel), D=384 ----------
__global__ __launch_bounds__(256) void k_gather_sel3w(const unsigned short* __restrict__ Xb,
    const int* __restrict__ nodes,
    const int* __restrict__ off, const int* __restrict__ csrc,
    const float* __restrict__ sd, const float* __restrict__ ss,
    const float* __restrict__ dnv,
    const float* __restrict__ gb0, const float* __restrict__ gb1, const float* __restrict__ gb2,
    float* __restrict__ outp){
  int wv = threadIdx.x >> 6, lane = threadIdx.x & 63;
  int i = blockIdx.x*4 + wv;
  int r = blockIdx.y;
  if (i >= NSEL) return;
  int n = nodes[i];
  const int* offr = off + r*(NN+1);
  const int* csr  = csrc + (size_t)r*NE;
  const float* ssr = ss + r*NN;
  const float* dnr = dnv + r*NN;
  float gbv = ((r==0)?gb0:((r==1)?gb1:gb2))[0];
  float sd_n = sd[r*NN + n], dn_n = dnr[n];
  const int g = lane >> 4, p = lane & 15;
  float acc[3][8];
  #pragma unroll
  for (int cc=0;cc<3;cc++)
    #pragma unroll
    for (int q=0;q<8;q++) acc[cc][q]=0.f;
  int p0 = offr[n], p1 = offr[n+1];
  for (int pc=p0; pc<p1; pc+=64){
    int m = min(64, p1-pc);
    int s = 0; float c = 0.f;
    if (lane < m){
      s = csr[pc+lane];
      c = tanhf(sd_n + ssr[s] + gbv) * dn_n * dnr[s];
    }
    for (int j=g; j<m; j+=4){
      int   sj = __shfl(s, j);
      float cj = __shfl(c, j);
      const unsigned short* row = &Xb[(size_t)sj*H3];
      #pragma unroll
      for (int cc=0;cc<3;cc++){
        us8 v = *(const us8*)&row[cc*HID + p*8];
        #pragma unroll
        for (int q=0;q<8;q++) acc[cc][q] = fmaf(cj, b2f(v[q]), acc[cc][q]);
      }
    }
  }
  #pragma unroll
  for (int cc=0;cc<3;cc++)
    #pragma unroll
    for (int q=0;q<8;q++){
      acc[cc][q] += __shfl_xor(acc[cc][q], 16);
      acc[cc][q] += __shfl_xor(acc[cc][q], 32);
    }
  if (g == 0){
    const unsigned short* xrow = &Xb[(size_t)n*H3];
    float* orow = &outp[((size_t)r*NSEL + i)*H3];
    #pragma unroll
    for (int cc=0;cc<3;cc++){
      us8 v = *(const us8*)&xrow[cc*HID + p*8];
      #pragma unroll
      for (int q=0;q<8;q++) acc[cc][q] = fmaf(EPSF, b2f(v[q]), acc[cc][q]);
      *(float4*)&orow[cc*HID + p*8]     = make_float4(acc[cc][0],acc[cc][1],acc[cc][2],acc[cc][3]);
      *(float4*)&orow[cc*HID + p*8 + 4] = make_float4(acc[cc][4],acc[cc][5],acc[cc][6],acc[cc][7]);
    }
  }
}

// ---------- gather raw0/raw1/raw2 rows into nf ----------
__global__ __launch_bounds__(192) void k_nf_fill(const float* __restrict__ h,
    const float* __restrict__ raw1, const unsigned short* __restrict__ raw2b,
    const int* __restrict__ nodes, float* __restrict__ nf){
  int i = blockIdx.x;
  int n = nodes[i];
  for (int c=threadIdx.x; c<576; c+=192){
    float v; int col;
    if (c < 64)       { v = h[(size_t)n*IND + c];            col = 384 + c; }
    else if (c < 192) { int q=c-64;  v = raw1[(size_t)n*HID + q]; col = 448 + q; }
    else              { int q=c-192; v = b2f(raw2b[(size_t)n*H3 + q]); col = 576 + q; }
    nf[(size_t)i*FDIM + col] = v;
  }
}

extern "C" void kernel_launch(void* const* d_in, const int* in_sizes, int n_in,
                              void* d_out, int out_size, void* d_ws, size_t ws_size,
                              hipStream_t stream){
  if (n_in < 32) return;
  const float* h = (const float*)d_in[0];
  const int* src[3] = {(const int*)d_in[1], (const int*)d_in[3], (const int*)d_in[5]};
  const int* dst[3] = {(const int*)d_in[2], (const int*)d_in[4], (const int*)d_in[6]};
  const int* nodes = (const int*)d_in[7];
  const float* t1w = (const float*)d_in[8];
  const float* t1b = (const float*)d_in[9];

  bool dictOrder = (in_sizes[12] == 768);
  const float *g1w[3],*g1b[3],*g2w[3],*g2b[3],*hw1[3],*hw2[3];
  for (int r=0;r<3;r++){
    if (dictOrder){
      int base = 10 + r*6;
      g1w[r]=(const float*)d_in[base+0]; g1b[r]=(const float*)d_in[base+1];
      g2w[r]=(const float*)d_in[base+2]; g2b[r]=(const float*)d_in[base+3];
      hw1[r]=(const float*)d_in[base+4]; hw2[r]=(const float*)d_in[base+5];
    } else {
      g1w[r]=(const float*)d_in[10+2*r]; g1b[r]=(const float*)d_in[11+2*r];
      g2w[r]=(const float*)d_in[16+2*r]; g2b[r]=(const float*)d_in[17+2*r];
      hw1[r]=(const float*)d_in[22+r];   hw2[r]=(const float*)d_in[25+r];
    }
  }
  const float* t2w = (const float*)d_in[28];
  const float* t2b = (const float*)d_in[29];
  const float* t3w = (const float*)d_in[30];
  const float* t3b = (const float*)d_in[31];
  float* outp = (float*)d_out;

  // workspace carve (~140 MB)
  char* w = (char*)d_ws;
  auto carve = [&](size_t bytes)->void*{
    void* p = (void*)w;
    w += ((bytes + 255) & ~size_t(255));
    return p;
  };
  int*   deg  = (int*)  carve((size_t)(3*NN+1024)*4);  // deg[3N] + bcur[3*NBK], one memset
  int*   bcur = deg + 3*NN;
  int*   off  = (int*)  carve((size_t)3*(NN+1)*4);
  float* dnv  = (float*)carve((size_t)3*NN*4);
  int*   bsum = (int*)  carve((size_t)128*4);
  int*   csrc = (int*)  carve((size_t)3*NE*4);
  float* sd1  = (float*)carve((size_t)3*NN*4);
  float* ss1  = (float*)carve((size_t)3*NN*4);
  float* sd2  = (float*)carve((size_t)3*NN*4);
  float* ss2  = (float*)carve((size_t)3*NN*4);
  __hip_bfloat16* w1t = (__hip_bfloat16*)carve((size_t)3*HID*HID*2);
  float* raw1 = (float*)carve((size_t)NN*HID*4);
  unsigned short* raw1b = (unsigned short*)carve((size_t)NN*HID*2);
  unsigned short* raw2b = (unsigned short*)carve((size_t)NN*H3*2);
  // union region: pairbuf[3*NE int2] | pre1b bf16 [3][NN][HID] |
  //               pre2[3*NSEL*H3]+hw2part[9*NSEL*HID] | t2part[KS2*NSEL*64]
  size_t ubytes = (size_t)3*NN*HID*2;                                // 38.4 MB
  size_t u2 = ((size_t)3*NSEL*H3 + (size_t)3*KS3*NSEL*HID)*4;        // 37.7 MB
  size_t u3 = (size_t)3*NE*8;                                        //  9.6 MB
  if (u2 > ubytes) ubytes = u2;
  if (u3 > ubytes) ubytes = u3;
  float* ureg = (float*)carve(ubytes);
  int2* pairbuf = (int2*)ureg;
  unsigned short* pre1b = (unsigned short*)ureg;
  float* pre2  = ureg;
  float* hw2p  = ureg + (size_t)3*NSEL*H3;
  float* t2p   = ureg;
  float* nf   = (float*)carve((size_t)NSEL*FDIM*4);

  hipMemsetAsync(deg, 0, (size_t)(3*NN+1024)*4, stream);
  k_deg   <<<(3*NE+255)/256, 256, 0, stream>>>(dst[0], dst[1], dst[2], deg);
  k_scan_a<<<3*NCHUNK, 256, 0, stream>>>(deg, off, bsum, dnv);
  k_scan_b<<<1, 64, 0, stream>>>(bsum);
  k_scan_c<<<3*NCHUNK, 256, 0, stream>>>(off, bsum);
  k_bfill_lds<<<dim3((NE+EPB-1)/EPB, 3), 256, 0, stream>>>(
      src[0],dst[0],src[1],dst[1],src[2],dst[2], off, bcur, pairbuf);
  k_bsort <<<dim3(NBK,3), 256, 0, stream>>>(pairbuf, off, csrc);

  // raw1 = leaky(h @ t1_w^T + t1_b)   (f32 + bf16 mirror)
  k_gemm<64,128,32,4,8,true,true,true><<<dim3(1,(NN+63)/64), 256, 0, stream>>>(
      h, IND, NN, IND, t1w, IND, t1b, raw1, HID, raw1b);

  k_scores<HID><<<(NN+3)/4, 256, 0, stream>>>(raw1, g1w[0], g1w[1], g1w[2], sd1, ss1);

  // layer-1 gathers (wave-per-node, 3 relations batched) + bf16 MFMA hw1 GEMMs
  k_wprep<<<(3*HID*HID+255)/256, 256, 0, stream>>>(hw1[0], hw1[1], hw1[2], w1t);
  k_gather_f3w<<<dim3(NN/4, 3), 256, 0, stream>>>(raw1, raw1b, off, csrc,
      sd1, ss1, dnv, g1b[0], g1b[1], g1b[2], pre1b);
  k_mfma128<<<dim3((NN+63)/64, 3), 256, 0, stream>>>((const __hip_bfloat16*)pre1b, w1t, raw2b, NN);

  k_scores_bf<H3><<<(NN+3)/4, 256, 0, stream>>>(raw2b, g2w[0], g2w[1], g2w[2], sd2, ss2);

  // batched selected gather over 3 relations (wave-per-selected-node)
  k_gather_sel3w<<<dim3(NSEL/4, 3), 256, 0, stream>>>(raw2b, nodes, off, csrc,
      sd2, ss2, dnv, g2b[0], g2b[1], g2b[2], pre2);

  // hw2: split-K x3, z-batched over relations -> partials -> reduce into nf
  k_sk<32,128,32,2,8,false,KS3><<<dim3(KS3, NSEL/32, 3), 256, 0, stream>>>(
      pre2, H3, NSEL, KCH3, (size_t)NSEL*H3, hw2[0], hw2[1], hw2[2], HID, hw2p);
  k_hw2_red<<<(3*NSEL*HID/4 + 255)/256, 256, 0, stream>>>(hw2p, nf);

  k_nf_fill<<<NSEL, 192, 0, stream>>>(h, raw1, raw2b, nodes, nf);

  // t2 split-K x10 partials then fused reduce + leaky + t3
  k_sk<64,64,32,4,4,true,1><<<dim3(KS2, NSEL/64, 1), 256, 0, stream>>>(
      nf, FDIM, NSEL, KCH2, 0, t2w, t2w, t2w, FDIM, t2p);
  k_final_wave<<<(NSEL*64+255)/256, 256, 0, stream>>>(t2p, t2b, t3w, t3b, outp);
}

// Round 7
// 286.186 us; speedup vs baseline: 3.2008x; 1.1931x over previous
//
#include <hip/hip_runtime.h>
#include <hip/hip_bf16.h>

#define NN 50000
#define NE 400000
#define IND 64
#define HID 128
#define H3 384
#define FDIM 960
#define NSEL 4096
#define EPSF 0.3f
#define SLOPEF 0.3f
#define SCHUNK 2048
#define NCHUNK 25          // ceil(NN/SCHUNK)
#define KS2 10             // t2 split-K
#define KCH2 96            // 960/10
#define NBK 196            // ceil(NN/256) dst-buckets per relation
#define BCAP 4096          // fixed bucket capacity (mean 2048, sigma 45)
#define EPB 8192           // edges per block in k_bfill2

typedef __attribute__((ext_vector_type(8))) short bfrag;   // 8 bf16 (4 VGPR)
typedef __attribute__((ext_vector_type(4))) float f4;
typedef __attribute__((ext_vector_type(8))) unsigned short us8;

__device__ __forceinline__ float leaky1(float v){ return v>=0.f? v : SLOPEF*v; }
__device__ __forceinline__ float b2f(unsigned short u){
  return __uint_as_float(((unsigned)u)<<16);
}
__device__ __forceinline__ unsigned short f2b(float v){
  __hip_bfloat16 b = __float2bfloat16(v);
  return *(unsigned short*)&b;
}

// ---------- fused degree + bucketed fill (fixed-capacity buckets) ----------
__global__ __launch_bounds__(256) void k_bfill2(
    const int* __restrict__ s0,const int* __restrict__ d0,
    const int* __restrict__ s1,const int* __restrict__ d1,
    const int* __restrict__ s2,const int* __restrict__ d2,
    int* __restrict__ deg, int* __restrict__ bcnt,
    int2* __restrict__ pairbuf)
{
  __shared__ int hist[NBK];
  __shared__ int cur[NBK];
  __shared__ int gbase[NBK];
  const int r = blockIdx.y;
  const int* S = (r==0)?s0:((r==1)?s1:s2);
  const int* D = (r==0)?d0:((r==1)?d1:d2);
  const int e0 = blockIdx.x*EPB;
  const int t = threadIdx.x;
  for (int i=t; i<NBK; i+=256){ hist[i]=0; cur[i]=0; }
  __syncthreads();
  int sv[EPB/256], dv[EPB/256];
  #pragma unroll
  for (int j=0;j<EPB/256;j++){
    int e = e0 + j*256 + t;
    if (e < NE){
      sv[j] = S[e];
      int d = D[e];
      dv[j] = d;
      atomicAdd(&deg[r*NN + d], 1);
      atomicAdd(&hist[d>>8], 1);
    }
  }
  __syncthreads();
  if (t < NBK){
    int h = hist[t];
    gbase[t] = (h>0) ? atomicAdd(&bcnt[r*NBK+t], h) : 0;
  }
  __syncthreads();
  #pragma unroll
  for (int j=0;j<EPB/256;j++){
    int e = e0 + j*256 + t;
    if (e < NE){
      int b = dv[j] >> 8;
      int pos = atomicAdd(&cur[b], 1);
      pairbuf[((size_t)(r*NBK + b))*BCAP + gbase[b] + pos] = make_int2(sv[j], dv[j]);
    }
  }
}

// ---------- 3-phase parallel scan (75 blocks), fused dnorm ----------
__global__ __launch_bounds__(256) void k_scan_a(const int* __restrict__ deg,
    int* __restrict__ off, int* __restrict__ bsum, float* __restrict__ dnv){
  int b = blockIdx.x;
  int r = b / NCHUNK, c = b - r*NCHUNK;
  const int* dg = deg + r*NN;
  int* o = off + r*(NN+1);
  int t = threadIdx.x;
  int base = c*SCHUNK + t*8;
  int v[8];
  #pragma unroll
  for (int j=0;j<8;j++){
    int i = base+j;
    int g = (i<NN)? dg[i] : 0;
    v[j] = g;
    if (i<NN) dnv[r*NN+i] = (g>0)? rsqrtf((float)g) : 0.f;
  }
  int s=0;
  #pragma unroll
  for (int j=0;j<8;j++){ s += v[j]; v[j] = s; }
  int lane = t & 63, wid = t >> 6;
  int x = s;
  #pragma unroll
  for (int d=1; d<64; d<<=1){ int y=__shfl_up(x,(unsigned)d); if(lane>=d) x+=y; }
  __shared__ int ws[4];
  if (lane==63) ws[wid]=x;
  __syncthreads();
  int wpre = 0;
  if (wid>0) wpre += ws[0];
  if (wid>1) wpre += ws[1];
  if (wid>2) wpre += ws[2];
  int excl = wpre + x - s;
  #pragma unroll
  for (int j=0;j<8;j++){ int i=base+j; if (i<NN) o[i+1] = excl + v[j]; }
  if (t==255) bsum[b] = wpre + x;
}

__global__ void k_scan_b(int* __restrict__ bsum){
  int r = threadIdx.x;
  if (r < 3){
    int run = 0;
    for (int c=0;c<NCHUNK;c++){
      int t = bsum[r*NCHUNK+c];
      bsum[r*NCHUNK+c] = run;
      run += t;
    }
  }
}

__global__ __launch_bounds__(256) void k_scan_c(int* __restrict__ off,
                                                const int* __restrict__ bsum){
  int b = blockIdx.x;
  int r = b / NCHUNK, c = b - r*NCHUNK;
  int add = bsum[b];
  int* o = off + r*(NN+1);
  if (threadIdx.x==0 && c==0) o[0]=0;
  int base = c*SCHUNK;
  for (int j=threadIdx.x; j<SCHUNK; j+=256){
    int i = base+j;
    if (i<NN) o[i+1] += add;
  }
}

// ---------- bucket sort -> compact CSR (csrc) ----------
__global__ __launch_bounds__(256) void k_bsort2(const int2* __restrict__ pairbuf,
                                                const int* __restrict__ bcnt,
                                                const int* __restrict__ off,
                                                int* __restrict__ csrc){
  __shared__ int cur2[256];
  int r = blockIdx.y, b = blockIdx.x;
  int nb0 = b << 8;
  const int* offr = off + r*(NN+1);
  cur2[threadIdx.x] = 0;
  __syncthreads();
  int cnt = bcnt[r*NBK + b];
  const int2* pb = pairbuf + ((size_t)(r*NBK + b))*BCAP;
  for (int e = (int)threadIdx.x; e < cnt; e += 256){
    int2 p = pb[e];
    int slot = atomicAdd(&cur2[p.y - nb0], 1);
    csrc[(size_t)r*NE + offr[p.y] + slot] = p.x;
  }
}

// ---------- h -> bf16 cast ----------
__global__ void k_cast_h(const float* __restrict__ h, unsigned short* __restrict__ hb){
  int t = blockIdx.x*256 + threadIdx.x;
  if (t >= NN*IND/8) return;
  const float4 a = ((const float4*)h)[t*2];
  const float4 b = ((const float4*)h)[t*2+1];
  us8 o;
  o[0]=f2b(a.x); o[1]=f2b(a.y); o[2]=f2b(a.z); o[3]=f2b(a.w);
  o[4]=f2b(b.x); o[5]=f2b(b.y); o[6]=f2b(b.z); o[7]=f2b(b.w);
  *(us8*)&hb[t*8] = o;
}

// ---------- all weight preps -> bf16 [n][k] layouts ----------
__global__ void k_wprep_all(const float* __restrict__ t1w,
    const float* __restrict__ hw1_0, const float* __restrict__ hw1_1, const float* __restrict__ hw1_2,
    const float* __restrict__ hw2_0, const float* __restrict__ hw2_1, const float* __restrict__ hw2_2,
    unsigned short* __restrict__ wt1, unsigned short* __restrict__ w1t,
    unsigned short* __restrict__ w2t){
  int t = blockIdx.x*256 + threadIdx.x;
  if (t < 8192){                      // t1w already [n=128][k=64]
    wt1[t] = f2b(t1w[t]);
  } else if (t < 8192 + 3*16384){     // hw1 [k=128][n=128] -> [r][n][k]
    int e = t - 8192;
    int r = e / 16384, q = e - r*16384;
    int n = q >> 7, k = q & 127;
    const float* W = (r==0)?hw1_0:((r==1)?hw1_1:hw1_2);
    w1t[e] = f2b(W[k*HID + n]);
  } else if (t < 8192 + 3*16384 + 3*49152){  // hw2 [k=384][n=128] -> [r][n][k]
    int e = t - 8192 - 3*16384;
    int r = e / 49152, q = e - r*49152;
    int n = q / H3, k = q - n*H3;
    const float* W = (r==0)?hw2_0:((r==1)?hw2_1:hw2_2);
    w2t[e] = f2b(W[k*HID + n]);
  }
}

// ---------- t1 MFMA: raw1 = leaky(hb @ wt1^T + t1b), f32 + bf16 out ----------
__global__ __launch_bounds__(256) void k_mfma_t1(
    const unsigned short* __restrict__ Ab, const unsigned short* __restrict__ W,
    const float* __restrict__ bias,
    float* __restrict__ Cf, unsigned short* __restrict__ Cb)
{
  __shared__ short As[64][72];
  __shared__ short Bs[128][72];
  const int tid = threadIdx.x;
  const int bm = blockIdx.x*64;

  for (int q = tid; q < 64*8; q += 256){
    int row = q >> 3, c8 = q & 7;
    int grow = bm + row; grow = (grow < NN) ? grow : (NN-1);
    *(us8*)&As[row][c8*8] = *(const us8*)&Ab[(size_t)grow*IND + c8*8];
  }
  for (int q = tid; q < 128*8; q += 256){
    int n = q >> 3, c8 = q & 7;
    *(us8*)&Bs[n][c8*8] = *(const us8*)&W[n*IND + c8*8];
  }
  __syncthreads();

  const int wid = tid >> 6, lane = tid & 63;
  const int wrow = (wid & 1)*32, wcol = (wid >> 1)*64;
  const int fr = lane & 15, fq = lane >> 4;
  f4 acc[2][4];
  #pragma unroll
  for (int mi=0;mi<2;mi++)
    #pragma unroll
    for (int ni=0;ni<4;ni++) acc[mi][ni] = (f4){0.f,0.f,0.f,0.f};

  #pragma unroll
  for (int ks=0; ks<2; ks++){
    int kb = ks*32 + fq*8;
    bfrag a[2], b[4];
    #pragma unroll
    for (int mi=0;mi<2;mi++) a[mi] = *(const bfrag*)&As[wrow + mi*16 + fr][kb];
    #pragma unroll
    for (int ni=0;ni<4;ni++) b[ni] = *(const bfrag*)&Bs[wcol + ni*16 + fr][kb];
    #pragma unroll
    for (int mi=0;mi<2;mi++)
      #pragma unroll
      for (int ni=0;ni<4;ni++)
        acc[mi][ni] = __builtin_amdgcn_mfma_f32_16x16x32_bf16(a[mi], b[ni], acc[mi][ni], 0, 0, 0);
  }

  #pragma unroll
  for (int mi=0;mi<2;mi++){
    int row0 = bm + wrow + mi*16 + fq*4;
    #pragma unroll
    for (int j=0;j<4;j++){
      int row = row0 + j;
      if (row < NN){
        #pragma unroll
        for (int ni=0;ni<4;ni++){
          int col = wcol + ni*16 + fr;
          float v = leaky1(acc[mi][ni][j] + bias[col]);
          Cf[(size_t)row*HID + col] = v;
          Cb[(size_t)row*HID + col] = f2b(v);
        }
      }
    }
  }
}

// ---------- batched bf16 MFMA: raw2b[:, r*128..] = leaky(pre1b[r] @ hw1[r]) ----------
__global__ __launch_bounds__(256) void k_mfma128(
    const unsigned short* __restrict__ Abf, const unsigned short* __restrict__ Wt,
    unsigned short* __restrict__ Cb, int M)
{
  __shared__ short As[64][136];
  __shared__ short Bs[128][136];
  const int r = blockIdx.y;
  const unsigned short* Ar = Abf + (size_t)r*M*HID;
  const unsigned short* W  = Wt + (size_t)r*HID*HID;
  const int tid = threadIdx.x;
  const int bm = blockIdx.x*64;

  for (int q = tid; q < 64*16; q += 256){
    int row = q >> 4, c8 = q & 15;
    int grow = bm + row; grow = (grow < M) ? grow : (M-1);
    *(us8*)&As[row][c8*8] = *(const us8*)&Ar[(size_t)grow*HID + c8*8];
  }
  for (int q = tid; q < 128*16; q += 256){
    int n = q >> 4, c8 = q & 15;
    *(us8*)&Bs[n][c8*8] = *(const us8*)&W[n*HID + c8*8];
  }
  __syncthreads();

  const int wid = tid >> 6, lane = tid & 63;
  const int wrow = (wid & 1)*32, wcol = (wid >> 1)*64;
  const int fr = lane & 15, fq = lane >> 4;
  f4 acc[2][4];
  #pragma unroll
  for (int mi=0;mi<2;mi++)
    #pragma unroll
    for (int ni=0;ni<4;ni++) acc[mi][ni] = (f4){0.f,0.f,0.f,0.f};

  #pragma unroll
  for (int ks=0; ks<4; ks++){
    int kb = ks*32 + fq*8;
    bfrag a[2], b[4];
    #pragma unroll
    for (int mi=0;mi<2;mi++) a[mi] = *(const bfrag*)&As[wrow + mi*16 + fr][kb];
    #pragma unroll
    for (int ni=0;ni<4;ni++) b[ni] = *(const bfrag*)&Bs[wcol + ni*16 + fr][kb];
    #pragma unroll
    for (int mi=0;mi<2;mi++)
      #pragma unroll
      for (int ni=0;ni<4;ni++)
        acc[mi][ni] = __builtin_amdgcn_mfma_f32_16x16x32_bf16(a[mi], b[ni], acc[mi][ni], 0, 0, 0);
  }

  const int coff = r*HID;
  #pragma unroll
  for (int mi=0;mi<2;mi++){
    int row0 = bm + wrow + mi*16 + fq*4;
    #pragma unroll
    for (int j=0;j<4;j++){
      int row = row0 + j;
      if (row < M){
        #pragma unroll
        for (int ni=0;ni<4;ni++){
          Cb[(size_t)row*H3 + coff + wcol + ni*16 + fr] = f2b(leaky1(acc[mi][ni][j]));
        }
      }
    }
  }
}

// ---------- hw2 MFMA: nf[:, r*128..] = leaky(pre2b[r] @ hw2[r]), K=384 ----------
__global__ __launch_bounds__(256) void k_mfma384(
    const unsigned short* __restrict__ Abf, const unsigned short* __restrict__ Wt,
    float* __restrict__ nf)
{
  __shared__ short As[32][72];
  __shared__ short Bs[128][72];
  const int r = blockIdx.y;
  const unsigned short* Ar = Abf + (size_t)r*NSEL*H3;
  const unsigned short* W  = Wt + (size_t)r*HID*H3;
  const int tid = threadIdx.x;
  const int bm = blockIdx.x*32;
  const int wid = tid >> 6, lane = tid & 63;
  const int fr = lane & 15, fq = lane >> 4;
  f4 acc[2][2];
  #pragma unroll
  for (int mi=0;mi<2;mi++)
    #pragma unroll
    for (int ni=0;ni<2;ni++) acc[mi][ni] = (f4){0.f,0.f,0.f,0.f};

  for (int kc=0; kc<6; kc++){
    for (int q = tid; q < 32*8; q += 256){
      int row = q >> 3, c8 = q & 7;
      *(us8*)&As[row][c8*8] = *(const us8*)&Ar[(size_t)(bm+row)*H3 + kc*64 + c8*8];
    }
    for (int q = tid; q < 128*8; q += 256){
      int n = q >> 3, c8 = q & 7;
      *(us8*)&Bs[n][c8*8] = *(const us8*)&W[(size_t)n*H3 + kc*64 + c8*8];
    }
    __syncthreads();
    #pragma unroll
    for (int ks=0; ks<2; ks++){
      int kb = ks*32 + fq*8;
      bfrag a[2], b[2];
      #pragma unroll
      for (int mi=0;mi<2;mi++) a[mi] = *(const bfrag*)&As[mi*16 + fr][kb];
      #pragma unroll
      for (int ni=0;ni<2;ni++) b[ni] = *(const bfrag*)&Bs[wid*32 + ni*16 + fr][kb];
      #pragma unroll
      for (int mi=0;mi<2;mi++)
        #pragma unroll
        for (int ni=0;ni<2;ni++)
          acc[mi][ni] = __builtin_amdgcn_mfma_f32_16x16x32_bf16(a[mi], b[ni], acc[mi][ni], 0, 0, 0);
    }
    __syncthreads();
  }

  #pragma unroll
  for (int mi=0;mi<2;mi++){
    int row0 = bm + mi*16 + fq*4;
    #pragma unroll
    for (int j=0;j<4;j++){
      int i = row0 + j;
      #pragma unroll
      for (int ni=0;ni<2;ni++){
        int col = wid*32 + ni*16 + fr;
        nf[(size_t)i*FDIM + r*HID + col] = leaky1(acc[mi][ni][j]);
      }
    }
  }
}

// ---------- split-K GEMM for t2 (WT layout), raw partials ----------
template<int BM,int BN,int BK,int TM,int TN>
__global__ __launch_bounds__(256) void k_sk(
    const float* __restrict__ A, int lda, int M, int kch,
    const float* __restrict__ B, int ldb, float* __restrict__ part)
{
  constexpr int TX = BN/TN;
  constexpr int TY = BM/TM;
  static_assert(TX*TY==256, "256 threads");
  __shared__ float As[BK][BM+4];
  __shared__ float Bs[BK][BN+4];
  const int ks = blockIdx.x;
  const int tid = threadIdx.x;
  const int tx = tid % TX, ty = tid / TX;
  const int bm = blockIdx.y*BM;
  float acc[TM][TN];
  #pragma unroll
  for (int i=0;i<TM;i++)
    #pragma unroll
    for (int j=0;j<TN;j++) acc[i][j]=0.f;

  const int kbeg = ks*kch;
  for (int k0=kbeg; k0<kbeg+kch; k0+=BK){
    #pragma unroll
    for (int q=tid; q<BM*BK/4; q+=256){
      int m = q/(BK/4), kq = q - m*(BK/4);
      const float4 v = *(const float4*)&A[(size_t)(bm+m)*lda + k0 + kq*4];
      As[kq*4+0][m]=v.x; As[kq*4+1][m]=v.y; As[kq*4+2][m]=v.z; As[kq*4+3][m]=v.w;
    }
    #pragma unroll
    for (int q=tid; q<BN*BK/4; q+=256){
      int nj = q/(BK/4), kq = q - nj*(BK/4);
      const float4 v = *(const float4*)&B[(size_t)nj*ldb + k0 + kq*4];
      Bs[kq*4+0][nj]=v.x; Bs[kq*4+1][nj]=v.y; Bs[kq*4+2][nj]=v.z; Bs[kq*4+3][nj]=v.w;
    }
    __syncthreads();
    #pragma unroll
    for (int kk=0;kk<BK;kk++){
      float a[TM], b[TN];
      #pragma unroll
      for (int i=0;i<TM;i++) a[i]=As[kk][ty*TM+i];
      #pragma unroll
      for (int j=0;j<TN;j++) b[j]=Bs[kk][tx*TN+j];
      #pragma unroll
      for (int i=0;i<TM;i++)
        #pragma unroll
        for (int j=0;j<TN;j++) acc[i][j] = fmaf(a[i], b[j], acc[i][j]);
    }
    __syncthreads();
  }
  #pragma unroll
  for (int i=0;i<TM;i++){
    int row = bm+ty*TM+i;
    #pragma unroll
    for (int j4=0;j4<TN/4;j4++){
      float4 v = make_float4(acc[i][j4*4+0],acc[i][j4*4+1],acc[i][j4*4+2],acc[i][j4*4+3]);
      *(float4*)&part[(((size_t)ks*M + row))*BN + tx*TN + j4*4] = v;
    }
  }
}

// partial-reduce + bias + leaky + t3 projection, one wave per selected row
__global__ __launch_bounds__(256) void k_final_wave(
    const float* __restrict__ part, const float* __restrict__ t2b,
    const float* __restrict__ t3w, const float* __restrict__ t3b,
    float* __restrict__ outp)
{
  int w = (blockIdx.x*256 + threadIdx.x) >> 6;
  int j = threadIdx.x & 63;
  if (w >= NSEL) return;
  float v = 0.f;
  #pragma unroll
  for (int s=0;s<KS2;s++) v += part[((size_t)s*NSEL + w)*64 + j];
  v += t2b[j];
  v = leaky1(v);
  float a0 = v*t3w[j], a1 = v*t3w[64+j];
  #pragma unroll
  for (int sft=32;sft>0;sft>>=1){
    a0 += __shfl_down(a0,(unsigned)sft);
    a1 += __shfl_down(a1,(unsigned)sft);
  }
  if (j==0){
    outp[2*w+0] = a0 + t3b[0];
    outp[2*w+1] = a1 + t3b[1];
  }
}

// ---------- per-node gate scores (bf16 input, us2-vectorized) ----------
template<int D>
__global__ __launch_bounds__(256) void k_scores_bf(const unsigned short* __restrict__ X,
    const float* __restrict__ g0, const float* __restrict__ g1, const float* __restrict__ g2,
    float* __restrict__ sd, float* __restrict__ ss){
  int w = (blockIdx.x*256 + threadIdx.x) >> 6;
  int lane = threadIdx.x & 63;
  if (w >= NN) return;
  const unsigned short* x = X + (size_t)w*D;
  float a0=0,a1=0,a2=0,a3=0,a4=0,a5=0;
  #pragma unroll
  for (int kb=0; kb<D; kb+=128){
    int k = kb + lane*2;
    ushort2 u = *(const ushort2*)&x[k];
    float v0 = b2f(u.x), v1 = b2f(u.y);
    float2 w0 = *(const float2*)&g0[k];   float2 w0b = *(const float2*)&g0[D+k];
    float2 w1 = *(const float2*)&g1[k];   float2 w1b = *(const float2*)&g1[D+k];
    float2 w2 = *(const float2*)&g2[k];   float2 w2b = *(const float2*)&g2[D+k];
    a0 = fmaf(v0,w0.x, fmaf(v1,w0.y, a0));  a1 = fmaf(v0,w0b.x, fmaf(v1,w0b.y, a1));
    a2 = fmaf(v0,w1.x, fmaf(v1,w1.y, a2));  a3 = fmaf(v0,w1b.x, fmaf(v1,w1b.y, a3));
    a4 = fmaf(v0,w2.x, fmaf(v1,w2.y, a4));  a5 = fmaf(v0,w2b.x, fmaf(v1,w2b.y, a5));
  }
  #pragma unroll
  for (int s=32;s>0;s>>=1){
    a0 += __shfl_down(a0,(unsigned)s); a1 += __shfl_down(a1,(unsigned)s);
    a2 += __shfl_down(a2,(unsigned)s); a3 += __shfl_down(a3,(unsigned)s);
    a4 += __shfl_down(a4,(unsigned)s); a5 += __shfl_down(a5,(unsigned)s);
  }
  if (lane==0){
    sd[0*NN+w]=a0; ss[0*NN+w]=a1;
    sd[1*NN+w]=a2; ss[1*NN+w]=a3;
    sd[2*NN+w]=a4; ss[2*NN+w]=a5;
  }
}

// ---------- layer-1 aggregation: GROUP(16)-PER-NODE ----------
// 16-lane group owns one (node, rel): full 128-col accumulator in 8 regs/lane.
// No cross-group reduction. 4 groups/wave process 4 nodes concurrently.
__global__ __launch_bounds__(256) void k_gather_f3w2(const float* __restrict__ Xf,
    const unsigned short* __restrict__ Xb,
    const int* __restrict__ off, const int* __restrict__ csrc,
    const float* __restrict__ sd, const float* __restrict__ ss,
    const float* __restrict__ dnv,
    const float* __restrict__ gb0, const float* __restrict__ gb1, const float* __restrict__ gb2,
    unsigned short* __restrict__ outp){
  const int tid = threadIdx.x;
  const int lane = tid & 63;
  const int wg = lane >> 4;          // group within wave
  const int p  = lane & 15;          // lane within group
  const int n = blockIdx.x*16 + (tid >> 4);
  const int r = blockIdx.y;
  const int* offr = off + r*(NN+1);
  const int* csr  = csrc + (size_t)r*NE;
  const float* ssr = ss + r*NN;
  const float* dnr = dnv + r*NN;
  float gbv = ((r==0)?gb0:((r==1)?gb1:gb2))[0];
  float sd_n = sd[r*NN + n], dn_n = dnr[n];
  float acc[8];
  #pragma unroll
  for (int i=0;i<8;i++) acc[i]=0.f;
  int p0 = offr[n], p1 = offr[n+1];
  for (int pc=p0; pc<p1; pc+=16){
    int m = min(16, p1-pc);
    int s = 0; float c = 0.f;
    if (p < m){
      s = csr[pc+p];
      c = tanhf(sd_n + ssr[s] + gbv) * dn_n * dnr[s];
    }
    for (int j=0;j<m;j++){
      int   sj = __shfl(s, wg*16+j);
      float cj = __shfl(c, wg*16+j);
      us8 v = *(const us8*)&Xb[(size_t)sj*HID + p*8];
      #pragma unroll
      for (int i=0;i<8;i++) acc[i] = fmaf(cj, b2f(v[i]), acc[i]);
    }
  }
  const float4 r0 = *(const float4*)&Xf[(size_t)n*HID + p*8];
  const float4 r1 = *(const float4*)&Xf[(size_t)n*HID + p*8 + 4];
  acc[0] = fmaf(EPSF, r0.x, acc[0]); acc[1] = fmaf(EPSF, r0.y, acc[1]);
  acc[2] = fmaf(EPSF, r0.z, acc[2]); acc[3] = fmaf(EPSF, r0.w, acc[3]);
  acc[4] = fmaf(EPSF, r1.x, acc[4]); acc[5] = fmaf(EPSF, r1.y, acc[5]);
  acc[6] = fmaf(EPSF, r1.z, acc[6]); acc[7] = fmaf(EPSF, r1.w, acc[7]);
  us8 o;
  #pragma unroll
  for (int i=0;i<8;i++) o[i] = f2b(acc[i]);
  *(us8*)&outp[((size_t)r*NN + n)*HID + p*8] = o;
}

// ---------- layer-2 selected aggregation: group-per-node, D=384, bf16 out ----------
__global__ __launch_bounds__(256) void k_gather_sel3w2(const unsigned short* __restrict__ Xb,
    const int* __restrict__ nodes,
    const int* __restrict__ off, const int* __restrict__ csrc,
    const float* __restrict__ sd, const float* __restrict__ ss,
    const float* __restrict__ dnv,
    const float* __restrict__ gb0, const float* __restrict__ gb1, const float* __restrict__ gb2,
    unsigned short* __restrict__ outp){
  const int tid = threadIdx.x;
  const int lane = tid & 63;
  const int wg = lane >> 4;
  const int p  = lane & 15;
  const int i = blockIdx.x*16 + (tid >> 4);
  const int r = blockIdx.y;
  const int n = nodes[i];
  const int* offr = off + r*(NN+1);
  const int* csr  = csrc + (size_t)r*NE;
  const float* ssr = ss + r*NN;
  const float* dnr = dnv + r*NN;
  float gbv = ((r==0)?gb0:((r==1)?gb1:gb2))[0];
  float sd_n = sd[r*NN + n], dn_n = dnr[n];
  float acc[3][8];
  #pragma unroll
  for (int cc=0;cc<3;cc++)
    #pragma unroll
    for (int q=0;q<8;q++) acc[cc][q]=0.f;
  int p0 = offr[n], p1 = offr[n+1];
  for (int pc=p0; pc<p1; pc+=16){
    int m = min(16, p1-pc);
    int s = 0; float c = 0.f;
    if (p < m){
      s = csr[pc+p];
      c = tanhf(sd_n + ssr[s] + gbv) * dn_n * dnr[s];
    }
    for (int j=0;j<m;j++){
      int   sj = __shfl(s, wg*16+j);
      float cj = __shfl(c, wg*16+j);
      const unsigned short* row = &Xb[(size_t)sj*H3];
      #pragma unroll
      for (int cc=0;cc<3;cc++){
        us8 v = *(const us8*)&row[cc*HID + p*8];
        #pragma unroll
        for (int q=0;q<8;q++) acc[cc][q] = fmaf(cj, b2f(v[q]), acc[cc][q]);
      }
    }
  }
  const unsigned short* xrow = &Xb[(size_t)n*H3];
  unsigned short* orow = &outp[((size_t)r*NSEL + i)*H3];
  #pragma unroll
  for (int cc=0;cc<3;cc++){
    us8 v = *(const us8*)&xrow[cc*HID + p*8];
    us8 o;
    #pragma unroll
    for (int q=0;q<8;q++) o[q] = f2b(fmaf(EPSF, b2f(v[q]), acc[cc][q]));
    *(us8*)&orow[cc*HID + p*8] = o;
  }
}

// ---------- gather raw0/raw1/raw2 rows into nf (float4-vectorized) ----------
__global__ __launch_bounds__(192) void k_nf_fill(const float* __restrict__ h,
    const float* __restrict__ raw1, const unsigned short* __restrict__ raw2b,
    const int* __restrict__ nodes, float* __restrict__ nf){
  int i = blockIdx.x;
  int n = nodes[i];
  int t = threadIdx.x;
  if (t >= 144) return;
  float4 v; int col4;
  if (t < 16){
    v = ((const float4*)&h[(size_t)n*IND])[t];       col4 = 96 + t;
  } else if (t < 48){
    int q = t-16;
    v = ((const float4*)&raw1[(size_t)n*HID])[q];    col4 = 112 + q;
  } else {
    int q = t-48;
    ushort4 u = ((const ushort4*)&raw2b[(size_t)n*H3])[q];
    v = make_float4(b2f(u.x), b2f(u.y), b2f(u.z), b2f(u.w));
    col4 = 144 + q;
  }
  ((float4*)&nf[(size_t)i*FDIM])[col4] = v;
}

extern "C" void kernel_launch(void* const* d_in, const int* in_sizes, int n_in,
                              void* d_out, int out_size, void* d_ws, size_t ws_size,
                              hipStream_t stream){
  if (n_in < 32) return;
  const float* h = (const float*)d_in[0];
  const int* src[3] = {(const int*)d_in[1], (const int*)d_in[3], (const int*)d_in[5]};
  const int* dst[3] = {(const int*)d_in[2], (const int*)d_in[4], (const int*)d_in[6]};
  const int* nodes = (const int*)d_in[7];
  const float* t1w = (const float*)d_in[8];
  const float* t1b = (const float*)d_in[9];

  bool dictOrder = (in_sizes[12] == 768);
  const float *g1w[3],*g1b[3],*g2w[3],*g2b[3],*hw1[3],*hw2[3];
  for (int r=0;r<3;r++){
    if (dictOrder){
      int base = 10 + r*6;
      g1w[r]=(const float*)d_in[base+0]; g1b[r]=(const float*)d_in[base+1];
      g2w[r]=(const float*)d_in[base+2]; g2b[r]=(const float*)d_in[base+3];
      hw1[r]=(const float*)d_in[base+4]; hw2[r]=(const float*)d_in[base+5];
    } else {
      g1w[r]=(const float*)d_in[10+2*r]; g1b[r]=(const float*)d_in[11+2*r];
      g2w[r]=(const float*)d_in[16+2*r]; g2b[r]=(const float*)d_in[17+2*r];
      hw1[r]=(const float*)d_in[22+r];   hw2[r]=(const float*)d_in[25+r];
    }
  }
  const float* t2w = (const float*)d_in[28];
  const float* t2b = (const float*)d_in[29];
  const float* t3w = (const float*)d_in[30];
  const float* t3b = (const float*)d_in[31];
  float* outp = (float*)d_out;

  // workspace carve (~150 MB)
  char* w = (char*)d_ws;
  auto carve = [&](size_t bytes)->void*{
    void* p = (void*)w;
    w += ((bytes + 255) & ~size_t(255));
    return p;
  };
  int*   deg  = (int*)  carve((size_t)(3*NN+1024)*4);  // deg[3N] + bcnt[3*NBK], one memset
  int*   bcnt = deg + 3*NN;
  int*   off  = (int*)  carve((size_t)3*(NN+1)*4);
  float* dnv  = (float*)carve((size_t)3*NN*4);
  int*   bsum = (int*)  carve((size_t)128*4);
  int*   csrc = (int*)  carve((size_t)3*NE*4);
  float* sd1  = (float*)carve((size_t)3*NN*4);
  float* ss1  = (float*)carve((size_t)3*NN*4);
  float* sd2  = (float*)carve((size_t)3*NN*4);
  float* ss2  = (float*)carve((size_t)3*NN*4);
  unsigned short* wt1 = (unsigned short*)carve((size_t)HID*IND*2);
  unsigned short* w1t = (unsigned short*)carve((size_t)3*HID*HID*2);
  unsigned short* w2t = (unsigned short*)carve((size_t)3*HID*H3*2);
  unsigned short* hb  = (unsigned short*)carve((size_t)NN*IND*2);
  float* raw1 = (float*)carve((size_t)NN*HID*4);
  unsigned short* raw1b = (unsigned short*)carve((size_t)NN*HID*2);
  unsigned short* raw2b = (unsigned short*)carve((size_t)NN*H3*2);
  // union region (38.4MB): pairbuf[3*NBK*BCAP int2] | pre1b bf16 [3][NN][HID] |
  //   { pre2b bf16 [3][NSEL][H3] @0  +  t2p f32 [KS2][NSEL][64] @24MB }
  size_t ubytes = (size_t)3*NN*HID*2;
  float* ureg = (float*)carve(ubytes);
  int2* pairbuf = (int2*)ureg;
  unsigned short* pre1b = (unsigned short*)ureg;
  unsigned short* pre2b = (unsigned short*)ureg;
  float* t2p = (float*)((char*)ureg + (size_t)24*1024*1024);
  float* nf   = (float*)carve((size_t)NSEL*FDIM*4);

  hipMemsetAsync(deg, 0, (size_t)(3*NN+1024)*4, stream);
  k_bfill2<<<dim3((NE+EPB-1)/EPB, 3), 256, 0, stream>>>(
      src[0],dst[0],src[1],dst[1],src[2],dst[2], deg, bcnt, pairbuf);
  k_scan_a<<<3*NCHUNK, 256, 0, stream>>>(deg, off, bsum, dnv);
  k_scan_b<<<1, 64, 0, stream>>>(bsum);
  k_scan_c<<<3*NCHUNK, 256, 0, stream>>>(off, bsum);
  k_bsort2<<<dim3(NBK,3), 256, 0, stream>>>(pairbuf, bcnt, off, csrc);

  k_cast_h<<<(NN*IND/8 + 255)/256, 256, 0, stream>>>(h, hb);
  k_wprep_all<<<(8192 + 3*16384 + 3*49152 + 255)/256, 256, 0, stream>>>(
      t1w, hw1[0], hw1[1], hw1[2], hw2[0], hw2[1], hw2[2], wt1, w1t, w2t);

  // raw1 = leaky(h @ t1_w^T + t1_b)  via bf16 MFMA (f32 + bf16 out)
  k_mfma_t1<<<(NN+63)/64, 256, 0, stream>>>(hb, wt1, t1b, raw1, raw1b);

  k_scores_bf<HID><<<(NN+3)/4, 256, 0, stream>>>(raw1b, g1w[0], g1w[1], g1w[2], sd1, ss1);

  // layer-1 gathers (group-per-node, 3 relations batched) + bf16 MFMA hw1
  k_gather_f3w2<<<dim3(NN/16, 3), 256, 0, stream>>>(raw1, raw1b, off, csrc,
      sd1, ss1, dnv, g1b[0], g1b[1], g1b[2], pre1b);
  k_mfma128<<<dim3((NN+63)/64, 3), 256, 0, stream>>>(pre1b, w1t, raw2b, NN);

  k_scores_bf<H3><<<(NN+3)/4, 256, 0, stream>>>(raw2b, g2w[0], g2w[1], g2w[2], sd2, ss2);

  // layer-2 selected gather (group-per-node) -> bf16 pre2
  k_gather_sel3w2<<<dim3(NSEL/16, 3), 256, 0, stream>>>(raw2b, nodes, off, csrc,
      sd2, ss2, dnv, g2b[0], g2b[1], g2b[2], pre2b);

  // hw2 via bf16 MFMA -> nf cols [0,384)
  k_mfma384<<<dim3(NSEL/32, 3), 256, 0, stream>>>(pre2b, w2t, nf);

  k_nf_fill<<<NSEL, 192, 0, stream>>>(h, raw1, raw2b, nodes, nf);

  // t2 split-K x10 partials then fused reduce + leaky + t3
  k_sk<64,64,32,4,4><<<dim3(KS2, NSEL/64), 256, 0, stream>>>(
      nf, FDIM, NSEL, KCH2, t2w, FDIM, t2p);
  k_final_wave<<<(NSEL*64+255)/256, 256, 0, stream>>>(t2p, t2b, t3w, t3b, outp);
}

// Round 8
// 252.291 us; speedup vs baseline: 3.6309x; 1.1343x over previous
//
#include <hip/hip_runtime.h>
#include <hip/hip_bf16.h>

#define NN 50000
#define NE 400000
#define IND 64
#define HID 128
#define H3 384
#define FDIM 960
#define NSEL 4096
#define EPSF 0.3f
#define SLOPEF 0.3f
#define SCHUNK 2048
#define NCHUNK 25          // ceil(NN/SCHUNK)
#define NBK 196            // ceil(NN/256) dst-buckets per relation
#define BCAP 4096          // fixed bucket capacity (mean 2048, sigma 45)
#define EPB 8192           // edges per block in k_bfill2

typedef __attribute__((ext_vector_type(8))) short bfrag;   // 8 bf16 (4 VGPR)
typedef __attribute__((ext_vector_type(4))) float f4;
typedef __attribute__((ext_vector_type(8))) unsigned short us8;

__device__ __forceinline__ float leaky1(float v){ return v>=0.f? v : SLOPEF*v; }
__device__ __forceinline__ float b2f(unsigned short u){
  return __uint_as_float(((unsigned)u)<<16);
}
__device__ __forceinline__ unsigned short f2b(float v){
  __hip_bfloat16 b = __float2bfloat16(v);
  return *(unsigned short*)&b;
}

// ---------- fused degree + bucketed fill (packed u32 pairs) ----------
__global__ __launch_bounds__(256) void k_bfill2(
    const int* __restrict__ s0,const int* __restrict__ d0,
    const int* __restrict__ s1,const int* __restrict__ d1,
    const int* __restrict__ s2,const int* __restrict__ d2,
    int* __restrict__ deg, int* __restrict__ bcnt,
    unsigned int* __restrict__ pairbuf)
{
  __shared__ int hist[NBK];
  __shared__ int cur[NBK];
  __shared__ int gbase[NBK];
  const int r = blockIdx.y;
  const int* S = (r==0)?s0:((r==1)?s1:s2);
  const int* D = (r==0)?d0:((r==1)?d1:d2);
  const int e0 = blockIdx.x*EPB;
  const int t = threadIdx.x;
  for (int i=t; i<NBK; i+=256){ hist[i]=0; cur[i]=0; }
  __syncthreads();
  unsigned int pv[EPB/256];
  #pragma unroll
  for (int j=0;j<EPB/256;j++){
    int e = e0 + j*256 + t;
    if (e < NE){
      int s = S[e], d = D[e];
      pv[j] = ((unsigned)d<<16) | (unsigned)s;
      atomicAdd(&deg[r*NN + d], 1);
      atomicAdd(&hist[d>>8], 1);
    }
  }
  __syncthreads();
  if (t < NBK){
    int h = hist[t];
    gbase[t] = (h>0) ? atomicAdd(&bcnt[r*NBK+t], h) : 0;
  }
  __syncthreads();
  #pragma unroll
  for (int j=0;j<EPB/256;j++){
    int e = e0 + j*256 + t;
    if (e < NE){
      int b = (int)(pv[j] >> 24);      // dst>>8
      int pos = atomicAdd(&cur[b], 1);
      pairbuf[((size_t)(r*NBK + b))*BCAP + gbase[b] + pos] = pv[j];
    }
  }
}

// ---------- 3-phase parallel scan (75 blocks), fused dnorm ----------
__global__ __launch_bounds__(256) void k_scan_a(const int* __restrict__ deg,
    int* __restrict__ off, int* __restrict__ bsum, float* __restrict__ dnv){
  int b = blockIdx.x;
  int r = b / NCHUNK, c = b - r*NCHUNK;
  const int* dg = deg + r*NN;
  int* o = off + r*(NN+1);
  int t = threadIdx.x;
  int base = c*SCHUNK + t*8;
  int v[8];
  #pragma unroll
  for (int j=0;j<8;j++){
    int i = base+j;
    int g = (i<NN)? dg[i] : 0;
    v[j] = g;
    if (i<NN) dnv[r*NN+i] = (g>0)? rsqrtf((float)g) : 0.f;
  }
  int s=0;
  #pragma unroll
  for (int j=0;j<8;j++){ s += v[j]; v[j] = s; }
  int lane = t & 63, wid = t >> 6;
  int x = s;
  #pragma unroll
  for (int d=1; d<64; d<<=1){ int y=__shfl_up(x,(unsigned)d); if(lane>=d) x+=y; }
  __shared__ int ws[4];
  if (lane==63) ws[wid]=x;
  __syncthreads();
  int wpre = 0;
  if (wid>0) wpre += ws[0];
  if (wid>1) wpre += ws[1];
  if (wid>2) wpre += ws[2];
  int excl = wpre + x - s;
  #pragma unroll
  for (int j=0;j<8;j++){ int i=base+j; if (i<NN) o[i+1] = excl + v[j]; }
  if (t==255) bsum[b] = wpre + x;
}

__global__ void k_scan_b(int* __restrict__ bsum){
  int r = threadIdx.x;
  if (r < 3){
    int run = 0;
    for (int c=0;c<NCHUNK;c++){
      int t = bsum[r*NCHUNK+c];
      bsum[r*NCHUNK+c] = run;
      run += t;
    }
  }
}

__global__ __launch_bounds__(256) void k_scan_c(int* __restrict__ off,
                                                const int* __restrict__ bsum){
  int b = blockIdx.x;
  int r = b / NCHUNK, c = b - r*NCHUNK;
  int add = bsum[b];
  int* o = off + r*(NN+1);
  if (threadIdx.x==0 && c==0) o[0]=0;
  int base = c*SCHUNK;
  for (int j=threadIdx.x; j<SCHUNK; j+=256){
    int i = base+j;
    if (i<NN) o[i+1] += add;
  }
}

// ---------- bucket sort -> compact CSR (u16 csrc) ----------
__global__ __launch_bounds__(256) void k_bsort2(const unsigned int* __restrict__ pairbuf,
                                                const int* __restrict__ bcnt,
                                                const int* __restrict__ off,
                                                unsigned short* __restrict__ csrc){
  __shared__ int cur2[256];
  int r = blockIdx.y, b = blockIdx.x;
  int nb0 = b << 8;
  const int* offr = off + r*(NN+1);
  cur2[threadIdx.x] = 0;
  __syncthreads();
  int cnt = bcnt[r*NBK + b];
  const unsigned int* pb = pairbuf + ((size_t)(r*NBK + b))*BCAP;
  for (int e = (int)threadIdx.x; e < cnt; e += 256){
    unsigned int pv = pb[e];
    int dd = (int)(pv >> 16);
    int slot = atomicAdd(&cur2[dd - nb0], 1);
    csrc[(size_t)r*NE + offr[dd] + slot] = (unsigned short)(pv & 0xffffu);
  }
}

// ---------- all weight preps + h-cast (one kernel) ----------
__global__ void k_wprep2(const float* __restrict__ t1w,
    const float* __restrict__ hw1_0, const float* __restrict__ hw1_1, const float* __restrict__ hw1_2,
    const float* __restrict__ hw2_0, const float* __restrict__ hw2_1, const float* __restrict__ hw2_2,
    const float* __restrict__ t2w, const float* __restrict__ h,
    unsigned short* __restrict__ wt1, unsigned short* __restrict__ w1t,
    unsigned short* __restrict__ w2t, unsigned short* __restrict__ wt2,
    unsigned short* __restrict__ hb){
  int t = blockIdx.x*256 + threadIdx.x;
  if (t < 8192){                              // t1w [128][64] = [n][k]
    wt1[t] = f2b(t1w[t]);
  } else if (t < 57344){                      // hw1 [k=128][n=128] -> [r][n][k]
    int e = t - 8192;
    int r = e / 16384, q = e - r*16384;
    int n = q >> 7, k = q & 127;
    const float* W = (r==0)?hw1_0:((r==1)?hw1_1:hw1_2);
    w1t[e] = f2b(W[k*HID + n]);
  } else if (t < 204800){                     // hw2 [k=384][n=128] -> [r][n][k]
    int e = t - 57344;
    int r = e / 49152, q = e - r*49152;
    int n = q / H3, k = q - n*H3;
    const float* W = (r==0)?hw2_0:((r==1)?hw2_1:hw2_2);
    w2t[e] = f2b(W[k*HID + n]);
  } else if (t < 266240){                     // t2w [64][960] = [n][k]
    int e = t - 204800;
    wt2[e] = f2b(t2w[e]);
  } else if (t < 666240){                     // h cast: one us8 chunk each
    int q = t - 266240;
    const float4 a = ((const float4*)h)[q*2];
    const float4 b = ((const float4*)h)[q*2+1];
    us8 o;
    o[0]=f2b(a.x); o[1]=f2b(a.y); o[2]=f2b(a.z); o[3]=f2b(a.w);
    o[4]=f2b(b.x); o[5]=f2b(b.y); o[6]=f2b(b.z); o[7]=f2b(b.w);
    *(us8*)&hb[q*8] = o;
  }
}

// ---------- t1 MFMA: raw1b = leaky(hb @ wt1^T + t1b) (bf16 out only) ----------
__global__ __launch_bounds__(256) void k_mfma_t1(
    const unsigned short* __restrict__ Ab, const unsigned short* __restrict__ W,
    const float* __restrict__ bias, unsigned short* __restrict__ Cb)
{
  __shared__ short As[64][72];
  __shared__ short Bs[128][72];
  const int tid = threadIdx.x;
  const int bm = blockIdx.x*64;

  for (int q = tid; q < 64*8; q += 256){
    int row = q >> 3, c8 = q & 7;
    int grow = bm + row; grow = (grow < NN) ? grow : (NN-1);
    *(us8*)&As[row][c8*8] = *(const us8*)&Ab[(size_t)grow*IND + c8*8];
  }
  for (int q = tid; q < 128*8; q += 256){
    int n = q >> 3, c8 = q & 7;
    *(us8*)&Bs[n][c8*8] = *(const us8*)&W[n*IND + c8*8];
  }
  __syncthreads();

  const int wid = tid >> 6, lane = tid & 63;
  const int wrow = (wid & 1)*32, wcol = (wid >> 1)*64;
  const int fr = lane & 15, fq = lane >> 4;
  f4 acc[2][4];
  #pragma unroll
  for (int mi=0;mi<2;mi++)
    #pragma unroll
    for (int ni=0;ni<4;ni++) acc[mi][ni] = (f4){0.f,0.f,0.f,0.f};

  #pragma unroll
  for (int ks=0; ks<2; ks++){
    int kb = ks*32 + fq*8;
    bfrag a[2], b[4];
    #pragma unroll
    for (int mi=0;mi<2;mi++) a[mi] = *(const bfrag*)&As[wrow + mi*16 + fr][kb];
    #pragma unroll
    for (int ni=0;ni<4;ni++) b[ni] = *(const bfrag*)&Bs[wcol + ni*16 + fr][kb];
    #pragma unroll
    for (int mi=0;mi<2;mi++)
      #pragma unroll
      for (int ni=0;ni<4;ni++)
        acc[mi][ni] = __builtin_amdgcn_mfma_f32_16x16x32_bf16(a[mi], b[ni], acc[mi][ni], 0, 0, 0);
  }

  #pragma unroll
  for (int mi=0;mi<2;mi++){
    int row0 = bm + wrow + mi*16 + fq*4;
    #pragma unroll
    for (int j=0;j<4;j++){
      int row = row0 + j;
      if (row < NN){
        #pragma unroll
        for (int ni=0;ni<4;ni++){
          int col = wcol + ni*16 + fr;
          Cb[(size_t)row*HID + col] = f2b(leaky1(acc[mi][ni][j] + bias[col]));
        }
      }
    }
  }
}

// ---------- batched bf16 MFMA: raw2b[:, r*128..] = leaky(pre1b[r] @ hw1[r]) ----------
__global__ __launch_bounds__(256) void k_mfma128(
    const unsigned short* __restrict__ Abf, const unsigned short* __restrict__ Wt,
    unsigned short* __restrict__ Cb, int M)
{
  __shared__ short As[64][136];
  __shared__ short Bs[128][136];
  const int r = blockIdx.y;
  const unsigned short* Ar = Abf + (size_t)r*M*HID;
  const unsigned short* W  = Wt + (size_t)r*HID*HID;
  const int tid = threadIdx.x;
  const int bm = blockIdx.x*64;

  for (int q = tid; q < 64*16; q += 256){
    int row = q >> 4, c8 = q & 15;
    int grow = bm + row; grow = (grow < M) ? grow : (M-1);
    *(us8*)&As[row][c8*8] = *(const us8*)&Ar[(size_t)grow*HID + c8*8];
  }
  for (int q = tid; q < 128*16; q += 256){
    int n = q >> 4, c8 = q & 15;
    *(us8*)&Bs[n][c8*8] = *(const us8*)&W[n*HID + c8*8];
  }
  __syncthreads();

  const int wid = tid >> 6, lane = tid & 63;
  const int wrow = (wid & 1)*32, wcol = (wid >> 1)*64;
  const int fr = lane & 15, fq = lane >> 4;
  f4 acc[2][4];
  #pragma unroll
  for (int mi=0;mi<2;mi++)
    #pragma unroll
    for (int ni=0;ni<4;ni++) acc[mi][ni] = (f4){0.f,0.f,0.f,0.f};

  #pragma unroll
  for (int ks=0; ks<4; ks++){
    int kb = ks*32 + fq*8;
    bfrag a[2], b[4];
    #pragma unroll
    for (int mi=0;mi<2;mi++) a[mi] = *(const bfrag*)&As[wrow + mi*16 + fr][kb];
    #pragma unroll
    for (int ni=0;ni<4;ni++) b[ni] = *(const bfrag*)&Bs[wcol + ni*16 + fr][kb];
    #pragma unroll
    for (int mi=0;mi<2;mi++)
      #pragma unroll
      for (int ni=0;ni<4;ni++)
        acc[mi][ni] = __builtin_amdgcn_mfma_f32_16x16x32_bf16(a[mi], b[ni], acc[mi][ni], 0, 0, 0);
  }

  const int coff = r*HID;
  #pragma unroll
  for (int mi=0;mi<2;mi++){
    int row0 = bm + wrow + mi*16 + fq*4;
    #pragma unroll
    for (int j=0;j<4;j++){
      int row = row0 + j;
      if (row < M){
        #pragma unroll
        for (int ni=0;ni<4;ni++){
          Cb[(size_t)row*H3 + coff + wcol + ni*16 + fr] = f2b(leaky1(acc[mi][ni][j]));
        }
      }
    }
  }
}

// ---------- hw2 MFMA: nfb[:, r*128..] = leaky(pre2b[r] @ hw2[r]), K=384, bf16 out ----------
__global__ __launch_bounds__(256) void k_mfma384(
    const unsigned short* __restrict__ Abf, const unsigned short* __restrict__ Wt,
    unsigned short* __restrict__ nfb)
{
  __shared__ short As[32][72];
  __shared__ short Bs[128][72];
  const int r = blockIdx.y;
  const unsigned short* Ar = Abf + (size_t)r*NSEL*H3;
  const unsigned short* W  = Wt + (size_t)r*HID*H3;
  const int tid = threadIdx.x;
  const int bm = blockIdx.x*32;
  const int wid = tid >> 6, lane = tid & 63;
  const int fr = lane & 15, fq = lane >> 4;
  f4 acc[2][2];
  #pragma unroll
  for (int mi=0;mi<2;mi++)
    #pragma unroll
    for (int ni=0;ni<2;ni++) acc[mi][ni] = (f4){0.f,0.f,0.f,0.f};

  for (int kc=0; kc<6; kc++){
    for (int q = tid; q < 32*8; q += 256){
      int row = q >> 3, c8 = q & 7;
      *(us8*)&As[row][c8*8] = *(const us8*)&Ar[(size_t)(bm+row)*H3 + kc*64 + c8*8];
    }
    for (int q = tid; q < 128*8; q += 256){
      int n = q >> 3, c8 = q & 7;
      *(us8*)&Bs[n][c8*8] = *(const us8*)&W[(size_t)n*H3 + kc*64 + c8*8];
    }
    __syncthreads();
    #pragma unroll
    for (int ks=0; ks<2; ks++){
      int kb = ks*32 + fq*8;
      bfrag a[2], b[2];
      #pragma unroll
      for (int mi=0;mi<2;mi++) a[mi] = *(const bfrag*)&As[mi*16 + fr][kb];
      #pragma unroll
      for (int ni=0;ni<2;ni++) b[ni] = *(const bfrag*)&Bs[wid*32 + ni*16 + fr][kb];
      #pragma unroll
      for (int mi=0;mi<2;mi++)
        #pragma unroll
        for (int ni=0;ni<2;ni++)
          acc[mi][ni] = __builtin_amdgcn_mfma_f32_16x16x32_bf16(a[mi], b[ni], acc[mi][ni], 0, 0, 0);
    }
    __syncthreads();
  }

  #pragma unroll
  for (int mi=0;mi<2;mi++){
    int row0 = bm + mi*16 + fq*4;
    #pragma unroll
    for (int j=0;j<4;j++){
      int i = row0 + j;
      #pragma unroll
      for (int ni=0;ni<2;ni++){
        int col = wid*32 + ni*16 + fr;
        nfb[(size_t)i*FDIM + r*HID + col] = f2b(leaky1(acc[mi][ni][j]));
      }
    }
  }
}

// ---------- t2 MFMA: sbuf = nfb @ wt2^T (f32 raw, K=960) ----------
__global__ __launch_bounds__(256) void k_mfma_t2(
    const unsigned short* __restrict__ Abf, const unsigned short* __restrict__ W,
    float* __restrict__ sbuf)
{
  __shared__ short As[32][72];
  __shared__ short Bs[64][72];
  const int tid = threadIdx.x;
  const int bm = blockIdx.x*32;
  const int wid = tid >> 6, lane = tid & 63;
  const int fr = lane & 15, fq = lane >> 4;
  f4 acc[2];
  acc[0] = (f4){0.f,0.f,0.f,0.f};
  acc[1] = (f4){0.f,0.f,0.f,0.f};

  for (int kc=0; kc<15; kc++){
    for (int q = tid; q < 32*8; q += 256){
      int row = q >> 3, c8 = q & 7;
      *(us8*)&As[row][c8*8] = *(const us8*)&Abf[(size_t)(bm+row)*FDIM + kc*64 + c8*8];
    }
    for (int q = tid; q < 64*8; q += 256){
      int n = q >> 3, c8 = q & 7;
      *(us8*)&Bs[n][c8*8] = *(const us8*)&W[(size_t)n*FDIM + kc*64 + c8*8];
    }
    __syncthreads();
    #pragma unroll
    for (int ks=0; ks<2; ks++){
      int kb = ks*32 + fq*8;
      bfrag a[2], b;
      a[0] = *(const bfrag*)&As[fr][kb];
      a[1] = *(const bfrag*)&As[16 + fr][kb];
      b = *(const bfrag*)&Bs[wid*16 + fr][kb];
      acc[0] = __builtin_amdgcn_mfma_f32_16x16x32_bf16(a[0], b, acc[0], 0, 0, 0);
      acc[1] = __builtin_amdgcn_mfma_f32_16x16x32_bf16(a[1], b, acc[1], 0, 0, 0);
    }
    __syncthreads();
  }

  #pragma unroll
  for (int mi=0;mi<2;mi++){
    int row0 = bm + mi*16 + fq*4;
    #pragma unroll
    for (int j=0;j<4;j++){
      sbuf[(size_t)(row0+j)*64 + wid*16 + fr] = acc[mi][j];
    }
  }
}

// bias + leaky + t3 projection, one wave per selected row
__global__ __launch_bounds__(256) void k_final_wave(
    const float* __restrict__ sbuf, const float* __restrict__ t2b,
    const float* __restrict__ t3w, const float* __restrict__ t3b,
    float* __restrict__ outp)
{
  int w = (blockIdx.x*256 + threadIdx.x) >> 6;
  int j = threadIdx.x & 63;
  if (w >= NSEL) return;
  float v = leaky1(sbuf[(size_t)w*64 + j] + t2b[j]);
  float a0 = v*t3w[j], a1 = v*t3w[64+j];
  #pragma unroll
  for (int sft=32;sft>0;sft>>=1){
    a0 += __shfl_down(a0,(unsigned)sft);
    a1 += __shfl_down(a1,(unsigned)sft);
  }
  if (j==0){
    outp[2*w+0] = a0 + t3b[0];
    outp[2*w+1] = a1 + t3b[1];
  }
}

// ---------- per-node gate scores: group(16)-per-node, us8 loads ----------
template<int D>
__global__ __launch_bounds__(256) void k_scores_g(const unsigned short* __restrict__ X,
    const float* __restrict__ g0, const float* __restrict__ g1, const float* __restrict__ g2,
    float* __restrict__ sd, float* __restrict__ ss){
  const int tid = threadIdx.x;
  const int p = tid & 15;
  const int n = blockIdx.x*16 + (tid >> 4);
  const unsigned short* x = X + (size_t)n*D;
  float a0=0,a1=0,a2=0,a3=0,a4=0,a5=0;
  #pragma unroll
  for (int it=0; it<D/128; it++){
    int k = it*128 + p*8;
    us8 u = *(const us8*)&x[k];
    #pragma unroll
    for (int e=0;e<8;e++){
      float v = b2f(u[e]);
      a0 = fmaf(v, g0[k+e],   a0);  a1 = fmaf(v, g0[D+k+e], a1);
      a2 = fmaf(v, g1[k+e],   a2);  a3 = fmaf(v, g1[D+k+e], a3);
      a4 = fmaf(v, g2[k+e],   a4);  a5 = fmaf(v, g2[D+k+e], a5);
    }
  }
  #pragma unroll
  for (int s=8;s>0;s>>=1){
    a0 += __shfl_xor(a0,(unsigned)s); a1 += __shfl_xor(a1,(unsigned)s);
    a2 += __shfl_xor(a2,(unsigned)s); a3 += __shfl_xor(a3,(unsigned)s);
    a4 += __shfl_xor(a4,(unsigned)s); a5 += __shfl_xor(a5,(unsigned)s);
  }
  if (p==0){
    sd[0*NN+n]=a0; ss[0*NN+n]=a1;
    sd[1*NN+n]=a2; ss[1*NN+n]=a3;
    sd[2*NN+n]=a4; ss[2*NN+n]=a5;
  }
}

// ---------- layer-1 aggregation: group(16)-per-node, 3 rels fused ----------
__global__ __launch_bounds__(256) void k_gather_f3z(
    const unsigned short* __restrict__ Xb,
    const int* __restrict__ off, const unsigned short* __restrict__ csrc,
    const float* __restrict__ sd, const float* __restrict__ ss,
    const float* __restrict__ dnv,
    const float* __restrict__ gb0, const float* __restrict__ gb1, const float* __restrict__ gb2,
    unsigned short* __restrict__ outp){
  const int tid = threadIdx.x;
  const int lane = tid & 63;
  const int wg = lane >> 4;
  const int p  = lane & 15;
  const int n = blockIdx.x*16 + (tid >> 4);
  // residual from bf16 (output is bf16-rounded anyway)
  us8 rv = *(const us8*)&Xb[(size_t)n*HID + p*8];
  float resid[8];
  #pragma unroll
  for (int i=0;i<8;i++) resid[i] = EPSF * b2f(rv[i]);

  for (int r=0;r<3;r++){
    const int* offr = off + r*(NN+1);
    const unsigned short* csr = csrc + (size_t)r*NE;
    const float* ssr = ss + r*NN;
    const float* dnr = dnv + r*NN;
    float gbv = ((r==0)?gb0:((r==1)?gb1:gb2))[0];
    float sd_n = sd[r*NN + n], dn_n = dnr[n];
    float acc[8];
    #pragma unroll
    for (int i=0;i<8;i++) acc[i] = resid[i];
    int p0 = offr[n], p1 = offr[n+1];
    for (int pc=p0; pc<p1; pc+=16){
      int m = min(16, p1-pc);
      int s = 0; float c = 0.f;
      if (p < m){
        s = csr[pc+p];
        c = tanhf(sd_n + ssr[s] + gbv) * dn_n * dnr[s];
      }
      for (int j=0;j<m;j++){
        int   sj = __shfl(s, wg*16+j);
        float cj = __shfl(c, wg*16+j);
        us8 v = *(const us8*)&Xb[(size_t)sj*HID + p*8];
        #pragma unroll
        for (int i=0;i<8;i++) acc[i] = fmaf(cj, b2f(v[i]), acc[i]);
      }
    }
    us8 o;
    #pragma unroll
    for (int i=0;i<8;i++) o[i] = f2b(acc[i]);
    *(us8*)&outp[((size_t)r*NN + n)*HID + p*8] = o;
  }
}

// ---------- layer-2 selected aggregation: group-per-node, D=384, bf16 out ----------
__global__ __launch_bounds__(256) void k_gather_sel3w2(const unsigned short* __restrict__ Xb,
    const int* __restrict__ nodes,
    const int* __restrict__ off, const unsigned short* __restrict__ csrc,
    const float* __restrict__ sd, const float* __restrict__ ss,
    const float* __restrict__ dnv,
    const float* __restrict__ gb0, const float* __restrict__ gb1, const float* __restrict__ gb2,
    unsigned short* __restrict__ outp){
  const int tid = threadIdx.x;
  const int lane = tid & 63;
  const int wg = lane >> 4;
  const int p  = lane & 15;
  const int i = blockIdx.x*16 + (tid >> 4);
  const int r = blockIdx.y;
  const int n = nodes[i];
  const int* offr = off + r*(NN+1);
  const unsigned short* csr = csrc + (size_t)r*NE;
  const float* ssr = ss + r*NN;
  const float* dnr = dnv + r*NN;
  float gbv = ((r==0)?gb0:((r==1)?gb1:gb2))[0];
  float sd_n = sd[r*NN + n], dn_n = dnr[n];
  float acc[3][8];
  #pragma unroll
  for (int cc=0;cc<3;cc++)
    #pragma unroll
    for (int q=0;q<8;q++) acc[cc][q]=0.f;
  int p0 = offr[n], p1 = offr[n+1];
  for (int pc=p0; pc<p1; pc+=16){
    int m = min(16, p1-pc);
    int s = 0; float c = 0.f;
    if (p < m){
      s = csr[pc+p];
      c = tanhf(sd_n + ssr[s] + gbv) * dn_n * dnr[s];
    }
    for (int j=0;j<m;j++){
      int   sj = __shfl(s, wg*16+j);
      float cj = __shfl(c, wg*16+j);
      const unsigned short* row = &Xb[(size_t)sj*H3];
      #pragma unroll
      for (int cc=0;cc<3;cc++){
        us8 v = *(const us8*)&row[cc*HID + p*8];
        #pragma unroll
        for (int q=0;q<8;q++) acc[cc][q] = fmaf(cj, b2f(v[q]), acc[cc][q]);
      }
    }
  }
  const unsigned short* xrow = &Xb[(size_t)n*H3];
  unsigned short* orow = &outp[((size_t)r*NSEL + i)*H3];
  #pragma unroll
  for (int cc=0;cc<3;cc++){
    us8 v = *(const us8*)&xrow[cc*HID + p*8];
    us8 o;
    #pragma unroll
    for (int q=0;q<8;q++) o[q] = f2b(fmaf(EPSF, b2f(v[q]), acc[cc][q]));
    *(us8*)&orow[cc*HID + p*8] = o;
  }
}

// ---------- gather hb/raw1b/raw2b rows into nfb (pure u16 copies) ----------
__global__ __launch_bounds__(256) void k_nf_fillb(const unsigned short* __restrict__ hb,
    const unsigned short* __restrict__ raw1b, const unsigned short* __restrict__ raw2b,
    const int* __restrict__ nodes, unsigned short* __restrict__ nfb){
  int t = blockIdx.x*256 + threadIdx.x;
  if (t >= NSEL*72) return;
  int i = t/72, c = t - i*72;
  int n = nodes[i];
  us8 v; int col;
  if (c < 8)       { v = *(const us8*)&hb[(size_t)n*IND + c*8];           col = 384 + c*8; }
  else if (c < 24) { int q=c-8;  v = *(const us8*)&raw1b[(size_t)n*HID + q*8]; col = 448 + q*8; }
  else             { int q=c-24; v = *(const us8*)&raw2b[(size_t)n*H3  + q*8]; col = 576 + q*8; }
  *(us8*)&nfb[(size_t)i*FDIM + col] = v;
}

extern "C" void kernel_launch(void* const* d_in, const int* in_sizes, int n_in,
                              void* d_out, int out_size, void* d_ws, size_t ws_size,
                              hipStream_t stream){
  if (n_in < 32) return;
  const float* h = (const float*)d_in[0];
  const int* src[3] = {(const int*)d_in[1], (const int*)d_in[3], (const int*)d_in[5]};
  const int* dst[3] = {(const int*)d_in[2], (const int*)d_in[4], (const int*)d_in[6]};
  const int* nodes = (const int*)d_in[7];
  const float* t1w = (const float*)d_in[8];
  const float* t1b = (const float*)d_in[9];

  bool dictOrder = (in_sizes[12] == 768);
  const float *g1w[3],*g1b[3],*g2w[3],*g2b[3],*hw1[3],*hw2[3];
  for (int r=0;r<3;r++){
    if (dictOrder){
      int base = 10 + r*6;
      g1w[r]=(const float*)d_in[base+0]; g1b[r]=(const float*)d_in[base+1];
      g2w[r]=(const float*)d_in[base+2]; g2b[r]=(const float*)d_in[base+3];
      hw1[r]=(const float*)d_in[base+4]; hw2[r]=(const float*)d_in[base+5];
    } else {
      g1w[r]=(const float*)d_in[10+2*r]; g1b[r]=(const float*)d_in[11+2*r];
      g2w[r]=(const float*)d_in[16+2*r]; g2b[r]=(const float*)d_in[17+2*r];
      hw1[r]=(const float*)d_in[22+r];   hw2[r]=(const float*)d_in[25+r];
    }
  }
  const float* t2w = (const float*)d_in[28];
  const float* t2b = (const float*)d_in[29];
  const float* t3w = (const float*)d_in[30];
  const float* t3b = (const float*)d_in[31];
  float* outp = (float*)d_out;

  // workspace carve (~115 MB)
  char* w = (char*)d_ws;
  auto carve = [&](size_t bytes)->void*{
    void* p = (void*)w;
    w += ((bytes + 255) & ~size_t(255));
    return p;
  };
  int*   deg  = (int*)  carve((size_t)(3*NN+1024)*4);  // deg[3N] + bcnt[3*NBK]
  int*   bcnt = deg + 3*NN;
  int*   off  = (int*)  carve((size_t)3*(NN+1)*4);
  float* dnv  = (float*)carve((size_t)3*NN*4);
  int*   bsum = (int*)  carve((size_t)128*4);
  unsigned short* csrc = (unsigned short*)carve((size_t)3*NE*2);
  float* sd1  = (float*)carve((size_t)3*NN*4);
  float* ss1  = (float*)carve((size_t)3*NN*4);
  float* sd2  = (float*)carve((size_t)3*NN*4);
  float* ss2  = (float*)carve((size_t)3*NN*4);
  unsigned short* wt1 = (unsigned short*)carve((size_t)HID*IND*2);
  unsigned short* w1t = (unsigned short*)carve((size_t)3*HID*HID*2);
  unsigned short* w2t = (unsigned short*)carve((size_t)3*HID*H3*2);
  unsigned short* wt2 = (unsigned short*)carve((size_t)64*FDIM*2);
  unsigned short* hb  = (unsigned short*)carve((size_t)NN*IND*2);
  unsigned short* raw1b = (unsigned short*)carve((size_t)NN*HID*2);
  unsigned short* raw2b = (unsigned short*)carve((size_t)NN*H3*2);
  // union region (38.4MB): pairbuf u32 [3*NBK*BCAP] (9.6MB) | pre1b [3][NN][HID] |
  //   { pre2b [3][NSEL][H3] (9.4MB) @0  +  sbuf f32 [NSEL][64] (1MB) @16MB }
  size_t ubytes = (size_t)3*NN*HID*2;
  float* ureg = (float*)carve(ubytes);
  unsigned int* pairbuf = (unsigned int*)ureg;
  unsigned short* pre1b = (unsigned short*)ureg;
  unsigned short* pre2b = (unsigned short*)ureg;
  float* sbuf = (float*)((char*)ureg + (size_t)16*1024*1024);
  unsigned short* nfb = (unsigned short*)carve((size_t)NSEL*FDIM*2);

  hipMemsetAsync(deg, 0, (size_t)(3*NN+1024)*4, stream);
  k_bfill2<<<dim3((NE+EPB-1)/EPB, 3), 256, 0, stream>>>(
      src[0],dst[0],src[1],dst[1],src[2],dst[2], deg, bcnt, pairbuf);
  k_scan_a<<<3*NCHUNK, 256, 0, stream>>>(deg, off, bsum, dnv);
  k_scan_b<<<1, 64, 0, stream>>>(bsum);
  k_scan_c<<<3*NCHUNK, 256, 0, stream>>>(off, bsum);
  k_bsort2<<<dim3(NBK,3), 256, 0, stream>>>(pairbuf, bcnt, off, csrc);

  k_wprep2<<<(666240+255)/256, 256, 0, stream>>>(
      t1w, hw1[0], hw1[1], hw1[2], hw2[0], hw2[1], hw2[2], t2w, h,
      wt1, w1t, w2t, wt2, hb);

  // raw1b = leaky(hb @ t1w^T + t1b)
  k_mfma_t1<<<(NN+63)/64, 256, 0, stream>>>(hb, wt1, t1b, raw1b);

  k_scores_g<HID><<<NN/16, 256, 0, stream>>>(raw1b, g1w[0], g1w[1], g1w[2], sd1, ss1);

  // layer-1 gather (group-per-node, 3 rels fused) + hw1 MFMA
  k_gather_f3z<<<NN/16, 256, 0, stream>>>(raw1b, off, csrc,
      sd1, ss1, dnv, g1b[0], g1b[1], g1b[2], pre1b);
  k_mfma128<<<dim3((NN+63)/64, 3), 256, 0, stream>>>(pre1b, w1t, raw2b, NN);

  k_scores_g<H3><<<NN/16, 256, 0, stream>>>(raw2b, g2w[0], g2w[1], g2w[2], sd2, ss2);

  // layer-2 selected gather -> bf16 pre2
  k_gather_sel3w2<<<dim3(NSEL/16, 3), 256, 0, stream>>>(raw2b, nodes, off, csrc,
      sd2, ss2, dnv, g2b[0], g2b[1], g2b[2], pre2b);

  // hw2 MFMA -> nfb cols [0,384)
  k_mfma384<<<dim3(NSEL/32, 3), 256, 0, stream>>>(pre2b, w2t, nfb);

  k_nf_fillb<<<(NSEL*72+255)/256, 256, 0, stream>>>(hb, raw1b, raw2b, nodes, nfb);

  // t2 MFMA (K=960) -> sbuf, then fused bias+leaky+t3
  k_mfma_t2<<<NSEL/32, 256, 0, stream>>>(nfb, wt2, sbuf);
  k_final_wave<<<(NSEL*64+255)/256, 256, 0, stream>>>(sbuf, t2b, t3w, t3b, outp);
}

// Round 9
// 249.244 us; speedup vs baseline: 3.6752x; 1.0122x over previous
//
#include <hip/hip_runtime.h>
#include <hip/hip_bf16.h>

#define NN 50000
#define NE 400000
#define IND 64
#define HID 128
#define H3 384
#define FDIM 960
#define NSEL 4096
#define EPSF 0.3f
#define SLOPEF 0.3f
#define SCHUNK 2048
#define NCHUNK 25          // ceil(NN/SCHUNK)
#define NBK 196            // ceil(NN/256) dst-buckets per relation
#define BCAP 4096          // fixed bucket capacity (mean 2048, sigma 45)
#define EPB 4096           // edges per block in k_bfill3
#define NOEDGE 0xFFFFFFFFu

typedef __attribute__((ext_vector_type(8))) short bfrag;   // 8 bf16 (4 VGPR)
typedef __attribute__((ext_vector_type(4))) float f4;
typedef __attribute__((ext_vector_type(8))) unsigned short us8;

__device__ __forceinline__ float leaky1(float v){ return v>=0.f? v : SLOPEF*v; }
__device__ __forceinline__ float b2f(unsigned short u){
  return __uint_as_float(((unsigned)u)<<16);
}
__device__ __forceinline__ unsigned short f2b(float v){
  __hip_bfloat16 b = __float2bfloat16(v);
  return *(unsigned short*)&b;
}

// ---------- fused degree + bucketed fill, LDS-staged (dense writes) ----------
__global__ __launch_bounds__(256) void k_bfill3(
    const int* __restrict__ s0,const int* __restrict__ d0,
    const int* __restrict__ s1,const int* __restrict__ d1,
    const int* __restrict__ s2,const int* __restrict__ d2,
    int* __restrict__ deg, int* __restrict__ bcnt,
    unsigned int* __restrict__ pairbuf)
{
  __shared__ unsigned int lbuf[EPB];     // 16 KB staging
  __shared__ int hist[256];
  __shared__ int lbase[256];
  __shared__ int lcur[256];
  __shared__ int gbase[NBK];
  __shared__ int wsum[4];
  const int r = blockIdx.y;
  const int* S = (r==0)?s0:((r==1)?s1:s2);
  const int* D = (r==0)?d0:((r==1)?d1:d2);
  const int e0 = blockIdx.x*EPB;
  const int t = threadIdx.x;
  hist[t] = 0; lcur[t] = 0;
  __syncthreads();

  // load 16 edges/thread as int4 pairs (NE % 4 == 0)
  unsigned int pv[16];
  #pragma unroll
  for (int j=0;j<4;j++){
    int e = e0 + (j*256 + t)*4;
    if (e < NE){
      int4 sv = *(const int4*)&S[e];
      int4 dv = *(const int4*)&D[e];
      pv[j*4+0] = ((unsigned)dv.x<<16)|(unsigned)sv.x;
      pv[j*4+1] = ((unsigned)dv.y<<16)|(unsigned)sv.y;
      pv[j*4+2] = ((unsigned)dv.z<<16)|(unsigned)sv.z;
      pv[j*4+3] = ((unsigned)dv.w<<16)|(unsigned)sv.w;
    } else {
      pv[j*4+0]=NOEDGE; pv[j*4+1]=NOEDGE; pv[j*4+2]=NOEDGE; pv[j*4+3]=NOEDGE;
    }
  }
  #pragma unroll
  for (int i=0;i<16;i++){
    if (pv[i] != NOEDGE){
      int d = (int)(pv[i] >> 16);
      atomicAdd(&deg[r*NN + d], 1);
      atomicAdd(&hist[d>>8], 1);
    }
  }
  __syncthreads();
  // block-local exclusive prefix scan of hist[0..255]
  {
    int hv = hist[t];
    int lane = t & 63, wid = t >> 6;
    int x = hv;
    #pragma unroll
    for (int d=1; d<64; d<<=1){ int y=__shfl_up(x,(unsigned)d); if(lane>=d) x+=y; }
    if (lane==63) wsum[wid]=x;
    __syncthreads();
    int wpre = 0;
    if (wid>0) wpre += wsum[0];
    if (wid>1) wpre += wsum[1];
    if (wid>2) wpre += wsum[2];
    lbase[t] = wpre + x - hv;
    if (t < NBK){
      int hh = hist[t];
      gbase[t] = (hh>0) ? atomicAdd(&bcnt[r*NBK+t], hh) : 0;
    }
  }
  __syncthreads();
  // scatter to LDS (bucket-sorted within block)
  #pragma unroll
  for (int i=0;i<16;i++){
    if (pv[i] != NOEDGE){
      int b = (int)(pv[i] >> 24);
      int pos = lbase[b] + atomicAdd(&lcur[b], 1);
      lbuf[pos] = pv[i];
    }
  }
  __syncthreads();
  // stream out: consecutive idx within a bucket run -> consecutive global dst
  int tot = min(NE - e0, EPB);
  for (int idx = t; idx < tot; idx += 256){
    unsigned int v = lbuf[idx];
    int b = (int)(v >> 24);
    pairbuf[((size_t)(r*NBK + b))*BCAP + gbase[b] + (idx - lbase[b])] = v;
  }
}

// ---------- 3-phase parallel scan (75 blocks), fused dnorm ----------
__global__ __launch_bounds__(256) void k_scan_a(const int* __restrict__ deg,
    int* __restrict__ off, int* __restrict__ bsum, float* __restrict__ dnv){
  int b = blockIdx.x;
  int r = b / NCHUNK, c = b - r*NCHUNK;
  const int* dg = deg + r*NN;
  int* o = off + r*(NN+1);
  int t = threadIdx.x;
  int base = c*SCHUNK + t*8;
  int v[8];
  #pragma unroll
  for (int j=0;j<8;j++){
    int i = base+j;
    int g = (i<NN)? dg[i] : 0;
    v[j] = g;
    if (i<NN) dnv[r*NN+i] = (g>0)? rsqrtf((float)g) : 0.f;
  }
  int s=0;
  #pragma unroll
  for (int j=0;j<8;j++){ s += v[j]; v[j] = s; }
  int lane = t & 63, wid = t >> 6;
  int x = s;
  #pragma unroll
  for (int d=1; d<64; d<<=1){ int y=__shfl_up(x,(unsigned)d); if(lane>=d) x+=y; }
  __shared__ int ws[4];
  if (lane==63) ws[wid]=x;
  __syncthreads();
  int wpre = 0;
  if (wid>0) wpre += ws[0];
  if (wid>1) wpre += ws[1];
  if (wid>2) wpre += ws[2];
  int excl = wpre + x - s;
  #pragma unroll
  for (int j=0;j<8;j++){ int i=base+j; if (i<NN) o[i+1] = excl + v[j]; }
  if (t==255) bsum[b] = wpre + x;
}

__global__ void k_scan_b(int* __restrict__ bsum){
  int r = threadIdx.x;
  if (r < 3){
    int run = 0;
    for (int c=0;c<NCHUNK;c++){
      int t = bsum[r*NCHUNK+c];
      bsum[r*NCHUNK+c] = run;
      run += t;
    }
  }
}

__global__ __launch_bounds__(256) void k_scan_c(int* __restrict__ off,
                                                const int* __restrict__ bsum){
  int b = blockIdx.x;
  int r = b / NCHUNK, c = b - r*NCHUNK;
  int add = bsum[b];
  int* o = off + r*(NN+1);
  if (threadIdx.x==0 && c==0) o[0]=0;
  int base = c*SCHUNK;
  for (int j=threadIdx.x; j<SCHUNK; j+=256){
    int i = base+j;
    if (i<NN) o[i+1] += add;
  }
}

// ---------- bucket sort -> compact CSR (u16), LDS-staged dense writes ----------
__global__ __launch_bounds__(256) void k_bsort3(const unsigned int* __restrict__ pairbuf,
                                                const int* __restrict__ bcnt,
                                                const int* __restrict__ off,
                                                unsigned short* __restrict__ csrc){
  __shared__ unsigned short lout[BCAP];   // 8 KB
  __shared__ int cur2[256];
  __shared__ int nbase[256];
  int r = blockIdx.y, b = blockIdx.x;
  int nb0 = b << 8;
  const int* offr = off + r*(NN+1);
  int t = threadIdx.x;
  cur2[t] = 0;
  int e0g = offr[nb0];
  int nidx = nb0 + t;
  nbase[t] = (nidx < NN) ? (offr[nidx] - e0g) : 0;
  __syncthreads();
  int cnt = bcnt[r*NBK + b];
  const unsigned int* pb = pairbuf + ((size_t)(r*NBK + b))*BCAP;
  for (int e = t; e < cnt; e += 256){
    unsigned int pv = pb[e];
    int p = (int)(pv >> 16) - nb0;
    int slot = atomicAdd(&cur2[p], 1);
    lout[nbase[p] + slot] = (unsigned short)(pv & 0xffffu);
  }
  __syncthreads();
  unsigned short* op = csrc + (size_t)r*NE + e0g;
  for (int idx = t; idx < cnt; idx += 256) op[idx] = lout[idx];
}

// ---------- all weight preps + h-cast (one kernel) ----------
__global__ void k_wprep2(const float* __restrict__ t1w,
    const float* __restrict__ hw1_0, const float* __restrict__ hw1_1, const float* __restrict__ hw1_2,
    const float* __restrict__ hw2_0, const float* __restrict__ hw2_1, const float* __restrict__ hw2_2,
    const float* __restrict__ t2w, const float* __restrict__ h,
    unsigned short* __restrict__ wt1, unsigned short* __restrict__ w1t,
    unsigned short* __restrict__ w2t, unsigned short* __restrict__ wt2,
    unsigned short* __restrict__ hb){
  int t = blockIdx.x*256 + threadIdx.x;
  if (t < 8192){                              // t1w [128][64] = [n][k]
    wt1[t] = f2b(t1w[t]);
  } else if (t < 57344){                      // hw1 [k=128][n=128] -> [r][n][k]
    int e = t - 8192;
    int r = e / 16384, q = e - r*16384;
    int n = q >> 7, k = q & 127;
    const float* W = (r==0)?hw1_0:((r==1)?hw1_1:hw1_2);
    w1t[e] = f2b(W[k*HID + n]);
  } else if (t < 204800){                     // hw2 [k=384][n=128] -> [r][n][k]
    int e = t - 57344;
    int r = e / 49152, q = e - r*49152;
    int n = q / H3, k = q - n*H3;
    const float* W = (r==0)?hw2_0:((r==1)?hw2_1:hw2_2);
    w2t[e] = f2b(W[k*HID + n]);
  } else if (t < 266240){                     // t2w [64][960] = [n][k]
    int e = t - 204800;
    wt2[e] = f2b(t2w[e]);
  } else if (t < 666240){                     // h cast: one us8 chunk each
    int q = t - 266240;
    const float4 a = ((const float4*)h)[q*2];
    const float4 b = ((const float4*)h)[q*2+1];
    us8 o;
    o[0]=f2b(a.x); o[1]=f2b(a.y); o[2]=f2b(a.z); o[3]=f2b(a.w);
    o[4]=f2b(b.x); o[5]=f2b(b.y); o[6]=f2b(b.z); o[7]=f2b(b.w);
    *(us8*)&hb[q*8] = o;
  }
}

// ---------- t1 MFMA: raw1b = leaky(hb @ wt1^T + t1b) (bf16 out only) ----------
__global__ __launch_bounds__(256) void k_mfma_t1(
    const unsigned short* __restrict__ Ab, const unsigned short* __restrict__ W,
    const float* __restrict__ bias, unsigned short* __restrict__ Cb)
{
  __shared__ short As[64][72];
  __shared__ short Bs[128][72];
  const int tid = threadIdx.x;
  const int bm = blockIdx.x*64;

  for (int q = tid; q < 64*8; q += 256){
    int row = q >> 3, c8 = q & 7;
    int grow = bm + row; grow = (grow < NN) ? grow : (NN-1);
    *(us8*)&As[row][c8*8] = *(const us8*)&Ab[(size_t)grow*IND + c8*8];
  }
  for (int q = tid; q < 128*8; q += 256){
    int n = q >> 3, c8 = q & 7;
    *(us8*)&Bs[n][c8*8] = *(const us8*)&W[n*IND + c8*8];
  }
  __syncthreads();

  const int wid = tid >> 6, lane = tid & 63;
  const int wrow = (wid & 1)*32, wcol = (wid >> 1)*64;
  const int fr = lane & 15, fq = lane >> 4;
  f4 acc[2][4];
  #pragma unroll
  for (int mi=0;mi<2;mi++)
    #pragma unroll
    for (int ni=0;ni<4;ni++) acc[mi][ni] = (f4){0.f,0.f,0.f,0.f};

  #pragma unroll
  for (int ks=0; ks<2; ks++){
    int kb = ks*32 + fq*8;
    bfrag a[2], b[4];
    #pragma unroll
    for (int mi=0;mi<2;mi++) a[mi] = *(const bfrag*)&As[wrow + mi*16 + fr][kb];
    #pragma unroll
    for (int ni=0;ni<4;ni++) b[ni] = *(const bfrag*)&Bs[wcol + ni*16 + fr][kb];
    #pragma unroll
    for (int mi=0;mi<2;mi++)
      #pragma unroll
      for (int ni=0;ni<4;ni++)
        acc[mi][ni] = __builtin_amdgcn_mfma_f32_16x16x32_bf16(a[mi], b[ni], acc[mi][ni], 0, 0, 0);
  }

  #pragma unroll
  for (int mi=0;mi<2;mi++){
    int row0 = bm + wrow + mi*16 + fq*4;
    #pragma unroll
    for (int j=0;j<4;j++){
      int row = row0 + j;
      if (row < NN){
        #pragma unroll
        for (int ni=0;ni<4;ni++){
          int col = wcol + ni*16 + fr;
          Cb[(size_t)row*HID + col] = f2b(leaky1(acc[mi][ni][j] + bias[col]));
        }
      }
    }
  }
}

// ---------- batched bf16 MFMA: raw2b[:, r*128..] = leaky(pre1b[r] @ hw1[r]) ----------
__global__ __launch_bounds__(256) void k_mfma128(
    const unsigned short* __restrict__ Abf, const unsigned short* __restrict__ Wt,
    unsigned short* __restrict__ Cb, int M)
{
  __shared__ short As[64][136];
  __shared__ short Bs[128][136];
  const int r = blockIdx.y;
  const unsigned short* Ar = Abf + (size_t)r*M*HID;
  const unsigned short* W  = Wt + (size_t)r*HID*HID;
  const int tid = threadIdx.x;
  const int bm = blockIdx.x*64;

  for (int q = tid; q < 64*16; q += 256){
    int row = q >> 4, c8 = q & 15;
    int grow = bm + row; grow = (grow < M) ? grow : (M-1);
    *(us8*)&As[row][c8*8] = *(const us8*)&Ar[(size_t)grow*HID + c8*8];
  }
  for (int q = tid; q < 128*16; q += 256){
    int n = q >> 4, c8 = q & 15;
    *(us8*)&Bs[n][c8*8] = *(const us8*)&W[n*HID + c8*8];
  }
  __syncthreads();

  const int wid = tid >> 6, lane = tid & 63;
  const int wrow = (wid & 1)*32, wcol = (wid >> 1)*64;
  const int fr = lane & 15, fq = lane >> 4;
  f4 acc[2][4];
  #pragma unroll
  for (int mi=0;mi<2;mi++)
    #pragma unroll
    for (int ni=0;ni<4;ni++) acc[mi][ni] = (f4){0.f,0.f,0.f,0.f};

  #pragma unroll
  for (int ks=0; ks<4; ks++){
    int kb = ks*32 + fq*8;
    bfrag a[2], b[4];
    #pragma unroll
    for (int mi=0;mi<2;mi++) a[mi] = *(const bfrag*)&As[wrow + mi*16 + fr][kb];
    #pragma unroll
    for (int ni=0;ni<4;ni++) b[ni] = *(const bfrag*)&Bs[wcol + ni*16 + fr][kb];
    #pragma unroll
    for (int mi=0;mi<2;mi++)
      #pragma unroll
      for (int ni=0;ni<4;ni++)
        acc[mi][ni] = __builtin_amdgcn_mfma_f32_16x16x32_bf16(a[mi], b[ni], acc[mi][ni], 0, 0, 0);
  }

  const int coff = r*HID;
  #pragma unroll
  for (int mi=0;mi<2;mi++){
    int row0 = bm + wrow + mi*16 + fq*4;
    #pragma unroll
    for (int j=0;j<4;j++){
      int row = row0 + j;
      if (row < M){
        #pragma unroll
        for (int ni=0;ni<4;ni++){
          Cb[(size_t)row*H3 + coff + wcol + ni*16 + fr] = f2b(leaky1(acc[mi][ni][j]));
        }
      }
    }
  }
}

// ---------- hw2 MFMA: nfb[:, r*128..] = leaky(pre2b[r] @ hw2[r]), K=384, bf16 out ----------
__global__ __launch_bounds__(256) void k_mfma384(
    const unsigned short* __restrict__ Abf, const unsigned short* __restrict__ Wt,
    unsigned short* __restrict__ nfb)
{
  __shared__ short As[32][72];
  __shared__ short Bs[128][72];
  const int r = blockIdx.y;
  const unsigned short* Ar = Abf + (size_t)r*NSEL*H3;
  const unsigned short* W  = Wt + (size_t)r*HID*H3;
  const int tid = threadIdx.x;
  const int bm = blockIdx.x*32;
  const int wid = tid >> 6, lane = tid & 63;
  const int fr = lane & 15, fq = lane >> 4;
  f4 acc[2][2];
  #pragma unroll
  for (int mi=0;mi<2;mi++)
    #pragma unroll
    for (int ni=0;ni<2;ni++) acc[mi][ni] = (f4){0.f,0.f,0.f,0.f};

  for (int kc=0; kc<6; kc++){
    for (int q = tid; q < 32*8; q += 256){
      int row = q >> 3, c8 = q & 7;
      *(us8*)&As[row][c8*8] = *(const us8*)&Ar[(size_t)(bm+row)*H3 + kc*64 + c8*8];
    }
    for (int q = tid; q < 128*8; q += 256){
      int n = q >> 3, c8 = q & 7;
      *(us8*)&Bs[n][c8*8] = *(const us8*)&W[(size_t)n*H3 + kc*64 + c8*8];
    }
    __syncthreads();
    #pragma unroll
    for (int ks=0; ks<2; ks++){
      int kb = ks*32 + fq*8;
      bfrag a[2], b[2];
      #pragma unroll
      for (int mi=0;mi<2;mi++) a[mi] = *(const bfrag*)&As[mi*16 + fr][kb];
      #pragma unroll
      for (int ni=0;ni<2;ni++) b[ni] = *(const bfrag*)&Bs[wid*32 + ni*16 + fr][kb];
      #pragma unroll
      for (int mi=0;mi<2;mi++)
        #pragma unroll
        for (int ni=0;ni<2;ni++)
          acc[mi][ni] = __builtin_amdgcn_mfma_f32_16x16x32_bf16(a[mi], b[ni], acc[mi][ni], 0, 0, 0);
    }
    __syncthreads();
  }

  #pragma unroll
  for (int mi=0;mi<2;mi++){
    int row0 = bm + mi*16 + fq*4;
    #pragma unroll
    for (int j=0;j<4;j++){
      int i = row0 + j;
      #pragma unroll
      for (int ni=0;ni<2;ni++){
        int col = wid*32 + ni*16 + fr;
        nfb[(size_t)i*FDIM + r*HID + col] = f2b(leaky1(acc[mi][ni][j]));
      }
    }
  }
}

// ---------- t2 MFMA: sbuf = nfb @ wt2^T (f32 raw, K=960) ----------
__global__ __launch_bounds__(256) void k_mfma_t2(
    const unsigned short* __restrict__ Abf, const unsigned short* __restrict__ W,
    float* __restrict__ sbuf)
{
  __shared__ short As[32][72];
  __shared__ short Bs[64][72];
  const int tid = threadIdx.x;
  const int bm = blockIdx.x*32;
  const int wid = tid >> 6, lane = tid & 63;
  const int fr = lane & 15, fq = lane >> 4;
  f4 acc[2];
  acc[0] = (f4){0.f,0.f,0.f,0.f};
  acc[1] = (f4){0.f,0.f,0.f,0.f};

  for (int kc=0; kc<15; kc++){
    for (int q = tid; q < 32*8; q += 256){
      int row = q >> 3, c8 = q & 7;
      *(us8*)&As[row][c8*8] = *(const us8*)&Abf[(size_t)(bm+row)*FDIM + kc*64 + c8*8];
    }
    for (int q = tid; q < 64*8; q += 256){
      int n = q >> 3, c8 = q & 7;
      *(us8*)&Bs[n][c8*8] = *(const us8*)&W[(size_t)n*FDIM + kc*64 + c8*8];
    }
    __syncthreads();
    #pragma unroll
    for (int ks=0; ks<2; ks++){
      int kb = ks*32 + fq*8;
      bfrag a[2], b;
      a[0] = *(const bfrag*)&As[fr][kb];
      a[1] = *(const bfrag*)&As[16 + fr][kb];
      b = *(const bfrag*)&Bs[wid*16 + fr][kb];
      acc[0] = __builtin_amdgcn_mfma_f32_16x16x32_bf16(a[0], b, acc[0], 0, 0, 0);
      acc[1] = __builtin_amdgcn_mfma_f32_16x16x32_bf16(a[1], b, acc[1], 0, 0, 0);
    }
    __syncthreads();
  }

  #pragma unroll
  for (int mi=0;mi<2;mi++){
    int row0 = bm + mi*16 + fq*4;
    #pragma unroll
    for (int j=0;j<4;j++){
      sbuf[(size_t)(row0+j)*64 + wid*16 + fr] = acc[mi][j];
    }
  }
}

// bias + leaky + t3 projection, one wave per selected row
__global__ __launch_bounds__(256) void k_final_wave(
    const float* __restrict__ sbuf, const float* __restrict__ t2b,
    const float* __restrict__ t3w, const float* __restrict__ t3b,
    float* __restrict__ outp)
{
  int w = (blockIdx.x*256 + threadIdx.x) >> 6;
  int j = threadIdx.x & 63;
  if (w >= NSEL) return;
  float v = leaky1(sbuf[(size_t)w*64 + j] + t2b[j]);
  float a0 = v*t3w[j], a1 = v*t3w[64+j];
  #pragma unroll
  for (int sft=32;sft>0;sft>>=1){
    a0 += __shfl_down(a0,(unsigned)sft);
    a1 += __shfl_down(a1,(unsigned)sft);
  }
  if (j==0){
    outp[2*w+0] = a0 + t3b[0];
    outp[2*w+1] = a1 + t3b[1];
  }
}

// ---------- per-node gate scores: group(16)-per-node, us8 loads ----------
template<int D>
__global__ __launch_bounds__(256) void k_scores_g(const unsigned short* __restrict__ X,
    const float* __restrict__ g0, const float* __restrict__ g1, const float* __restrict__ g2,
    float* __restrict__ sd, float* __restrict__ ss){
  const int tid = threadIdx.x;
  const int p = tid & 15;
  const int n = blockIdx.x*16 + (tid >> 4);
  const unsigned short* x = X + (size_t)n*D;
  float a0=0,a1=0,a2=0,a3=0,a4=0,a5=0;
  #pragma unroll
  for (int it=0; it<D/128; it++){
    int k = it*128 + p*8;
    us8 u = *(const us8*)&x[k];
    #pragma unroll
    for (int e=0;e<8;e++){
      float v = b2f(u[e]);
      a0 = fmaf(v, g0[k+e],   a0);  a1 = fmaf(v, g0[D+k+e], a1);
      a2 = fmaf(v, g1[k+e],   a2);  a3 = fmaf(v, g1[D+k+e], a3);
      a4 = fmaf(v, g2[k+e],   a4);  a5 = fmaf(v, g2[D+k+e], a5);
    }
  }
  #pragma unroll
  for (int s=8;s>0;s>>=1){
    a0 += __shfl_xor(a0,(unsigned)s); a1 += __shfl_xor(a1,(unsigned)s);
    a2 += __shfl_xor(a2,(unsigned)s); a3 += __shfl_xor(a3,(unsigned)s);
    a4 += __shfl_xor(a4,(unsigned)s); a5 += __shfl_xor(a5,(unsigned)s);
  }
  if (p==0){
    sd[0*NN+n]=a0; ss[0*NN+n]=a1;
    sd[1*NN+n]=a2; ss[1*NN+n]=a3;
    sd[2*NN+n]=a4; ss[2*NN+n]=a5;
  }
}

// ---------- layer-1 aggregation: group(16)-per-node, 3 rels fused ----------
__global__ __launch_bounds__(256) void k_gather_f3z(
    const unsigned short* __restrict__ Xb,
    const int* __restrict__ off, const unsigned short* __restrict__ csrc,
    const float* __restrict__ sd, const float* __restrict__ ss,
    const float* __restrict__ dnv,
    const float* __restrict__ gb0, const float* __restrict__ gb1, const float* __restrict__ gb2,
    unsigned short* __restrict__ outp){
  const int tid = threadIdx.x;
  const int lane = tid & 63;
  const int wg = lane >> 4;
  const int p  = lane & 15;
  const int n = blockIdx.x*16 + (tid >> 4);
  us8 rv = *(const us8*)&Xb[(size_t)n*HID + p*8];
  float resid[8];
  #pragma unroll
  for (int i=0;i<8;i++) resid[i] = EPSF * b2f(rv[i]);

  for (int r=0;r<3;r++){
    const int* offr = off + r*(NN+1);
    const unsigned short* csr = csrc + (size_t)r*NE;
    const float* ssr = ss + r*NN;
    const float* dnr = dnv + r*NN;
    float gbv = ((r==0)?gb0:((r==1)?gb1:gb2))[0];
    float sd_n = sd[r*NN + n], dn_n = dnr[n];
    float acc[8];
    #pragma unroll
    for (int i=0;i<8;i++) acc[i] = resid[i];
    int p0 = offr[n], p1 = offr[n+1];
    for (int pc=p0; pc<p1; pc+=16){
      int m = min(16, p1-pc);
      int s = 0; float c = 0.f;
      if (p < m){
        s = csr[pc+p];
        c = tanhf(sd_n + ssr[s] + gbv) * dn_n * dnr[s];
      }
      for (int j=0;j<m;j++){
        int   sj = __shfl(s, wg*16+j);
        float cj = __shfl(c, wg*16+j);
        us8 v = *(const us8*)&Xb[(size_t)sj*HID + p*8];
        #pragma unroll
        for (int i=0;i<8;i++) acc[i] = fmaf(cj, b2f(v[i]), acc[i]);
      }
    }
    us8 o;
    #pragma unroll
    for (int i=0;i<8;i++) o[i] = f2b(acc[i]);
    *(us8*)&outp[((size_t)r*NN + n)*HID + p*8] = o;
  }
}

// ---------- layer-2 selected aggregation: group-per-node, D=384, bf16 out ----------
__global__ __launch_bounds__(256) void k_gather_sel3w2(const unsigned short* __restrict__ Xb,
    const int* __restrict__ nodes,
    const int* __restrict__ off, const unsigned short* __restrict__ csrc,
    const float* __restrict__ sd, const float* __restrict__ ss,
    const float* __restrict__ dnv,
    const float* __restrict__ gb0, const float* __restrict__ gb1, const float* __restrict__ gb2,
    unsigned short* __restrict__ outp){
  const int tid = threadIdx.x;
  const int lane = tid & 63;
  const int wg = lane >> 4;
  const int p  = lane & 15;
  const int i = blockIdx.x*16 + (tid >> 4);
  const int r = blockIdx.y;
  const int n = nodes[i];
  const int* offr = off + r*(NN+1);
  const unsigned short* csr = csrc + (size_t)r*NE;
  const float* ssr = ss + r*NN;
  const float* dnr = dnv + r*NN;
  float gbv = ((r==0)?gb0:((r==1)?gb1:gb2))[0];
  float sd_n = sd[r*NN + n], dn_n = dnr[n];
  float acc[3][8];
  #pragma unroll
  for (int cc=0;cc<3;cc++)
    #pragma unroll
    for (int q=0;q<8;q++) acc[cc][q]=0.f;
  int p0 = offr[n], p1 = offr[n+1];
  for (int pc=p0; pc<p1; pc+=16){
    int m = min(16, p1-pc);
    int s = 0; float c = 0.f;
    if (p < m){
      s = csr[pc+p];
      c = tanhf(sd_n + ssr[s] + gbv) * dn_n * dnr[s];
    }
    for (int j=0;j<m;j++){
      int   sj = __shfl(s, wg*16+j);
      float cj = __shfl(c, wg*16+j);
      const unsigned short* row = &Xb[(size_t)sj*H3];
      #pragma unroll
      for (int cc=0;cc<3;cc++){
        us8 v = *(const us8*)&row[cc*HID + p*8];
        #pragma unroll
        for (int q=0;q<8;q++) acc[cc][q] = fmaf(cj, b2f(v[q]), acc[cc][q]);
      }
    }
  }
  const unsigned short* xrow = &Xb[(size_t)n*H3];
  unsigned short* orow = &outp[((size_t)r*NSEL + i)*H3];
  #pragma unroll
  for (int cc=0;cc<3;cc++){
    us8 v = *(const us8*)&xrow[cc*HID + p*8];
    us8 o;
    #pragma unroll
    for (int q=0;q<8;q++) o[q] = f2b(fmaf(EPSF, b2f(v[q]), acc[cc][q]));
    *(us8*)&orow[cc*HID + p*8] = o;
  }
}

// ---------- gather hb/raw1b/raw2b rows into nfb (pure u16 copies) ----------
__global__ __launch_bounds__(256) void k_nf_fillb(const unsigned short* __restrict__ hb,
    const unsigned short* __restrict__ raw1b, const unsigned short* __restrict__ raw2b,
    const int* __restrict__ nodes, unsigned short* __restrict__ nfb){
  int t = blockIdx.x*256 + threadIdx.x;
  if (t >= NSEL*72) return;
  int i = t/72, c = t - i*72;
  int n = nodes[i];
  us8 v; int col;
  if (c < 8)       { v = *(const us8*)&hb[(size_t)n*IND + c*8];           col = 384 + c*8; }
  else if (c < 24) { int q=c-8;  v = *(const us8*)&raw1b[(size_t)n*HID + q*8]; col = 448 + q*8; }
  else             { int q=c-24; v = *(const us8*)&raw2b[(size_t)n*H3  + q*8]; col = 576 + q*8; }
  *(us8*)&nfb[(size_t)i*FDIM + col] = v;
}

extern "C" void kernel_launch(void* const* d_in, const int* in_sizes, int n_in,
                              void* d_out, int out_size, void* d_ws, size_t ws_size,
                              hipStream_t stream){
  if (n_in < 32) return;
  const float* h = (const float*)d_in[0];
  const int* src[3] = {(const int*)d_in[1], (const int*)d_in[3], (const int*)d_in[5]};
  const int* dst[3] = {(const int*)d_in[2], (const int*)d_in[4], (const int*)d_in[6]};
  const int* nodes = (const int*)d_in[7];
  const float* t1w = (const float*)d_in[8];
  const float* t1b = (const float*)d_in[9];

  bool dictOrder = (in_sizes[12] == 768);
  const float *g1w[3],*g1b[3],*g2w[3],*g2b[3],*hw1[3],*hw2[3];
  for (int r=0;r<3;r++){
    if (dictOrder){
      int base = 10 + r*6;
      g1w[r]=(const float*)d_in[base+0]; g1b[r]=(const float*)d_in[base+1];
      g2w[r]=(const float*)d_in[base+2]; g2b[r]=(const float*)d_in[base+3];
      hw1[r]=(const float*)d_in[base+4]; hw2[r]=(const float*)d_in[base+5];
    } else {
      g1w[r]=(const float*)d_in[10+2*r]; g1b[r]=(const float*)d_in[11+2*r];
      g2w[r]=(const float*)d_in[16+2*r]; g2b[r]=(const float*)d_in[17+2*r];
      hw1[r]=(const float*)d_in[22+r];   hw2[r]=(const float*)d_in[25+r];
    }
  }
  const float* t2w = (const float*)d_in[28];
  const float* t2b = (const float*)d_in[29];
  const float* t3w = (const float*)d_in[30];
  const float* t3b = (const float*)d_in[31];
  float* outp = (float*)d_out;

  // workspace carve (~115 MB)
  char* w = (char*)d_ws;
  auto carve = [&](size_t bytes)->void*{
    void* p = (void*)w;
    w += ((bytes + 255) & ~size_t(255));
    return p;
  };
  int*   deg  = (int*)  carve((size_t)(3*NN+1024)*4);  // deg[3N] + bcnt[3*NBK]
  int*   bcnt = deg + 3*NN;
  int*   off  = (int*)  carve((size_t)3*(NN+1)*4);
  float* dnv  = (float*)carve((size_t)3*NN*4);
  int*   bsum = (int*)  carve((size_t)128*4);
  unsigned short* csrc = (unsigned short*)carve((size_t)3*NE*2);
  float* sd1  = (float*)carve((size_t)3*NN*4);
  float* ss1  = (float*)carve((size_t)3*NN*4);
  float* sd2  = (float*)carve((size_t)3*NN*4);
  float* ss2  = (float*)carve((size_t)3*NN*4);
  unsigned short* wt1 = (unsigned short*)carve((size_t)HID*IND*2);
  unsigned short* w1t = (unsigned short*)carve((size_t)3*HID*HID*2);
  unsigned short* w2t = (unsigned short*)carve((size_t)3*HID*H3*2);
  unsigned short* wt2 = (unsigned short*)carve((size_t)64*FDIM*2);
  unsigned short* hb  = (unsigned short*)carve((size_t)NN*IND*2);
  unsigned short* raw1b = (unsigned short*)carve((size_t)NN*HID*2);
  unsigned short* raw2b = (unsigned short*)carve((size_t)NN*H3*2);
  // union region (38.4MB): pairbuf u32 [3*NBK*BCAP] (9.6MB) | pre1b [3][NN][HID] |
  //   { pre2b [3][NSEL][H3] (9.4MB) @0  +  sbuf f32 [NSEL][64] (1MB) @16MB }
  size_t ubytes = (size_t)3*NN*HID*2;
  float* ureg = (float*)carve(ubytes);
  unsigned int* pairbuf = (unsigned int*)ureg;
  unsigned short* pre1b = (unsigned short*)ureg;
  unsigned short* pre2b = (unsigned short*)ureg;
  float* sbuf = (float*)((char*)ureg + (size_t)16*1024*1024);
  unsigned short* nfb = (unsigned short*)carve((size_t)NSEL*FDIM*2);

  hipMemsetAsync(deg, 0, (size_t)(3*NN+1024)*4, stream);
  k_bfill3<<<dim3((NE+EPB-1)/EPB, 3), 256, 0, stream>>>(
      src[0],dst[0],src[1],dst[1],src[2],dst[2], deg, bcnt, pairbuf);
  k_scan_a<<<3*NCHUNK, 256, 0, stream>>>(deg, off, bsum, dnv);
  k_scan_b<<<1, 64, 0, stream>>>(bsum);
  k_scan_c<<<3*NCHUNK, 256, 0, stream>>>(off, bsum);
  k_bsort3<<<dim3(NBK,3), 256, 0, stream>>>(pairbuf, bcnt, off, csrc);

  k_wprep2<<<(666240+255)/256, 256, 0, stream>>>(
      t1w, hw1[0], hw1[1], hw1[2], hw2[0], hw2[1], hw2[2], t2w, h,
      wt1, w1t, w2t, wt2, hb);

  // raw1b = leaky(hb @ t1w^T + t1b)
  k_mfma_t1<<<(NN+63)/64, 256, 0, stream>>>(hb, wt1, t1b, raw1b);

  k_scores_g<HID><<<NN/16, 256, 0, stream>>>(raw1b, g1w[0], g1w[1], g1w[2], sd1, ss1);

  // layer-1 gather (group-per-node, 3 rels fused) + hw1 MFMA
  k_gather_f3z<<<NN/16, 256, 0, stream>>>(raw1b, off, csrc,
      sd1, ss1, dnv, g1b[0], g1b[1], g1b[2], pre1b);
  k_mfma128<<<dim3((NN+63)/64, 3), 256, 0, stream>>>(pre1b, w1t, raw2b, NN);

  k_scores_g<H3><<<NN/16, 256, 0, stream>>>(raw2b, g2w[0], g2w[1], g2w[2], sd2, ss2);

  // layer-2 selected gather -> bf16 pre2
  k_gather_sel3w2<<<dim3(NSEL/16, 3), 256, 0, stream>>>(raw2b, nodes, off, csrc,
      sd2, ss2, dnv, g2b[0], g2b[1], g2b[2], pre2b);

  // hw2 MFMA -> nfb cols [0,384)
  k_mfma384<<<dim3(NSEL/32, 3), 256, 0, stream>>>(pre2b, w2t, nfb);

  k_nf_fillb<<<(NSEL*72+255)/256, 256, 0, stream>>>(hb, raw1b, raw2b, nodes, nfb);

  // t2 MFMA (K=960) -> sbuf, then fused bias+leaky+t3
  k_mfma_t2<<<NSEL/32, 256, 0, stream>>>(nfb, wt2, sbuf);
  k_final_wave<<<(NSEL*64+255)/256, 256, 0, stream>>>(sbuf, t2b, t3w, t3b, outp);
}

// Round 10
// 207.301 us; speedup vs baseline: 4.4188x; 1.2023x over previous
//
#include <hip/hip_runtime.h>
#include <hip/hip_bf16.h>

#define NN 50000
#define NE 400000
#define IND 64
#define HID 128
#define H3 384
#define FDIM 960
#define NSEL 4096
#define EPSF 0.3f
#define SLOPEF 0.3f
#define SCHUNK 2048
#define NCHUNK 25          // ceil(NN/SCHUNK)
#define NBK 196            // ceil(NN/256) dst-buckets per relation
#define BCAP 4096          // fixed bucket capacity (mean 2048, sigma 45)
#define EPB 4096           // edges per block in k_bfill4
#define NOEDGE 0xFFFFFFFFu

typedef __attribute__((ext_vector_type(8))) short bfrag;   // 8 bf16 (4 VGPR)
typedef __attribute__((ext_vector_type(4))) float f4;
typedef __attribute__((ext_vector_type(8))) unsigned short us8;

__device__ __forceinline__ float leaky1(float v){ return v>=0.f? v : SLOPEF*v; }
__device__ __forceinline__ float b2f(unsigned short u){
  return __uint_as_float(((unsigned)u)<<16);
}
__device__ __forceinline__ unsigned short f2b(float v){
  __hip_bfloat16 b = __float2bfloat16(v);
  return *(unsigned short*)&b;
}

// ---------- bucketed fill, LDS-staged, NO per-edge global atomics ----------
__global__ __launch_bounds__(256) void k_bfill4(
    const int* __restrict__ s0,const int* __restrict__ d0,
    const int* __restrict__ s1,const int* __restrict__ d1,
    const int* __restrict__ s2,const int* __restrict__ d2,
    int* __restrict__ bcnt, unsigned int* __restrict__ pairbuf)
{
  __shared__ unsigned int lbuf[EPB];     // 16 KB staging
  __shared__ int hist[256];
  __shared__ int lbase[256];
  __shared__ int lcur[256];
  __shared__ int gbase[NBK];
  __shared__ int wsum[4];
  const int r = blockIdx.y;
  const int* S = (r==0)?s0:((r==1)?s1:s2);
  const int* D = (r==0)?d0:((r==1)?d1:d2);
  const int e0 = blockIdx.x*EPB;
  const int t = threadIdx.x;
  hist[t] = 0; lcur[t] = 0;
  __syncthreads();

  // load 16 edges/thread as int4 pairs (NE % 4 == 0)
  unsigned int pv[16];
  #pragma unroll
  for (int j=0;j<4;j++){
    int e = e0 + (j*256 + t)*4;
    if (e < NE){
      int4 sv = *(const int4*)&S[e];
      int4 dv = *(const int4*)&D[e];
      pv[j*4+0] = ((unsigned)dv.x<<16)|(unsigned)sv.x;
      pv[j*4+1] = ((unsigned)dv.y<<16)|(unsigned)sv.y;
      pv[j*4+2] = ((unsigned)dv.z<<16)|(unsigned)sv.z;
      pv[j*4+3] = ((unsigned)dv.w<<16)|(unsigned)sv.w;
    } else {
      pv[j*4+0]=NOEDGE; pv[j*4+1]=NOEDGE; pv[j*4+2]=NOEDGE; pv[j*4+3]=NOEDGE;
    }
  }
  #pragma unroll
  for (int i=0;i<16;i++){
    if (pv[i] != NOEDGE){
      atomicAdd(&hist[pv[i]>>24], 1);    // LDS histogram only
    }
  }
  __syncthreads();
  // block-local exclusive prefix scan of hist[0..255]
  {
    int hv = hist[t];
    int lane = t & 63, wid = t >> 6;
    int x = hv;
    #pragma unroll
    for (int d=1; d<64; d<<=1){ int y=__shfl_up(x,(unsigned)d); if(lane>=d) x+=y; }
    if (lane==63) wsum[wid]=x;
    __syncthreads();
    int wpre = 0;
    if (wid>0) wpre += wsum[0];
    if (wid>1) wpre += wsum[1];
    if (wid>2) wpre += wsum[2];
    lbase[t] = wpre + x - hv;
    if (t < NBK){
      int hh = hist[t];
      gbase[t] = (hh>0) ? atomicAdd(&bcnt[r*NBK+t], hh) : 0;   // 1 atomic/(block,bucket)
    }
  }
  __syncthreads();
  // scatter to LDS (bucket-sorted within block)
  #pragma unroll
  for (int i=0;i<16;i++){
    if (pv[i] != NOEDGE){
      int b = (int)(pv[i] >> 24);
      int pos = lbase[b] + atomicAdd(&lcur[b], 1);
      lbuf[pos] = pv[i];
    }
  }
  __syncthreads();
  // stream out: consecutive idx within a bucket run -> consecutive global dst
  int tot = min(NE - e0, EPB);
  for (int idx = t; idx < tot; idx += 256){
    unsigned int v = lbuf[idx];
    int b = (int)(v >> 24);
    pairbuf[((size_t)(r*NBK + b))*BCAP + gbase[b] + (idx - lbase[b])] = v;
  }
}

// ---------- per-bucket degree count (dense writes, no global atomics) ----------
__global__ __launch_bounds__(256) void k_count(const unsigned int* __restrict__ pairbuf,
                                               const int* __restrict__ bcnt,
                                               int* __restrict__ deg){
  __shared__ int hist[256];
  int r = blockIdx.y, b = blockIdx.x;
  int nb0 = b << 8;
  int t = threadIdx.x;
  hist[t] = 0;
  __syncthreads();
  int cnt = bcnt[r*NBK + b];
  const unsigned int* pb = pairbuf + ((size_t)(r*NBK + b))*BCAP;
  for (int e = t; e < cnt; e += 256){
    atomicAdd(&hist[(int)(pb[e] >> 16) - nb0], 1);
  }
  __syncthreads();
  int nidx = nb0 + t;
  if (nidx < NN) deg[r*NN + nidx] = hist[t];
}

// ---------- 3-phase parallel scan (75 blocks), fused dnorm ----------
__global__ __launch_bounds__(256) void k_scan_a(const int* __restrict__ deg,
    int* __restrict__ off, int* __restrict__ bsum, float* __restrict__ dnv){
  int b = blockIdx.x;
  int r = b / NCHUNK, c = b - r*NCHUNK;
  const int* dg = deg + r*NN;
  int* o = off + r*(NN+1);
  int t = threadIdx.x;
  int base = c*SCHUNK + t*8;
  int v[8];
  #pragma unroll
  for (int j=0;j<8;j++){
    int i = base+j;
    int g = (i<NN)? dg[i] : 0;
    v[j] = g;
    if (i<NN) dnv[r*NN+i] = (g>0)? rsqrtf((float)g) : 0.f;
  }
  int s=0;
  #pragma unroll
  for (int j=0;j<8;j++){ s += v[j]; v[j] = s; }
  int lane = t & 63, wid = t >> 6;
  int x = s;
  #pragma unroll
  for (int d=1; d<64; d<<=1){ int y=__shfl_up(x,(unsigned)d); if(lane>=d) x+=y; }
  __shared__ int ws[4];
  if (lane==63) ws[wid]=x;
  __syncthreads();
  int wpre = 0;
  if (wid>0) wpre += ws[0];
  if (wid>1) wpre += ws[1];
  if (wid>2) wpre += ws[2];
  int excl = wpre + x - s;
  #pragma unroll
  for (int j=0;j<8;j++){ int i=base+j; if (i<NN) o[i+1] = excl + v[j]; }
  if (t==255) bsum[b] = wpre + x;
}

__global__ void k_scan_b(int* __restrict__ bsum){
  int r = threadIdx.x;
  if (r < 3){
    int run = 0;
    for (int c=0;c<NCHUNK;c++){
      int t = bsum[r*NCHUNK+c];
      bsum[r*NCHUNK+c] = run;
      run += t;
    }
  }
}

__global__ __launch_bounds__(256) void k_scan_c(int* __restrict__ off,
                                                const int* __restrict__ bsum){
  int b = blockIdx.x;
  int r = b / NCHUNK, c = b - r*NCHUNK;
  int add = bsum[b];
  int* o = off + r*(NN+1);
  if (threadIdx.x==0 && c==0) o[0]=0;
  int base = c*SCHUNK;
  for (int j=threadIdx.x; j<SCHUNK; j+=256){
    int i = base+j;
    if (i<NN) o[i+1] += add;
  }
}

// ---------- bucket sort -> compact CSR (u16), LDS-staged dense writes ----------
__global__ __launch_bounds__(256) void k_bsort3(const unsigned int* __restrict__ pairbuf,
                                                const int* __restrict__ bcnt,
                                                const int* __restrict__ off,
                                                unsigned short* __restrict__ csrc){
  __shared__ unsigned short lout[BCAP];   // 8 KB
  __shared__ int cur2[256];
  __shared__ int nbase[256];
  int r = blockIdx.y, b = blockIdx.x;
  int nb0 = b << 8;
  const int* offr = off + r*(NN+1);
  int t = threadIdx.x;
  cur2[t] = 0;
  int e0g = offr[nb0];
  int nidx = nb0 + t;
  nbase[t] = (nidx < NN) ? (offr[nidx] - e0g) : 0;
  __syncthreads();
  int cnt = bcnt[r*NBK + b];
  const unsigned int* pb = pairbuf + ((size_t)(r*NBK + b))*BCAP;
  for (int e = t; e < cnt; e += 256){
    unsigned int pv = pb[e];
    int p = (int)(pv >> 16) - nb0;
    int slot = atomicAdd(&cur2[p], 1);
    lout[nbase[p] + slot] = (unsigned short)(pv & 0xffffu);
  }
  __syncthreads();
  unsigned short* op = csrc + (size_t)r*NE + e0g;
  for (int idx = t; idx < cnt; idx += 256) op[idx] = lout[idx];
}

// ---------- all weight preps + h-cast (one kernel) ----------
__global__ void k_wprep2(const float* __restrict__ t1w,
    const float* __restrict__ hw1_0, const float* __restrict__ hw1_1, const float* __restrict__ hw1_2,
    const float* __restrict__ hw2_0, const float* __restrict__ hw2_1, const float* __restrict__ hw2_2,
    const float* __restrict__ t2w, const float* __restrict__ h,
    unsigned short* __restrict__ wt1, unsigned short* __restrict__ w1t,
    unsigned short* __restrict__ w2t, unsigned short* __restrict__ wt2,
    unsigned short* __restrict__ hb){
  int t = blockIdx.x*256 + threadIdx.x;
  if (t < 8192){                              // t1w [128][64] = [n][k]
    wt1[t] = f2b(t1w[t]);
  } else if (t < 57344){                      // hw1 [k=128][n=128] -> [r][n][k]
    int e = t - 8192;
    int r = e / 16384, q = e - r*16384;
    int n = q >> 7, k = q & 127;
    const float* W = (r==0)?hw1_0:((r==1)?hw1_1:hw1_2);
    w1t[e] = f2b(W[k*HID + n]);
  } else if (t < 204800){                     // hw2 [k=384][n=128] -> [r][n][k]
    int e = t - 57344;
    int r = e / 49152, q = e - r*49152;
    int n = q / H3, k = q - n*H3;
    const float* W = (r==0)?hw2_0:((r==1)?hw2_1:hw2_2);
    w2t[e] = f2b(W[k*HID + n]);
  } else if (t < 266240){                     // t2w [64][960] = [n][k]
    int e = t - 204800;
    wt2[e] = f2b(t2w[e]);
  } else if (t < 666240){                     // h cast: one us8 chunk each
    int q = t - 266240;
    const float4 a = ((const float4*)h)[q*2];
    const float4 b = ((const float4*)h)[q*2+1];
    us8 o;
    o[0]=f2b(a.x); o[1]=f2b(a.y); o[2]=f2b(a.z); o[3]=f2b(a.w);
    o[4]=f2b(b.x); o[5]=f2b(b.y); o[6]=f2b(b.z); o[7]=f2b(b.w);
    *(us8*)&hb[q*8] = o;
  }
}

// ---------- t1 MFMA: raw1b = leaky(hb @ wt1^T + t1b) (bf16 out only) ----------
__global__ __launch_bounds__(256) void k_mfma_t1(
    const unsigned short* __restrict__ Ab, const unsigned short* __restrict__ W,
    const float* __restrict__ bias, unsigned short* __restrict__ Cb)
{
  __shared__ short As[64][72];
  __shared__ short Bs[128][72];
  const int tid = threadIdx.x;
  const int bm = blockIdx.x*64;

  for (int q = tid; q < 64*8; q += 256){
    int row = q >> 3, c8 = q & 7;
    int grow = bm + row; grow = (grow < NN) ? grow : (NN-1);
    *(us8*)&As[row][c8*8] = *(const us8*)&Ab[(size_t)grow*IND + c8*8];
  }
  for (int q = tid; q < 128*8; q += 256){
    int n = q >> 3, c8 = q & 7;
    *(us8*)&Bs[n][c8*8] = *(const us8*)&W[n*IND + c8*8];
  }
  __syncthreads();

  const int wid = tid >> 6, lane = tid & 63;
  const int wrow = (wid & 1)*32, wcol = (wid >> 1)*64;
  const int fr = lane & 15, fq = lane >> 4;
  f4 acc[2][4];
  #pragma unroll
  for (int mi=0;mi<2;mi++)
    #pragma unroll
    for (int ni=0;ni<4;ni++) acc[mi][ni] = (f4){0.f,0.f,0.f,0.f};

  #pragma unroll
  for (int ks=0; ks<2; ks++){
    int kb = ks*32 + fq*8;
    bfrag a[2], b[4];
    #pragma unroll
    for (int mi=0;mi<2;mi++) a[mi] = *(const bfrag*)&As[wrow + mi*16 + fr][kb];
    #pragma unroll
    for (int ni=0;ni<4;ni++) b[ni] = *(const bfrag*)&Bs[wcol + ni*16 + fr][kb];
    #pragma unroll
    for (int mi=0;mi<2;mi++)
      #pragma unroll
      for (int ni=0;ni<4;ni++)
        acc[mi][ni] = __builtin_amdgcn_mfma_f32_16x16x32_bf16(a[mi], b[ni], acc[mi][ni], 0, 0, 0);
  }

  #pragma unroll
  for (int mi=0;mi<2;mi++){
    int row0 = bm + wrow + mi*16 + fq*4;
    #pragma unroll
    for (int j=0;j<4;j++){
      int row = row0 + j;
      if (row < NN){
        #pragma unroll
        for (int ni=0;ni<4;ni++){
          int col = wcol + ni*16 + fr;
          Cb[(size_t)row*HID + col] = f2b(leaky1(acc[mi][ni][j] + bias[col]));
        }
      }
    }
  }
}

// ---------- batched bf16 MFMA: raw2b[:, r*128..] = leaky(pre1b[r] @ hw1[r]) ----------
__global__ __launch_bounds__(256) void k_mfma128(
    const unsigned short* __restrict__ Abf, const unsigned short* __restrict__ Wt,
    unsigned short* __restrict__ Cb, int M)
{
  __shared__ short As[64][136];
  __shared__ short Bs[128][136];
  const int r = blockIdx.y;
  const unsigned short* Ar = Abf + (size_t)r*M*HID;
  const unsigned short* W  = Wt + (size_t)r*HID*HID;
  const int tid = threadIdx.x;
  const int bm = blockIdx.x*64;

  for (int q = tid; q < 64*16; q += 256){
    int row = q >> 4, c8 = q & 15;
    int grow = bm + row; grow = (grow < M) ? grow : (M-1);
    *(us8*)&As[row][c8*8] = *(const us8*)&Ar[(size_t)grow*HID + c8*8];
  }
  for (int q = tid; q < 128*16; q += 256){
    int n = q >> 4, c8 = q & 15;
    *(us8*)&Bs[n][c8*8] = *(const us8*)&W[n*HID + c8*8];
  }
  __syncthreads();

  const int wid = tid >> 6, lane = tid & 63;
  const int wrow = (wid & 1)*32, wcol = (wid >> 1)*64;
  const int fr = lane & 15, fq = lane >> 4;
  f4 acc[2][4];
  #pragma unroll
  for (int mi=0;mi<2;mi++)
    #pragma unroll
    for (int ni=0;ni<4;ni++) acc[mi][ni] = (f4){0.f,0.f,0.f,0.f};

  #pragma unroll
  for (int ks=0; ks<4; ks++){
    int kb = ks*32 + fq*8;
    bfrag a[2], b[4];
    #pragma unroll
    for (int mi=0;mi<2;mi++) a[mi] = *(const bfrag*)&As[wrow + mi*16 + fr][kb];
    #pragma unroll
    for (int ni=0;ni<4;ni++) b[ni] = *(const bfrag*)&Bs[wcol + ni*16 + fr][kb];
    #pragma unroll
    for (int mi=0;mi<2;mi++)
      #pragma unroll
      for (int ni=0;ni<4;ni++)
        acc[mi][ni] = __builtin_amdgcn_mfma_f32_16x16x32_bf16(a[mi], b[ni], acc[mi][ni], 0, 0, 0);
  }

  const int coff = r*HID;
  #pragma unroll
  for (int mi=0;mi<2;mi++){
    int row0 = bm + wrow + mi*16 + fq*4;
    #pragma unroll
    for (int j=0;j<4;j++){
      int row = row0 + j;
      if (row < M){
        #pragma unroll
        for (int ni=0;ni<4;ni++){
          Cb[(size_t)row*H3 + coff + wcol + ni*16 + fr] = f2b(leaky1(acc[mi][ni][j]));
        }
      }
    }
  }
}

// ---------- hw2 MFMA: nfb[:, r*128..] = leaky(pre2b[r] @ hw2[r]), K=384, bf16 out ----------
__global__ __launch_bounds__(256) void k_mfma384(
    const unsigned short* __restrict__ Abf, const unsigned short* __restrict__ Wt,
    unsigned short* __restrict__ nfb)
{
  __shared__ short As[32][72];
  __shared__ short Bs[128][72];
  const int r = blockIdx.y;
  const unsigned short* Ar = Abf + (size_t)r*NSEL*H3;
  const unsigned short* W  = Wt + (size_t)r*HID*H3;
  const int tid = threadIdx.x;
  const int bm = blockIdx.x*32;
  const int wid = tid >> 6, lane = tid & 63;
  const int fr = lane & 15, fq = lane >> 4;
  f4 acc[2][2];
  #pragma unroll
  for (int mi=0;mi<2;mi++)
    #pragma unroll
    for (int ni=0;ni<2;ni++) acc[mi][ni] = (f4){0.f,0.f,0.f,0.f};

  for (int kc=0; kc<6; kc++){
    for (int q = tid; q < 32*8; q += 256){
      int row = q >> 3, c8 = q & 7;
      *(us8*)&As[row][c8*8] = *(const us8*)&Ar[(size_t)(bm+row)*H3 + kc*64 + c8*8];
    }
    for (int q = tid; q < 128*8; q += 256){
      int n = q >> 3, c8 = q & 7;
      *(us8*)&Bs[n][c8*8] = *(const us8*)&W[(size_t)n*H3 + kc*64 + c8*8];
    }
    __syncthreads();
    #pragma unroll
    for (int ks=0; ks<2; ks++){
      int kb = ks*32 + fq*8;
      bfrag a[2], b[2];
      #pragma unroll
      for (int mi=0;mi<2;mi++) a[mi] = *(const bfrag*)&As[mi*16 + fr][kb];
      #pragma unroll
      for (int ni=0;ni<2;ni++) b[ni] = *(const bfrag*)&Bs[wid*32 + ni*16 + fr][kb];
      #pragma unroll
      for (int mi=0;mi<2;mi++)
        #pragma unroll
        for (int ni=0;ni<2;ni++)
          acc[mi][ni] = __builtin_amdgcn_mfma_f32_16x16x32_bf16(a[mi], b[ni], acc[mi][ni], 0, 0, 0);
    }
    __syncthreads();
  }

  #pragma unroll
  for (int mi=0;mi<2;mi++){
    int row0 = bm + mi*16 + fq*4;
    #pragma unroll
    for (int j=0;j<4;j++){
      int i = row0 + j;
      #pragma unroll
      for (int ni=0;ni<2;ni++){
        int col = wid*32 + ni*16 + fr;
        nfb[(size_t)i*FDIM + r*HID + col] = f2b(leaky1(acc[mi][ni][j]));
      }
    }
  }
}

// ---------- t2 MFMA: sbuf = nfb @ wt2^T (f32 raw, K=960) ----------
__global__ __launch_bounds__(256) void k_mfma_t2(
    const unsigned short* __restrict__ Abf, const unsigned short* __restrict__ W,
    float* __restrict__ sbuf)
{
  __shared__ short As[32][72];
  __shared__ short Bs[64][72];
  const int tid = threadIdx.x;
  const int bm = blockIdx.x*32;
  const int wid = tid >> 6, lane = tid & 63;
  const int fr = lane & 15, fq = lane >> 4;
  f4 acc[2];
  acc[0] = (f4){0.f,0.f,0.f,0.f};
  acc[1] = (f4){0.f,0.f,0.f,0.f};

  for (int kc=0; kc<15; kc++){
    for (int q = tid; q < 32*8; q += 256){
      int row = q >> 3, c8 = q & 7;
      *(us8*)&As[row][c8*8] = *(const us8*)&Abf[(size_t)(bm+row)*FDIM + kc*64 + c8*8];
    }
    for (int q = tid; q < 64*8; q += 256){
      int n = q >> 3, c8 = q & 7;
      *(us8*)&Bs[n][c8*8] = *(const us8*)&W[(size_t)n*FDIM + kc*64 + c8*8];
    }
    __syncthreads();
    #pragma unroll
    for (int ks=0; ks<2; ks++){
      int kb = ks*32 + fq*8;
      bfrag a[2], b;
      a[0] = *(const bfrag*)&As[fr][kb];
      a[1] = *(const bfrag*)&As[16 + fr][kb];
      b = *(const bfrag*)&Bs[wid*16 + fr][kb];
      acc[0] = __builtin_amdgcn_mfma_f32_16x16x32_bf16(a[0], b, acc[0], 0, 0, 0);
      acc[1] = __builtin_amdgcn_mfma_f32_16x16x32_bf16(a[1], b, acc[1], 0, 0, 0);
    }
    __syncthreads();
  }

  #pragma unroll
  for (int mi=0;mi<2;mi++){
    int row0 = bm + mi*16 + fq*4;
    #pragma unroll
    for (int j=0;j<4;j++){
      sbuf[(size_t)(row0+j)*64 + wid*16 + fr] = acc[mi][j];
    }
  }
}

// bias + leaky + t3 projection, one wave per selected row
__global__ __launch_bounds__(256) void k_final_wave(
    const float* __restrict__ sbuf, const float* __restrict__ t2b,
    const float* __restrict__ t3w, const float* __restrict__ t3b,
    float* __restrict__ outp)
{
  int w = (blockIdx.x*256 + threadIdx.x) >> 6;
  int j = threadIdx.x & 63;
  if (w >= NSEL) return;
  float v = leaky1(sbuf[(size_t)w*64 + j] + t2b[j]);
  float a0 = v*t3w[j], a1 = v*t3w[64+j];
  #pragma unroll
  for (int sft=32;sft>0;sft>>=1){
    a0 += __shfl_down(a0,(unsigned)sft);
    a1 += __shfl_down(a1,(unsigned)sft);
  }
  if (j==0){
    outp[2*w+0] = a0 + t3b[0];
    outp[2*w+1] = a1 + t3b[1];
  }
}

// ---------- per-node gate scores: group(16)-per-node, us8 loads ----------
template<int D>
__global__ __launch_bounds__(256) void k_scores_g(const unsigned short* __restrict__ X,
    const float* __restrict__ g0, const float* __restrict__ g1, const float* __restrict__ g2,
    float* __restrict__ sd, float* __restrict__ ss){
  const int tid = threadIdx.x;
  const int p = tid & 15;
  const int n = blockIdx.x*16 + (tid >> 4);
  const unsigned short* x = X + (size_t)n*D;
  float a0=0,a1=0,a2=0,a3=0,a4=0,a5=0;
  #pragma unroll
  for (int it=0; it<D/128; it++){
    int k = it*128 + p*8;
    us8 u = *(const us8*)&x[k];
    #pragma unroll
    for (int e=0;e<8;e++){
      float v = b2f(u[e]);
      a0 = fmaf(v, g0[k+e],   a0);  a1 = fmaf(v, g0[D+k+e], a1);
      a2 = fmaf(v, g1[k+e],   a2);  a3 = fmaf(v, g1[D+k+e], a3);
      a4 = fmaf(v, g2[k+e],   a4);  a5 = fmaf(v, g2[D+k+e], a5);
    }
  }
  #pragma unroll
  for (int s=8;s>0;s>>=1){
    a0 += __shfl_xor(a0,(unsigned)s); a1 += __shfl_xor(a1,(unsigned)s);
    a2 += __shfl_xor(a2,(unsigned)s); a3 += __shfl_xor(a3,(unsigned)s);
    a4 += __shfl_xor(a4,(unsigned)s); a5 += __shfl_xor(a5,(unsigned)s);
  }
  if (p==0){
    sd[0*NN+n]=a0; ss[0*NN+n]=a1;
    sd[1*NN+n]=a2; ss[1*NN+n]=a3;
    sd[2*NN+n]=a4; ss[2*NN+n]=a5;
  }
}

// ---------- layer-1 aggregation: group(16)-per-node, 3 rels fused ----------
__global__ __launch_bounds__(256) void k_gather_f3z(
    const unsigned short* __restrict__ Xb,
    const int* __restrict__ off, const unsigned short* __restrict__ csrc,
    const float* __restrict__ sd, const float* __restrict__ ss,
    const float* __restrict__ dnv,
    const float* __restrict__ gb0, const float* __restrict__ gb1, const float* __restrict__ gb2,
    unsigned short* __restrict__ outp){
  const int tid = threadIdx.x;
  const int lane = tid & 63;
  const int wg = lane >> 4;
  const int p  = lane & 15;
  const int n = blockIdx.x*16 + (tid >> 4);
  us8 rv = *(const us8*)&Xb[(size_t)n*HID + p*8];
  float resid[8];
  #pragma unroll
  for (int i=0;i<8;i++) resid[i] = EPSF * b2f(rv[i]);

  for (int r=0;r<3;r++){
    const int* offr = off + r*(NN+1);
    const unsigned short* csr = csrc + (size_t)r*NE;
    const float* ssr = ss + r*NN;
    const float* dnr = dnv + r*NN;
    float gbv = ((r==0)?gb0:((r==1)?gb1:gb2))[0];
    float sd_n = sd[r*NN + n], dn_n = dnr[n];
    float acc[8];
    #pragma unroll
    for (int i=0;i<8;i++) acc[i] = resid[i];
    int p0 = offr[n], p1 = offr[n+1];
    for (int pc=p0; pc<p1; pc+=16){
      int m = min(16, p1-pc);
      int s = 0; float c = 0.f;
      if (p < m){
        s = csr[pc+p];
        c = tanhf(sd_n + ssr[s] + gbv) * dn_n * dnr[s];
      }
      for (int j=0;j<m;j++){
        int   sj = __shfl(s, wg*16+j);
        float cj = __shfl(c, wg*16+j);
        us8 v = *(const us8*)&Xb[(size_t)sj*HID + p*8];
        #pragma unroll
        for (int i=0;i<8;i++) acc[i] = fmaf(cj, b2f(v[i]), acc[i]);
      }
    }
    us8 o;
    #pragma unroll
    for (int i=0;i<8;i++) o[i] = f2b(acc[i]);
    *(us8*)&outp[((size_t)r*NN + n)*HID + p*8] = o;
  }
}

// ---------- layer-2 selected aggregation: group-per-node, D=384, bf16 out ----------
__global__ __launch_bounds__(256) void k_gather_sel3w2(const unsigned short* __restrict__ Xb,
    const int* __restrict__ nodes,
    const int* __restrict__ off, const unsigned short* __restrict__ csrc,
    const float* __restrict__ sd, const float* __restrict__ ss,
    const float* __restrict__ dnv,
    const float* __restrict__ gb0, const float* __restrict__ gb1, const float* __restrict__ gb2,
    unsigned short* __restrict__ outp){
  const int tid = threadIdx.x;
  const int lane = tid & 63;
  const int wg = lane >> 4;
  const int p  = lane & 15;
  const int i = blockIdx.x*16 + (tid >> 4);
  const int r = blockIdx.y;
  const int n = nodes[i];
  const int* offr = off + r*(NN+1);
  const unsigned short* csr = csrc + (size_t)r*NE;
  const float* ssr = ss + r*NN;
  const float* dnr = dnv + r*NN;
  float gbv = ((r==0)?gb0:((r==1)?gb1:gb2))[0];
  float sd_n = sd[r*NN + n], dn_n = dnr[n];
  float acc[3][8];
  #pragma unroll
  for (int cc=0;cc<3;cc++)
    #pragma unroll
    for (int q=0;q<8;q++) acc[cc][q]=0.f;
  int p0 = offr[n], p1 = offr[n+1];
  for (int pc=p0; pc<p1; pc+=16){
    int m = min(16, p1-pc);
    int s = 0; float c = 0.f;
    if (p < m){
      s = csr[pc+p];
      c = tanhf(sd_n + ssr[s] + gbv) * dn_n * dnr[s];
    }
    for (int j=0;j<m;j++){
      int   sj = __shfl(s, wg*16+j);
      float cj = __shfl(c, wg*16+j);
      const unsigned short* row = &Xb[(size_t)sj*H3];
      #pragma unroll
      for (int cc=0;cc<3;cc++){
        us8 v = *(const us8*)&row[cc*HID + p*8];
        #pragma unroll
        for (int q=0;q<8;q++) acc[cc][q] = fmaf(cj, b2f(v[q]), acc[cc][q]);
      }
    }
  }
  const unsigned short* xrow = &Xb[(size_t)n*H3];
  unsigned short* orow = &outp[((size_t)r*NSEL + i)*H3];
  #pragma unroll
  for (int cc=0;cc<3;cc++){
    us8 v = *(const us8*)&xrow[cc*HID + p*8];
    us8 o;
    #pragma unroll
    for (int q=0;q<8;q++) o[q] = f2b(fmaf(EPSF, b2f(v[q]), acc[cc][q]));
    *(us8*)&orow[cc*HID + p*8] = o;
  }
}

// ---------- gather hb/raw1b/raw2b rows into nfb (pure u16 copies) ----------
__global__ __launch_bounds__(256) void k_nf_fillb(const unsigned short* __restrict__ hb,
    const unsigned short* __restrict__ raw1b, const unsigned short* __restrict__ raw2b,
    const int* __restrict__ nodes, unsigned short* __restrict__ nfb){
  int t = blockIdx.x*256 + threadIdx.x;
  if (t >= NSEL*72) return;
  int i = t/72, c = t - i*72;
  int n = nodes[i];
  us8 v; int col;
  if (c < 8)       { v = *(const us8*)&hb[(size_t)n*IND + c*8];           col = 384 + c*8; }
  else if (c < 24) { int q=c-8;  v = *(const us8*)&raw1b[(size_t)n*HID + q*8]; col = 448 + q*8; }
  else             { int q=c-24; v = *(const us8*)&raw2b[(size_t)n*H3  + q*8]; col = 576 + q*8; }
  *(us8*)&nfb[(size_t)i*FDIM + col] = v;
}

extern "C" void kernel_launch(void* const* d_in, const int* in_sizes, int n_in,
                              void* d_out, int out_size, void* d_ws, size_t ws_size,
                              hipStream_t stream){
  if (n_in < 32) return;
  const float* h = (const float*)d_in[0];
  const int* src[3] = {(const int*)d_in[1], (const int*)d_in[3], (const int*)d_in[5]};
  const int* dst[3] = {(const int*)d_in[2], (const int*)d_in[4], (const int*)d_in[6]};
  const int* nodes = (const int*)d_in[7];
  const float* t1w = (const float*)d_in[8];
  const float* t1b = (const float*)d_in[9];

  bool dictOrder = (in_sizes[12] == 768);
  const float *g1w[3],*g1b[3],*g2w[3],*g2b[3],*hw1[3],*hw2[3];
  for (int r=0;r<3;r++){
    if (dictOrder){
      int base = 10 + r*6;
      g1w[r]=(const float*)d_in[base+0]; g1b[r]=(const float*)d_in[base+1];
      g2w[r]=(const float*)d_in[base+2]; g2b[r]=(const float*)d_in[base+3];
      hw1[r]=(const float*)d_in[base+4]; hw2[r]=(const float*)d_in[base+5];
    } else {
      g1w[r]=(const float*)d_in[10+2*r]; g1b[r]=(const float*)d_in[11+2*r];
      g2w[r]=(const float*)d_in[16+2*r]; g2b[r]=(const float*)d_in[17+2*r];
      hw1[r]=(const float*)d_in[22+r];   hw2[r]=(const float*)d_in[25+r];
    }
  }
  const float* t2w = (const float*)d_in[28];
  const float* t2b = (const float*)d_in[29];
  const float* t3w = (const float*)d_in[30];
  const float* t3b = (const float*)d_in[31];
  float* outp = (float*)d_out;

  // workspace carve (~115 MB)
  char* w = (char*)d_ws;
  auto carve = [&](size_t bytes)->void*{
    void* p = (void*)w;
    w += ((bytes + 255) & ~size_t(255));
    return p;
  };
  int*   deg  = (int*)  carve((size_t)(3*NN+1024)*4);  // deg[3N] + bcnt[3*NBK]
  int*   bcnt = deg + 3*NN;
  int*   off  = (int*)  carve((size_t)3*(NN+1)*4);
  float* dnv  = (float*)carve((size_t)3*NN*4);
  int*   bsum = (int*)  carve((size_t)128*4);
  unsigned short* csrc = (unsigned short*)carve((size_t)3*NE*2);
  float* sd1  = (float*)carve((size_t)3*NN*4);
  float* ss1  = (float*)carve((size_t)3*NN*4);
  float* sd2  = (float*)carve((size_t)3*NN*4);
  float* ss2  = (float*)carve((size_t)3*NN*4);
  unsigned short* wt1 = (unsigned short*)carve((size_t)HID*IND*2);
  unsigned short* w1t = (unsigned short*)carve((size_t)3*HID*HID*2);
  unsigned short* w2t = (unsigned short*)carve((size_t)3*HID*H3*2);
  unsigned short* wt2 = (unsigned short*)carve((size_t)64*FDIM*2);
  unsigned short* hb  = (unsigned short*)carve((size_t)NN*IND*2);
  unsigned short* raw1b = (unsigned short*)carve((size_t)NN*HID*2);
  unsigned short* raw2b = (unsigned short*)carve((size_t)NN*H3*2);
  // union region (38.4MB): pairbuf u32 [3*NBK*BCAP] (9.6MB) | pre1b [3][NN][HID] |
  //   { pre2b [3][NSEL][H3] (9.4MB) @0  +  sbuf f32 [NSEL][64] (1MB) @16MB }
  size_t ubytes = (size_t)3*NN*HID*2;
  float* ureg = (float*)carve(ubytes);
  unsigned int* pairbuf = (unsigned int*)ureg;
  unsigned short* pre1b = (unsigned short*)ureg;
  unsigned short* pre2b = (unsigned short*)ureg;
  float* sbuf = (float*)((char*)ureg + (size_t)16*1024*1024);
  unsigned short* nfb = (unsigned short*)carve((size_t)NSEL*FDIM*2);

  hipMemsetAsync(bcnt, 0, (size_t)1024*4, stream);
  k_bfill4<<<dim3((NE+EPB-1)/EPB, 3), 256, 0, stream>>>(
      src[0],dst[0],src[1],dst[1],src[2],dst[2], bcnt, pairbuf);
  k_count <<<dim3(NBK,3), 256, 0, stream>>>(pairbuf, bcnt, deg);
  k_scan_a<<<3*NCHUNK, 256, 0, stream>>>(deg, off, bsum, dnv);
  k_scan_b<<<1, 64, 0, stream>>>(bsum);
  k_scan_c<<<3*NCHUNK, 256, 0, stream>>>(off, bsum);
  k_bsort3<<<dim3(NBK,3), 256, 0, stream>>>(pairbuf, bcnt, off, csrc);

  k_wprep2<<<(666240+255)/256, 256, 0, stream>>>(
      t1w, hw1[0], hw1[1], hw1[2], hw2[0], hw2[1], hw2[2], t2w, h,
      wt1, w1t, w2t, wt2, hb);

  // raw1b = leaky(hb @ t1w^T + t1b)
  k_mfma_t1<<<(NN+63)/64, 256, 0, stream>>>(hb, wt1, t1b, raw1b);

  k_scores_g<HID><<<NN/16, 256, 0, stream>>>(raw1b, g1w[0], g1w[1], g1w[2], sd1, ss1);

  // layer-1 gather (group-per-node, 3 rels fused) + hw1 MFMA
  k_gather_f3z<<<NN/16, 256, 0, stream>>>(raw1b, off, csrc,
      sd1, ss1, dnv, g1b[0], g1b[1], g1b[2], pre1b);
  k_mfma128<<<dim3((NN+63)/64, 3), 256, 0, stream>>>(pre1b, w1t, raw2b, NN);

  k_scores_g<H3><<<NN/16, 256, 0, stream>>>(raw2b, g2w[0], g2w[1], g2w[2], sd2, ss2);

  // layer-2 selected gather -> bf16 pre2
  k_gather_sel3w2<<<dim3(NSEL/16, 3), 256, 0, stream>>>(raw2b, nodes, off, csrc,
      sd2, ss2, dnv, g2b[0], g2b[1], g2b[2], pre2b);

  // hw2 MFMA -> nfb cols [0,384)
  k_mfma384<<<dim3(NSEL/32, 3), 256, 0, stream>>>(pre2b, w2t, nfb);

  k_nf_fillb<<<(NSEL*72+255)/256, 256, 0, stream>>>(hb, raw1b, raw2b, nodes, nfb);

  // t2 MFMA (K=960) -> sbuf, then fused bias+leaky+t3
  k_mfma_t2<<<NSEL/32, 256, 0, stream>>>(nfb, wt2, sbuf);
  k_final_wave<<<(NSEL*64+255)/256, 256, 0, stream>>>(sbuf, t2b, t3w, t3b, outp);
}

// Round 11
// 197.041 us; speedup vs baseline: 4.6489x; 1.0521x over previous
//
#include <hip/hip_runtime.h>
#include <hip/hip_bf16.h>

#define NN 50000
#define NE 400000
#define IND 64
#define HID 128
#define H3 384
#define FDIM 960
#define NSEL 4096
#define EPSF 0.3f
#define SLOPEF 0.3f
#define NBK 196            // ceil(NN/256) dst-buckets per relation
#define BCAP 4096          // fixed bucket capacity (mean 2048, sigma 45)
#define EPB 4096           // edges per block in k_bfill4
#define NOEDGE 0xFFFFFFFFu

typedef __attribute__((ext_vector_type(8))) short bfrag;   // 8 bf16 (4 VGPR)
typedef __attribute__((ext_vector_type(4))) float f4;
typedef __attribute__((ext_vector_type(8))) unsigned short us8;

__device__ __forceinline__ float leaky1(float v){ return v>=0.f? v : SLOPEF*v; }
__device__ __forceinline__ float b2f(unsigned short u){
  return __uint_as_float(((unsigned)u)<<16);
}
__device__ __forceinline__ unsigned short f2b(float v){
  __hip_bfloat16 b = __float2bfloat16(v);
  return *(unsigned short*)&b;
}

// ---------- bucketed fill, LDS-staged, no per-edge global atomics ----------
__global__ __launch_bounds__(256) void k_bfill4(
    const int* __restrict__ s0,const int* __restrict__ d0,
    const int* __restrict__ s1,const int* __restrict__ d1,
    const int* __restrict__ s2,const int* __restrict__ d2,
    int* __restrict__ bcnt, unsigned int* __restrict__ pairbuf)
{
  __shared__ unsigned int lbuf[EPB];     // 16 KB staging
  __shared__ int hist[256];
  __shared__ int lbase[256];
  __shared__ int lcur[256];
  __shared__ int gbase[NBK];
  __shared__ int wsum[4];
  const int r = blockIdx.y;
  const int* S = (r==0)?s0:((r==1)?s1:s2);
  const int* D = (r==0)?d0:((r==1)?d1:d2);
  const int e0 = blockIdx.x*EPB;
  const int t = threadIdx.x;
  hist[t] = 0; lcur[t] = 0;
  __syncthreads();

  unsigned int pv[16];
  #pragma unroll
  for (int j=0;j<4;j++){
    int e = e0 + (j*256 + t)*4;
    if (e < NE){
      int4 sv = *(const int4*)&S[e];
      int4 dv = *(const int4*)&D[e];
      pv[j*4+0] = ((unsigned)dv.x<<16)|(unsigned)sv.x;
      pv[j*4+1] = ((unsigned)dv.y<<16)|(unsigned)sv.y;
      pv[j*4+2] = ((unsigned)dv.z<<16)|(unsigned)sv.z;
      pv[j*4+3] = ((unsigned)dv.w<<16)|(unsigned)sv.w;
    } else {
      pv[j*4+0]=NOEDGE; pv[j*4+1]=NOEDGE; pv[j*4+2]=NOEDGE; pv[j*4+3]=NOEDGE;
    }
  }
  #pragma unroll
  for (int i=0;i<16;i++){
    if (pv[i] != NOEDGE) atomicAdd(&hist[pv[i]>>24], 1);
  }
  __syncthreads();
  {
    int hv = hist[t];
    int lane = t & 63, wid = t >> 6;
    int x = hv;
    #pragma unroll
    for (int d=1; d<64; d<<=1){ int y=__shfl_up(x,(unsigned)d); if(lane>=d) x+=y; }
    if (lane==63) wsum[wid]=x;
    __syncthreads();
    int wpre = 0;
    if (wid>0) wpre += wsum[0];
    if (wid>1) wpre += wsum[1];
    if (wid>2) wpre += wsum[2];
    lbase[t] = wpre + x - hv;
    if (t < NBK){
      int hh = hist[t];
      gbase[t] = (hh>0) ? atomicAdd(&bcnt[r*NBK+t], hh) : 0;
    }
  }
  __syncthreads();
  #pragma unroll
  for (int i=0;i<16;i++){
    if (pv[i] != NOEDGE){
      int b = (int)(pv[i] >> 24);
      int pos = lbase[b] + atomicAdd(&lcur[b], 1);
      lbuf[pos] = pv[i];
    }
  }
  __syncthreads();
  int tot = min(NE - e0, EPB);
  for (int idx = t; idx < tot; idx += 256){
    unsigned int v = lbuf[idx];
    int b = (int)(v >> 24);
    pairbuf[((size_t)(r*NBK + b))*BCAP + gbase[b] + (idx - lbase[b])] = v;
  }
}

// ---------- fused: bucket base + per-node off/dnv + counting sort -> csrc ----------
// Replaces k_count + scan_a + scan_b + scan_c + bsort3 (5 dispatches -> 1)
__global__ __launch_bounds__(256) void k_bsort4(
    const unsigned int* __restrict__ pairbuf,
    const int* __restrict__ bcnt,
    int* __restrict__ off, float* __restrict__ dnv,
    unsigned short* __restrict__ csrc)
{
  __shared__ unsigned short lout[BCAP];   // 8 KB
  __shared__ int hist[256];
  __shared__ int excl[256];
  __shared__ int cur[256];
  __shared__ int red[256];
  __shared__ int wsum[4];
  const int r = blockIdx.y, b = blockIdx.x;
  const int nb0 = b << 8;
  const int t = threadIdx.x;
  red[t] = (t < b) ? bcnt[r*NBK + t] : 0;
  hist[t] = 0; cur[t] = 0;
  __syncthreads();
  // tree-reduce red -> bbase
  #pragma unroll
  for (int sdv=128; sdv>0; sdv>>=1){
    if (t < sdv) red[t] += red[t+sdv];
    __syncthreads();
  }
  const int bbase = red[0];
  const int cnt = bcnt[r*NBK + b];
  const unsigned int* pb = pairbuf + ((size_t)(r*NBK + b))*BCAP;
  // hold bucket's edges in registers (cnt <= BCAP = 4096 = 256*16)
  unsigned int pv[16];
  #pragma unroll
  for (int j=0;j<16;j++){
    int e = j*256 + t;
    pv[j] = (e < cnt) ? pb[e] : NOEDGE;
    if (pv[j] != NOEDGE) atomicAdd(&hist[(int)(pv[j]>>16) - nb0], 1);
  }
  __syncthreads();
  // block prefix scan hist -> excl
  {
    int hv = hist[t];
    int lane = t & 63, wid = t >> 6;
    int x = hv;
    #pragma unroll
    for (int d=1; d<64; d<<=1){ int y=__shfl_up(x,(unsigned)d); if(lane>=d) x+=y; }
    if (lane==63) wsum[wid]=x;
    __syncthreads();
    int wpre = 0;
    if (wid>0) wpre += wsum[0];
    if (wid>1) wpre += wsum[1];
    if (wid>2) wpre += wsum[2];
    excl[t] = wpre + x - hv;
  }
  __syncthreads();
  // write off (node start offsets) and dnv
  int nidx = nb0 + t;
  if (nidx < NN){
    off[r*(NN+1) + nidx] = bbase + excl[t];
    int g = hist[t];
    dnv[r*NN + nidx] = (g>0) ? rsqrtf((float)g) : 0.f;
  }
  if (b == NBK-1 && t == 0) off[r*(NN+1) + NN] = bbase + cnt;
  // place edges into LDS (counting sort within bucket)
  #pragma unroll
  for (int j=0;j<16;j++){
    if (pv[j] != NOEDGE){
      int pn = (int)(pv[j] >> 16) - nb0;
      int slot = atomicAdd(&cur[pn], 1);
      lout[excl[pn] + slot] = (unsigned short)(pv[j] & 0xffffu);
    }
  }
  __syncthreads();
  unsigned short* op = csrc + (size_t)r*NE + bbase;
  for (int idx = t; idx < cnt; idx += 256) op[idx] = lout[idx];
}

// ---------- all weight preps + h-cast (one kernel) ----------
__global__ void k_wprep2(const float* __restrict__ t1w,
    const float* __restrict__ hw1_0, const float* __restrict__ hw1_1, const float* __restrict__ hw1_2,
    const float* __restrict__ hw2_0, const float* __restrict__ hw2_1, const float* __restrict__ hw2_2,
    const float* __restrict__ t2w, const float* __restrict__ h,
    unsigned short* __restrict__ wt1, unsigned short* __restrict__ w1t,
    unsigned short* __restrict__ w2t, unsigned short* __restrict__ wt2,
    unsigned short* __restrict__ hb){
  int t = blockIdx.x*256 + threadIdx.x;
  if (t < 8192){                              // t1w [128][64] = [n][k]
    wt1[t] = f2b(t1w[t]);
  } else if (t < 57344){                      // hw1 [k=128][n=128] -> [r][n][k]
    int e = t - 8192;
    int r = e / 16384, q = e - r*16384;
    int n = q >> 7, k = q & 127;
    const float* W = (r==0)?hw1_0:((r==1)?hw1_1:hw1_2);
    w1t[e] = f2b(W[k*HID + n]);
  } else if (t < 204800){                     // hw2 [k=384][n=128] -> [r][n][k]
    int e = t - 57344;
    int r = e / 49152, q = e - r*49152;
    int n = q / H3, k = q - n*H3;
    const float* W = (r==0)?hw2_0:((r==1)?hw2_1:hw2_2);
    w2t[e] = f2b(W[k*HID + n]);
  } else if (t < 266240){                     // t2w [64][960] = [n][k]
    int e = t - 204800;
    wt2[e] = f2b(t2w[e]);
  } else if (t < 666240){                     // h cast: one us8 chunk each
    int q = t - 266240;
    const float4 a = ((const float4*)h)[q*2];
    const float4 b = ((const float4*)h)[q*2+1];
    us8 o;
    o[0]=f2b(a.x); o[1]=f2b(a.y); o[2]=f2b(a.z); o[3]=f2b(a.w);
    o[4]=f2b(b.x); o[5]=f2b(b.y); o[6]=f2b(b.z); o[7]=f2b(b.w);
    *(us8*)&hb[q*8] = o;
  }
}

// ---------- t1 MFMA: raw1b = leaky(hb @ wt1^T + t1b) (bf16 out only) ----------
__global__ __launch_bounds__(256) void k_mfma_t1(
    const unsigned short* __restrict__ Ab, const unsigned short* __restrict__ W,
    const float* __restrict__ bias, unsigned short* __restrict__ Cb)
{
  __shared__ short As[64][72];
  __shared__ short Bs[128][72];
  const int tid = threadIdx.x;
  const int bm = blockIdx.x*64;

  for (int q = tid; q < 64*8; q += 256){
    int row = q >> 3, c8 = q & 7;
    int grow = bm + row; grow = (grow < NN) ? grow : (NN-1);
    *(us8*)&As[row][c8*8] = *(const us8*)&Ab[(size_t)grow*IND + c8*8];
  }
  for (int q = tid; q < 128*8; q += 256){
    int n = q >> 3, c8 = q & 7;
    *(us8*)&Bs[n][c8*8] = *(const us8*)&W[n*IND + c8*8];
  }
  __syncthreads();

  const int wid = tid >> 6, lane = tid & 63;
  const int wrow = (wid & 1)*32, wcol = (wid >> 1)*64;
  const int fr = lane & 15, fq = lane >> 4;
  f4 acc[2][4];
  #pragma unroll
  for (int mi=0;mi<2;mi++)
    #pragma unroll
    for (int ni=0;ni<4;ni++) acc[mi][ni] = (f4){0.f,0.f,0.f,0.f};

  #pragma unroll
  for (int ks=0; ks<2; ks++){
    int kb = ks*32 + fq*8;
    bfrag a[2], b[4];
    #pragma unroll
    for (int mi=0;mi<2;mi++) a[mi] = *(const bfrag*)&As[wrow + mi*16 + fr][kb];
    #pragma unroll
    for (int ni=0;ni<4;ni++) b[ni] = *(const bfrag*)&Bs[wcol + ni*16 + fr][kb];
    #pragma unroll
    for (int mi=0;mi<2;mi++)
      #pragma unroll
      for (int ni=0;ni<4;ni++)
        acc[mi][ni] = __builtin_amdgcn_mfma_f32_16x16x32_bf16(a[mi], b[ni], acc[mi][ni], 0, 0, 0);
  }

  #pragma unroll
  for (int mi=0;mi<2;mi++){
    int row0 = bm + wrow + mi*16 + fq*4;
    #pragma unroll
    for (int j=0;j<4;j++){
      int row = row0 + j;
      if (row < NN){
        #pragma unroll
        for (int ni=0;ni<4;ni++){
          int col = wcol + ni*16 + fr;
          Cb[(size_t)row*HID + col] = f2b(leaky1(acc[mi][ni][j] + bias[col]));
        }
      }
    }
  }
}

// ---------- batched bf16 MFMA: raw2b[:, r*128..] = leaky(pre1b[r] @ hw1[r]) ----------
__global__ __launch_bounds__(256) void k_mfma128(
    const unsigned short* __restrict__ Abf, const unsigned short* __restrict__ Wt,
    unsigned short* __restrict__ Cb, int M)
{
  __shared__ short As[64][136];
  __shared__ short Bs[128][136];
  const int r = blockIdx.y;
  const unsigned short* Ar = Abf + (size_t)r*M*HID;
  const unsigned short* W  = Wt + (size_t)r*HID*HID;
  const int tid = threadIdx.x;
  const int bm = blockIdx.x*64;

  for (int q = tid; q < 64*16; q += 256){
    int row = q >> 4, c8 = q & 15;
    int grow = bm + row; grow = (grow < M) ? grow : (M-1);
    *(us8*)&As[row][c8*8] = *(const us8*)&Ar[(size_t)grow*HID + c8*8];
  }
  for (int q = tid; q < 128*16; q += 256){
    int n = q >> 4, c8 = q & 15;
    *(us8*)&Bs[n][c8*8] = *(const us8*)&W[n*HID + c8*8];
  }
  __syncthreads();

  const int wid = tid >> 6, lane = tid & 63;
  const int wrow = (wid & 1)*32, wcol = (wid >> 1)*64;
  const int fr = lane & 15, fq = lane >> 4;
  f4 acc[2][4];
  #pragma unroll
  for (int mi=0;mi<2;mi++)
    #pragma unroll
    for (int ni=0;ni<4;ni++) acc[mi][ni] = (f4){0.f,0.f,0.f,0.f};

  #pragma unroll
  for (int ks=0; ks<4; ks++){
    int kb = ks*32 + fq*8;
    bfrag a[2], b[4];
    #pragma unroll
    for (int mi=0;mi<2;mi++) a[mi] = *(const bfrag*)&As[wrow + mi*16 + fr][kb];
    #pragma unroll
    for (int ni=0;ni<4;ni++) b[ni] = *(const bfrag*)&Bs[wcol + ni*16 + fr][kb];
    #pragma unroll
    for (int mi=0;mi<2;mi++)
      #pragma unroll
      for (int ni=0;ni<4;ni++)
        acc[mi][ni] = __builtin_amdgcn_mfma_f32_16x16x32_bf16(a[mi], b[ni], acc[mi][ni], 0, 0, 0);
  }

  const int coff = r*HID;
  #pragma unroll
  for (int mi=0;mi<2;mi++){
    int row0 = bm + wrow + mi*16 + fq*4;
    #pragma unroll
    for (int j=0;j<4;j++){
      int row = row0 + j;
      if (row < M){
        #pragma unroll
        for (int ni=0;ni<4;ni++){
          Cb[(size_t)row*H3 + coff + wcol + ni*16 + fr] = f2b(leaky1(acc[mi][ni][j]));
        }
      }
    }
  }
}

// ---------- hw2 MFMA: nfb[:, r*128..] = leaky(pre2b[r] @ hw2[r]), K=384, bf16 out ----------
__global__ __launch_bounds__(256) void k_mfma384(
    const unsigned short* __restrict__ Abf, const unsigned short* __restrict__ Wt,
    unsigned short* __restrict__ nfb)
{
  __shared__ short As[32][72];
  __shared__ short Bs[128][72];
  const int r = blockIdx.y;
  const unsigned short* Ar = Abf + (size_t)r*NSEL*H3;
  const unsigned short* W  = Wt + (size_t)r*HID*H3;
  const int tid = threadIdx.x;
  const int bm = blockIdx.x*32;
  const int wid = tid >> 6, lane = tid & 63;
  const int fr = lane & 15, fq = lane >> 4;
  f4 acc[2][2];
  #pragma unroll
  for (int mi=0;mi<2;mi++)
    #pragma unroll
    for (int ni=0;ni<2;ni++) acc[mi][ni] = (f4){0.f,0.f,0.f,0.f};

  for (int kc=0; kc<6; kc++){
    for (int q = tid; q < 32*8; q += 256){
      int row = q >> 3, c8 = q & 7;
      *(us8*)&As[row][c8*8] = *(const us8*)&Ar[(size_t)(bm+row)*H3 + kc*64 + c8*8];
    }
    for (int q = tid; q < 128*8; q += 256){
      int n = q >> 3, c8 = q & 7;
      *(us8*)&Bs[n][c8*8] = *(const us8*)&W[(size_t)n*H3 + kc*64 + c8*8];
    }
    __syncthreads();
    #pragma unroll
    for (int ks=0; ks<2; ks++){
      int kb = ks*32 + fq*8;
      bfrag a[2], b[2];
      #pragma unroll
      for (int mi=0;mi<2;mi++) a[mi] = *(const bfrag*)&As[mi*16 + fr][kb];
      #pragma unroll
      for (int ni=0;ni<2;ni++) b[ni] = *(const bfrag*)&Bs[wid*32 + ni*16 + fr][kb];
      #pragma unroll
      for (int mi=0;mi<2;mi++)
        #pragma unroll
        for (int ni=0;ni<2;ni++)
          acc[mi][ni] = __builtin_amdgcn_mfma_f32_16x16x32_bf16(a[mi], b[ni], acc[mi][ni], 0, 0, 0);
    }
    __syncthreads();
  }

  #pragma unroll
  for (int mi=0;mi<2;mi++){
    int row0 = bm + mi*16 + fq*4;
    #pragma unroll
    for (int j=0;j<4;j++){
      int i = row0 + j;
      #pragma unroll
      for (int ni=0;ni<2;ni++){
        int col = wid*32 + ni*16 + fr;
        nfb[(size_t)i*FDIM + r*HID + col] = f2b(leaky1(acc[mi][ni][j]));
      }
    }
  }
}

// ---------- t2 MFMA: sbuf = nfb @ wt2^T (f32 raw, K=960) ----------
__global__ __launch_bounds__(256) void k_mfma_t2(
    const unsigned short* __restrict__ Abf, const unsigned short* __restrict__ W,
    float* __restrict__ sbuf)
{
  __shared__ short As[32][72];
  __shared__ short Bs[64][72];
  const int tid = threadIdx.x;
  const int bm = blockIdx.x*32;
  const int wid = tid >> 6, lane = tid & 63;
  const int fr = lane & 15, fq = lane >> 4;
  f4 acc[2];
  acc[0] = (f4){0.f,0.f,0.f,0.f};
  acc[1] = (f4){0.f,0.f,0.f,0.f};

  for (int kc=0; kc<15; kc++){
    for (int q = tid; q < 32*8; q += 256){
      int row = q >> 3, c8 = q & 7;
      *(us8*)&As[row][c8*8] = *(const us8*)&Abf[(size_t)(bm+row)*FDIM + kc*64 + c8*8];
    }
    for (int q = tid; q < 64*8; q += 256){
      int n = q >> 3, c8 = q & 7;
      *(us8*)&Bs[n][c8*8] = *(const us8*)&W[(size_t)n*FDIM + kc*64 + c8*8];
    }
    __syncthreads();
    #pragma unroll
    for (int ks=0; ks<2; ks++){
      int kb = ks*32 + fq*8;
      bfrag a[2], b;
      a[0] = *(const bfrag*)&As[fr][kb];
      a[1] = *(const bfrag*)&As[16 + fr][kb];
      b = *(const bfrag*)&Bs[wid*16 + fr][kb];
      acc[0] = __builtin_amdgcn_mfma_f32_16x16x32_bf16(a[0], b, acc[0], 0, 0, 0);
      acc[1] = __builtin_amdgcn_mfma_f32_16x16x32_bf16(a[1], b, acc[1], 0, 0, 0);
    }
    __syncthreads();
  }

  #pragma unroll
  for (int mi=0;mi<2;mi++){
    int row0 = bm + mi*16 + fq*4;
    #pragma unroll
    for (int j=0;j<4;j++){
      sbuf[(size_t)(row0+j)*64 + wid*16 + fr] = acc[mi][j];
    }
  }
}

// bias + leaky + t3 projection, one wave per selected row
__global__ __launch_bounds__(256) void k_final_wave(
    const float* __restrict__ sbuf, const float* __restrict__ t2b,
    const float* __restrict__ t3w, const float* __restrict__ t3b,
    float* __restrict__ outp)
{
  int w = (blockIdx.x*256 + threadIdx.x) >> 6;
  int j = threadIdx.x & 63;
  if (w >= NSEL) return;
  float v = leaky1(sbuf[(size_t)w*64 + j] + t2b[j]);
  float a0 = v*t3w[j], a1 = v*t3w[64+j];
  #pragma unroll
  for (int sft=32;sft>0;sft>>=1){
    a0 += __shfl_down(a0,(unsigned)sft);
    a1 += __shfl_down(a1,(unsigned)sft);
  }
  if (j==0){
    outp[2*w+0] = a0 + t3b[0];
    outp[2*w+1] = a1 + t3b[1];
  }
}

// ---------- per-node gate scores: group(16)-per-node, us8 loads ----------
template<int D>
__global__ __launch_bounds__(256) void k_scores_g(const unsigned short* __restrict__ X,
    const float* __restrict__ g0, const float* __restrict__ g1, const float* __restrict__ g2,
    float* __restrict__ sd, float* __restrict__ ss){
  const int tid = threadIdx.x;
  const int p = tid & 15;
  const int n = blockIdx.x*16 + (tid >> 4);
  const unsigned short* x = X + (size_t)n*D;
  float a0=0,a1=0,a2=0,a3=0,a4=0,a5=0;
  #pragma unroll
  for (int it=0; it<D/128; it++){
    int k = it*128 + p*8;
    us8 u = *(const us8*)&x[k];
    #pragma unroll
    for (int e=0;e<8;e++){
      float v = b2f(u[e]);
      a0 = fmaf(v, g0[k+e],   a0);  a1 = fmaf(v, g0[D+k+e], a1);
      a2 = fmaf(v, g1[k+e],   a2);  a3 = fmaf(v, g1[D+k+e], a3);
      a4 = fmaf(v, g2[k+e],   a4);  a5 = fmaf(v, g2[D+k+e], a5);
    }
  }
  #pragma unroll
  for (int s=8;s>0;s>>=1){
    a0 += __shfl_xor(a0,(unsigned)s); a1 += __shfl_xor(a1,(unsigned)s);
    a2 += __shfl_xor(a2,(unsigned)s); a3 += __shfl_xor(a3,(unsigned)s);
    a4 += __shfl_xor(a4,(unsigned)s); a5 += __shfl_xor(a5,(unsigned)s);
  }
  if (p==0){
    sd[0*NN+n]=a0; ss[0*NN+n]=a1;
    sd[1*NN+n]=a2; ss[1*NN+n]=a3;
    sd[2*NN+n]=a4; ss[2*NN+n]=a5;
  }
}

// ---------- layer-1 aggregation: group(16)-per-node, 3 rels fused, 1-ahead pipeline ----------
__global__ __launch_bounds__(256) void k_gather_f3z(
    const unsigned short* __restrict__ Xb,
    const int* __restrict__ off, const unsigned short* __restrict__ csrc,
    const float* __restrict__ sd, const float* __restrict__ ss,
    const float* __restrict__ dnv,
    const float* __restrict__ gb0, const float* __restrict__ gb1, const float* __restrict__ gb2,
    unsigned short* __restrict__ outp){
  const int tid = threadIdx.x;
  const int lane = tid & 63;
  const int wg = lane >> 4;
  const int p  = lane & 15;
  const int n = blockIdx.x*16 + (tid >> 4);
  us8 rv = *(const us8*)&Xb[(size_t)n*HID + p*8];
  // hoist all relations' CSR ranges (independent loads, overlap latency)
  int p0a[3], p1a[3];
  #pragma unroll
  for (int r=0;r<3;r++){
    p0a[r] = off[r*(NN+1) + n];
    p1a[r] = off[r*(NN+1) + n + 1];
  }
  float resid[8];
  #pragma unroll
  for (int i=0;i<8;i++) resid[i] = EPSF * b2f(rv[i]);

  for (int r=0;r<3;r++){
    const unsigned short* csr = csrc + (size_t)r*NE;
    const float* ssr = ss + r*NN;
    const float* dnr = dnv + r*NN;
    float gbv = ((r==0)?gb0:((r==1)?gb1:gb2))[0];
    float sd_n = sd[r*NN + n], dn_n = dnr[n];
    float acc[8];
    #pragma unroll
    for (int i=0;i<8;i++) acc[i] = resid[i];
    int p0 = p0a[r], p1 = p1a[r];
    for (int pc=p0; pc<p1; pc+=16){
      int m = min(16, p1-pc);
      int s = 0; float c = 0.f;
      if (p < m){
        s = csr[pc+p];
        c = tanhf(sd_n + ssr[s] + gbv) * dn_n * dnr[s];
      }
      // 1-ahead software pipeline: issue edge j+1's row load before edge j's FMAs
      int   sj = __shfl(s, wg*16);
      float cj = __shfl(c, wg*16);
      us8 v = *(const us8*)&Xb[(size_t)sj*HID + p*8];
      for (int j=1;j<=m;j++){
        us8 vn; float cn = 0.f;
        if (j < m){
          int sn = __shfl(s, wg*16+j);
          cn = __shfl(c, wg*16+j);
          vn = *(const us8*)&Xb[(size_t)sn*HID + p*8];
        }
        #pragma unroll
        for (int i=0;i<8;i++) acc[i] = fmaf(cj, b2f(v[i]), acc[i]);
        v = vn; cj = cn;
      }
    }
    us8 o;
    #pragma unroll
    for (int i=0;i<8;i++) o[i] = f2b(acc[i]);
    *(us8*)&outp[((size_t)r*NN + n)*HID + p*8] = o;
  }
}

// ---------- layer-2 selected aggregation: group-per-node, D=384, 1-ahead pipeline ----------
__global__ __launch_bounds__(256) void k_gather_sel3w2(const unsigned short* __restrict__ Xb,
    const int* __restrict__ nodes,
    const int* __restrict__ off, const unsigned short* __restrict__ csrc,
    const float* __restrict__ sd, const float* __restrict__ ss,
    const float* __restrict__ dnv,
    const float* __restrict__ gb0, const float* __restrict__ gb1, const float* __restrict__ gb2,
    unsigned short* __restrict__ outp){
  const int tid = threadIdx.x;
  const int lane = tid & 63;
  const int wg = lane >> 4;
  const int p  = lane & 15;
  const int i = blockIdx.x*16 + (tid >> 4);
  const int r = blockIdx.y;
  const int n = nodes[i];
  const int* offr = off + r*(NN+1);
  const unsigned short* csr = csrc + (size_t)r*NE;
  const float* ssr = ss + r*NN;
  const float* dnr = dnv + r*NN;
  float gbv = ((r==0)?gb0:((r==1)?gb1:gb2))[0];
  float sd_n = sd[r*NN + n], dn_n = dnr[n];
  float acc[3][8];
  #pragma unroll
  for (int cc=0;cc<3;cc++)
    #pragma unroll
    for (int q=0;q<8;q++) acc[cc][q]=0.f;
  int p0 = offr[n], p1 = offr[n+1];
  for (int pc=p0; pc<p1; pc+=16){
    int m = min(16, p1-pc);
    int s = 0; float c = 0.f;
    if (p < m){
      s = csr[pc+p];
      c = tanhf(sd_n + ssr[s] + gbv) * dn_n * dnr[s];
    }
    int   sj = __shfl(s, wg*16);
    float cj = __shfl(c, wg*16);
    const unsigned short* row = &Xb[(size_t)sj*H3];
    us8 v0 = *(const us8*)&row[0*HID + p*8];
    us8 v1 = *(const us8*)&row[1*HID + p*8];
    us8 v2 = *(const us8*)&row[2*HID + p*8];
    for (int j=1;j<=m;j++){
      us8 n0, n1, n2; float cn = 0.f;
      if (j < m){
        int sn = __shfl(s, wg*16+j);
        cn = __shfl(c, wg*16+j);
        const unsigned short* rw = &Xb[(size_t)sn*H3];
        n0 = *(const us8*)&rw[0*HID + p*8];
        n1 = *(const us8*)&rw[1*HID + p*8];
        n2 = *(const us8*)&rw[2*HID + p*8];
      }
      #pragma unroll
      for (int q=0;q<8;q++){
        acc[0][q] = fmaf(cj, b2f(v0[q]), acc[0][q]);
        acc[1][q] = fmaf(cj, b2f(v1[q]), acc[1][q]);
        acc[2][q] = fmaf(cj, b2f(v2[q]), acc[2][q]);
      }
      v0 = n0; v1 = n1; v2 = n2; cj = cn;
    }
  }
  const unsigned short* xrow = &Xb[(size_t)n*H3];
  unsigned short* orow = &outp[((size_t)r*NSEL + i)*H3];
  #pragma unroll
  for (int cc=0;cc<3;cc++){
    us8 v = *(const us8*)&xrow[cc*HID + p*8];
    us8 o;
    #pragma unroll
    for (int q=0;q<8;q++) o[q] = f2b(fmaf(EPSF, b2f(v[q]), acc[cc][q]));
    *(us8*)&orow[cc*HID + p*8] = o;
  }
}

// ---------- gather hb/raw1b/raw2b rows into nfb (pure u16 copies) ----------
__global__ __launch_bounds__(256) void k_nf_fillb(const unsigned short* __restrict__ hb,
    const unsigned short* __restrict__ raw1b, const unsigned short* __restrict__ raw2b,
    const int* __restrict__ nodes, unsigned short* __restrict__ nfb){
  int t = blockIdx.x*256 + threadIdx.x;
  if (t >= NSEL*72) return;
  int i = t/72, c = t - i*72;
  int n = nodes[i];
  us8 v; int col;
  if (c < 8)       { v = *(const us8*)&hb[(size_t)n*IND + c*8];           col = 384 + c*8; }
  else if (c < 24) { int q=c-8;  v = *(const us8*)&raw1b[(size_t)n*HID + q*8]; col = 448 + q*8; }
  else             { int q=c-24; v = *(const us8*)&raw2b[(size_t)n*H3  + q*8]; col = 576 + q*8; }
  *(us8*)&nfb[(size_t)i*FDIM + col] = v;
}

extern "C" void kernel_launch(void* const* d_in, const int* in_sizes, int n_in,
                              void* d_out, int out_size, void* d_ws, size_t ws_size,
                              hipStream_t stream){
  if (n_in < 32) return;
  const float* h = (const float*)d_in[0];
  const int* src[3] = {(const int*)d_in[1], (const int*)d_in[3], (const int*)d_in[5]};
  const int* dst[3] = {(const int*)d_in[2], (const int*)d_in[4], (const int*)d_in[6]};
  const int* nodes = (const int*)d_in[7];
  const float* t1w = (const float*)d_in[8];
  const float* t1b = (const float*)d_in[9];

  bool dictOrder = (in_sizes[12] == 768);
  const float *g1w[3],*g1b[3],*g2w[3],*g2b[3],*hw1[3],*hw2[3];
  for (int r=0;r<3;r++){
    if (dictOrder){
      int base = 10 + r*6;
      g1w[r]=(const float*)d_in[base+0]; g1b[r]=(const float*)d_in[base+1];
      g2w[r]=(const float*)d_in[base+2]; g2b[r]=(const float*)d_in[base+3];
      hw1[r]=(const float*)d_in[base+4]; hw2[r]=(const float*)d_in[base+5];
    } else {
      g1w[r]=(const float*)d_in[10+2*r]; g1b[r]=(const float*)d_in[11+2*r];
      g2w[r]=(const float*)d_in[16+2*r]; g2b[r]=(const float*)d_in[17+2*r];
      hw1[r]=(const float*)d_in[22+r];   hw2[r]=(const float*)d_in[25+r];
    }
  }
  const float* t2w = (const float*)d_in[28];
  const float* t2b = (const float*)d_in[29];
  const float* t3w = (const float*)d_in[30];
  const float* t3b = (const float*)d_in[31];
  float* outp = (float*)d_out;

  // workspace carve (~115 MB)
  char* w = (char*)d_ws;
  auto carve = [&](size_t bytes)->void*{
    void* p = (void*)w;
    w += ((bytes + 255) & ~size_t(255));
    return p;
  };
  int*   bcnt = (int*)  carve((size_t)1024*4);
  int*   off  = (int*)  carve((size_t)3*(NN+1)*4);
  float* dnv  = (float*)carve((size_t)3*NN*4);
  unsigned short* csrc = (unsigned short*)carve((size_t)3*NE*2);
  float* sd1  = (float*)carve((size_t)3*NN*4);
  float* ss1  = (float*)carve((size_t)3*NN*4);
  float* sd2  = (float*)carve((size_t)3*NN*4);
  float* ss2  = (float*)carve((size_t)3*NN*4);
  unsigned short* wt1 = (unsigned short*)carve((size_t)HID*IND*2);
  unsigned short* w1t = (unsigned short*)carve((size_t)3*HID*HID*2);
  unsigned short* w2t = (unsigned short*)carve((size_t)3*HID*H3*2);
  unsigned short* wt2 = (unsigned short*)carve((size_t)64*FDIM*2);
  unsigned short* hb  = (unsigned short*)carve((size_t)NN*IND*2);
  unsigned short* raw1b = (unsigned short*)carve((size_t)NN*HID*2);
  unsigned short* raw2b = (unsigned short*)carve((size_t)NN*H3*2);
  // union region (38.4MB): pairbuf u32 [3*NBK*BCAP] (9.6MB) | pre1b [3][NN][HID] |
  //   { pre2b [3][NSEL][H3] (9.4MB) @0  +  sbuf f32 [NSEL][64] (1MB) @16MB }
  size_t ubytes = (size_t)3*NN*HID*2;
  float* ureg = (float*)carve(ubytes);
  unsigned int* pairbuf = (unsigned int*)ureg;
  unsigned short* pre1b = (unsigned short*)ureg;
  unsigned short* pre2b = (unsigned short*)ureg;
  float* sbuf = (float*)((char*)ureg + (size_t)16*1024*1024);
  unsigned short* nfb = (unsigned short*)carve((size_t)NSEL*FDIM*2);

  hipMemsetAsync(bcnt, 0, (size_t)1024*4, stream);
  k_bfill4<<<dim3((NE+EPB-1)/EPB, 3), 256, 0, stream>>>(
      src[0],dst[0],src[1],dst[1],src[2],dst[2], bcnt, pairbuf);
  k_bsort4<<<dim3(NBK,3), 256, 0, stream>>>(pairbuf, bcnt, off, dnv, csrc);

  k_wprep2<<<(666240+255)/256, 256, 0, stream>>>(
      t1w, hw1[0], hw1[1], hw1[2], hw2[0], hw2[1], hw2[2], t2w, h,
      wt1, w1t, w2t, wt2, hb);

  // raw1b = leaky(hb @ t1w^T + t1b)
  k_mfma_t1<<<(NN+63)/64, 256, 0, stream>>>(hb, wt1, t1b, raw1b);

  k_scores_g<HID><<<NN/16, 256, 0, stream>>>(raw1b, g1w[0], g1w[1], g1w[2], sd1, ss1);

  // layer-1 gather (group-per-node, 3 rels fused, pipelined) + hw1 MFMA
  k_gather_f3z<<<NN/16, 256, 0, stream>>>(raw1b, off, csrc,
      sd1, ss1, dnv, g1b[0], g1b[1], g1b[2], pre1b);
  k_mfma128<<<dim3((NN+63)/64, 3), 256, 0, stream>>>(pre1b, w1t, raw2b, NN);

  k_scores_g<H3><<<NN/16, 256, 0, stream>>>(raw2b, g2w[0], g2w[1], g2w[2], sd2, ss2);

  // layer-2 selected gather -> bf16 pre2
  k_gather_sel3w2<<<dim3(NSEL/16, 3), 256, 0, stream>>>(raw2b, nodes, off, csrc,
      sd2, ss2, dnv, g2b[0], g2b[1], g2b[2], pre2b);

  // hw2 MFMA -> nfb cols [0,384)
  k_mfma384<<<dim3(NSEL/32, 3), 256, 0, stream>>>(pre2b, w2t, nfb);

  k_nf_fillb<<<(NSEL*72+255)/256, 256, 0, stream>>>(hb, raw1b, raw2b, nodes, nfb);

  // t2 MFMA (K=960) -> sbuf, then fused bias+leaky+t3
  k_mfma_t2<<<NSEL/32, 256, 0, stream>>>(nfb, wt2, sbuf);
  k_final_wave<<<(NSEL*64+255)/256, 256, 0, stream>>>(sbuf, t2b, t3w, t3b, outp);
}

// Round 12
// 186.054 us; speedup vs baseline: 4.9235x; 1.0591x over previous
//
#include <hip/hip_runtime.h>
#include <hip/hip_bf16.h>

#define NN 50000
#define NE 400000
#define IND 64
#define HID 128
#define H3 384
#define FDIM 960
#define NSEL 4096
#define EPSF 0.3f
#define SLOPEF 0.3f
#define NBK 196            // ceil(NN/256) dst-buckets per relation
#define BCAP 4096          // fixed bucket capacity (mean 2048, sigma 45)
#define EPB 4096           // edges per block in fill
#define NOEDGE 0xFFFFFFFFu
#define NBF 98             // blocks per relation in fill = ceil(NE/EPB)

typedef __attribute__((ext_vector_type(8))) short bfrag;   // 8 bf16 (4 VGPR)
typedef __attribute__((ext_vector_type(4))) float f4;
typedef __attribute__((ext_vector_type(8))) unsigned short us8;

__device__ __forceinline__ float leaky1(float v){ return v>=0.f? v : SLOPEF*v; }
__device__ __forceinline__ float b2f(unsigned short u){
  return __uint_as_float(((unsigned)u)<<16);
}
__device__ __forceinline__ unsigned short f2b(float v){
  __hip_bfloat16 b = __float2bfloat16(v);
  return *(unsigned short*)&b;
}

// ================= kA: bucketed fill (blocks 0..293)  UNION  weight-prep/h-cast =================
__global__ __launch_bounds__(256) void k_fill_prep(
    const int* __restrict__ s0,const int* __restrict__ d0,
    const int* __restrict__ s1,const int* __restrict__ d1,
    const int* __restrict__ s2,const int* __restrict__ d2,
    int* __restrict__ bcnt, unsigned int* __restrict__ pairbuf,
    const float* __restrict__ t1w,
    const float* __restrict__ hw1_0, const float* __restrict__ hw1_1, const float* __restrict__ hw1_2,
    const float* __restrict__ hw2_0, const float* __restrict__ hw2_1, const float* __restrict__ hw2_2,
    const float* __restrict__ t2w, const float* __restrict__ h,
    unsigned short* __restrict__ wt1, unsigned short* __restrict__ w1t,
    unsigned short* __restrict__ w2t, unsigned short* __restrict__ wt2,
    unsigned short* __restrict__ hb)
{
  __shared__ __align__(16) unsigned int lbuf[EPB];   // 16 KB
  __shared__ int hist[256];
  __shared__ int lbase[256];
  __shared__ int lcur[256];
  __shared__ int gbase[NBK];
  __shared__ int wsum[4];
  const int t = threadIdx.x;

  if (blockIdx.x < 3*NBF){
    // ---- bucketed fill ----
    const int r = blockIdx.x / NBF;
    const int bx = blockIdx.x - r*NBF;
    const int* S = (r==0)?s0:((r==1)?s1:s2);
    const int* D = (r==0)?d0:((r==1)?d1:d2);
    const int e0 = bx*EPB;
    hist[t] = 0; lcur[t] = 0;
    __syncthreads();
    unsigned int pv[16];
    #pragma unroll
    for (int j=0;j<4;j++){
      int e = e0 + (j*256 + t)*4;
      if (e < NE){
        int4 sv = *(const int4*)&S[e];
        int4 dv = *(const int4*)&D[e];
        pv[j*4+0] = ((unsigned)dv.x<<16)|(unsigned)sv.x;
        pv[j*4+1] = ((unsigned)dv.y<<16)|(unsigned)sv.y;
        pv[j*4+2] = ((unsigned)dv.z<<16)|(unsigned)sv.z;
        pv[j*4+3] = ((unsigned)dv.w<<16)|(unsigned)sv.w;
      } else {
        pv[j*4+0]=NOEDGE; pv[j*4+1]=NOEDGE; pv[j*4+2]=NOEDGE; pv[j*4+3]=NOEDGE;
      }
    }
    #pragma unroll
    for (int i=0;i<16;i++){
      if (pv[i] != NOEDGE) atomicAdd(&hist[pv[i]>>24], 1);
    }
    __syncthreads();
    {
      int hv = hist[t];
      int lane = t & 63, wid = t >> 6;
      int x = hv;
      #pragma unroll
      for (int d=1; d<64; d<<=1){ int y=__shfl_up(x,(unsigned)d); if(lane>=d) x+=y; }
      if (lane==63) wsum[wid]=x;
      __syncthreads();
      int wpre = 0;
      if (wid>0) wpre += wsum[0];
      if (wid>1) wpre += wsum[1];
      if (wid>2) wpre += wsum[2];
      lbase[t] = wpre + x - hv;
      if (t < NBK){
        int hh = hist[t];
        gbase[t] = (hh>0) ? atomicAdd(&bcnt[r*NBK+t], hh) : 0;
      }
    }
    __syncthreads();
    #pragma unroll
    for (int i=0;i<16;i++){
      if (pv[i] != NOEDGE){
        int b = (int)(pv[i] >> 24);
        int pos = lbase[b] + atomicAdd(&lcur[b], 1);
        lbuf[pos] = pv[i];
      }
    }
    __syncthreads();
    int tot = min(NE - e0, EPB);
    for (int idx = t; idx < tot; idx += 256){
      unsigned int v = lbuf[idx];
      int b = (int)(v >> 24);
      pairbuf[((size_t)(r*NBK + b))*BCAP + gbase[b] + (idx - lbase[b])] = v;
    }
  } else {
    // ---- weight prep + h cast ----
    int g = (blockIdx.x - 3*NBF)*256 + t;
    if (g < 8192){
      wt1[g] = f2b(t1w[g]);
    } else if (g < 57344){
      int e = g - 8192;
      int r = e / 16384, q = e - r*16384;
      int n = q >> 7, k = q & 127;
      const float* W = (r==0)?hw1_0:((r==1)?hw1_1:hw1_2);
      w1t[e] = f2b(W[k*HID + n]);
    } else if (g < 204800){
      int e = g - 57344;
      int r = e / 49152, q = e - r*49152;
      int n = q / H3, k = q - n*H3;
      const float* W = (r==0)?hw2_0:((r==1)?hw2_1:hw2_2);
      w2t[e] = f2b(W[k*HID + n]);
    } else if (g < 266240){
      int e = g - 204800;
      wt2[e] = f2b(t2w[e]);
    } else if (g < 666240){
      int q = g - 266240;
      const float4 a = ((const float4*)h)[q*2];
      const float4 b = ((const float4*)h)[q*2+1];
      us8 o;
      o[0]=f2b(a.x); o[1]=f2b(a.y); o[2]=f2b(a.z); o[3]=f2b(a.w);
      o[4]=f2b(b.x); o[5]=f2b(b.y); o[6]=f2b(b.z); o[7]=f2b(b.w);
      *(us8*)&hb[q*8] = o;
    }
  }
}

// ================= kB: bsort+off+dnv (0..587)  UNION  t1 MFMA (588..1369) =================
__global__ __launch_bounds__(256) void k_sort_t1(
    const unsigned int* __restrict__ pairbuf, const int* __restrict__ bcnt,
    int* __restrict__ off, float* __restrict__ dnv, unsigned short* __restrict__ csrc,
    const unsigned short* __restrict__ Ab, const unsigned short* __restrict__ W,
    const float* __restrict__ bias, unsigned short* __restrict__ Cb)
{
  __shared__ __align__(16) char smem[27648];
  const int t = threadIdx.x;

  if (blockIdx.x < 2*NBK + NBK){   // 3*NBK = 588
    // ---- bucket sort + off/dnv ----
    unsigned short* lout = (unsigned short*)smem;            // 8192 B
    int* hist = (int*)(smem + 8192);                         // 1024
    int* excl = (int*)(smem + 9216);
    int* cur  = (int*)(smem + 10240);
    int* red  = (int*)(smem + 11264);
    int* wsum = (int*)(smem + 12288);
    const int r = blockIdx.x / NBK;
    const int b = blockIdx.x - r*NBK;
    const int nb0 = b << 8;
    red[t] = (t < b) ? bcnt[r*NBK + t] : 0;
    hist[t] = 0; cur[t] = 0;
    __syncthreads();
    #pragma unroll
    for (int sdv=128; sdv>0; sdv>>=1){
      if (t < sdv) red[t] += red[t+sdv];
      __syncthreads();
    }
    const int bbase = red[0];
    const int cnt = bcnt[r*NBK + b];
    const unsigned int* pb = pairbuf + ((size_t)(r*NBK + b))*BCAP;
    unsigned int pv[16];
    #pragma unroll
    for (int j=0;j<16;j++){
      int e = j*256 + t;
      pv[j] = (e < cnt) ? pb[e] : NOEDGE;
      if (pv[j] != NOEDGE) atomicAdd(&hist[(int)(pv[j]>>16) - nb0], 1);
    }
    __syncthreads();
    {
      int hv = hist[t];
      int lane = t & 63, wid = t >> 6;
      int x = hv;
      #pragma unroll
      for (int d=1; d<64; d<<=1){ int y=__shfl_up(x,(unsigned)d); if(lane>=d) x+=y; }
      if (lane==63) wsum[wid]=x;
      __syncthreads();
      int wpre = 0;
      if (wid>0) wpre += wsum[0];
      if (wid>1) wpre += wsum[1];
      if (wid>2) wpre += wsum[2];
      excl[t] = wpre + x - hv;
    }
    __syncthreads();
    int nidx = nb0 + t;
    if (nidx < NN){
      off[r*(NN+1) + nidx] = bbase + excl[t];
      int g = hist[t];
      dnv[r*NN + nidx] = (g>0) ? rsqrtf((float)g) : 0.f;
    }
    if (b == NBK-1 && t == 0) off[r*(NN+1) + NN] = bbase + cnt;
    #pragma unroll
    for (int j=0;j<16;j++){
      if (pv[j] != NOEDGE){
        int pn = (int)(pv[j] >> 16) - nb0;
        int slot = atomicAdd(&cur[pn], 1);
        lout[excl[pn] + slot] = (unsigned short)(pv[j] & 0xffffu);
      }
    }
    __syncthreads();
    unsigned short* op = csrc + (size_t)r*NE + bbase;
    for (int idx = t; idx < cnt; idx += 256) op[idx] = lout[idx];
  } else {
    // ---- t1 MFMA ----
    short (*As)[72] = (short(*)[72])smem;                    // 9216 B
    short (*Bs)[72] = (short(*)[72])(smem + 9216);           // 18432 B
    const int bm = (blockIdx.x - 3*NBK)*64;
    for (int q = t; q < 64*8; q += 256){
      int row = q >> 3, c8 = q & 7;
      int grow = bm + row; grow = (grow < NN) ? grow : (NN-1);
      *(us8*)&As[row][c8*8] = *(const us8*)&Ab[(size_t)grow*IND + c8*8];
    }
    for (int q = t; q < 128*8; q += 256){
      int n = q >> 3, c8 = q & 7;
      *(us8*)&Bs[n][c8*8] = *(const us8*)&W[n*IND + c8*8];
    }
    __syncthreads();
    const int wid = t >> 6, lane = t & 63;
    const int wrow = (wid & 1)*32, wcol = (wid >> 1)*64;
    const int fr = lane & 15, fq = lane >> 4;
    f4 acc[2][4];
    #pragma unroll
    for (int mi=0;mi<2;mi++)
      #pragma unroll
      for (int ni=0;ni<4;ni++) acc[mi][ni] = (f4){0.f,0.f,0.f,0.f};
    #pragma unroll
    for (int ks=0; ks<2; ks++){
      int kb = ks*32 + fq*8;
      bfrag a[2], b[4];
      #pragma unroll
      for (int mi=0;mi<2;mi++) a[mi] = *(const bfrag*)&As[wrow + mi*16 + fr][kb];
      #pragma unroll
      for (int ni=0;ni<4;ni++) b[ni] = *(const bfrag*)&Bs[wcol + ni*16 + fr][kb];
      #pragma unroll
      for (int mi=0;mi<2;mi++)
        #pragma unroll
        for (int ni=0;ni<4;ni++)
          acc[mi][ni] = __builtin_amdgcn_mfma_f32_16x16x32_bf16(a[mi], b[ni], acc[mi][ni], 0, 0, 0);
    }
    #pragma unroll
    for (int mi=0;mi<2;mi++){
      int row0 = bm + wrow + mi*16 + fq*4;
      #pragma unroll
      for (int j=0;j<4;j++){
        int row = row0 + j;
        if (row < NN){
          #pragma unroll
          for (int ni=0;ni<4;ni++){
            int col = wcol + ni*16 + fr;
            Cb[(size_t)row*HID + col] = f2b(leaky1(acc[mi][ni][j] + bias[col]));
          }
        }
      }
    }
  }
}

// ---------- batched bf16 MFMA: raw2b[:, r*128..] = leaky(pre1b[r] @ hw1[r]) ----------
__global__ __launch_bounds__(256) void k_mfma128(
    const unsigned short* __restrict__ Abf, const unsigned short* __restrict__ Wt,
    unsigned short* __restrict__ Cb, int M)
{
  __shared__ short As[64][136];
  __shared__ short Bs[128][136];
  const int r = blockIdx.y;
  const unsigned short* Ar = Abf + (size_t)r*M*HID;
  const unsigned short* W  = Wt + (size_t)r*HID*HID;
  const int tid = threadIdx.x;
  const int bm = blockIdx.x*64;

  for (int q = tid; q < 64*16; q += 256){
    int row = q >> 4, c8 = q & 15;
    int grow = bm + row; grow = (grow < M) ? grow : (M-1);
    *(us8*)&As[row][c8*8] = *(const us8*)&Ar[(size_t)grow*HID + c8*8];
  }
  for (int q = tid; q < 128*16; q += 256){
    int n = q >> 4, c8 = q & 15;
    *(us8*)&Bs[n][c8*8] = *(const us8*)&W[n*HID + c8*8];
  }
  __syncthreads();

  const int wid = tid >> 6, lane = tid & 63;
  const int wrow = (wid & 1)*32, wcol = (wid >> 1)*64;
  const int fr = lane & 15, fq = lane >> 4;
  f4 acc[2][4];
  #pragma unroll
  for (int mi=0;mi<2;mi++)
    #pragma unroll
    for (int ni=0;ni<4;ni++) acc[mi][ni] = (f4){0.f,0.f,0.f,0.f};

  #pragma unroll
  for (int ks=0; ks<4; ks++){
    int kb = ks*32 + fq*8;
    bfrag a[2], b[4];
    #pragma unroll
    for (int mi=0;mi<2;mi++) a[mi] = *(const bfrag*)&As[wrow + mi*16 + fr][kb];
    #pragma unroll
    for (int ni=0;ni<4;ni++) b[ni] = *(const bfrag*)&Bs[wcol + ni*16 + fr][kb];
    #pragma unroll
    for (int mi=0;mi<2;mi++)
      #pragma unroll
      for (int ni=0;ni<4;ni++)
        acc[mi][ni] = __builtin_amdgcn_mfma_f32_16x16x32_bf16(a[mi], b[ni], acc[mi][ni], 0, 0, 0);
  }

  const int coff = r*HID;
  #pragma unroll
  for (int mi=0;mi<2;mi++){
    int row0 = bm + wrow + mi*16 + fq*4;
    #pragma unroll
    for (int j=0;j<4;j++){
      int row = row0 + j;
      if (row < M){
        #pragma unroll
        for (int ni=0;ni<4;ni++){
          Cb[(size_t)row*H3 + coff + wcol + ni*16 + fr] = f2b(leaky1(acc[mi][ni][j]));
        }
      }
    }
  }
}

// ================= kH: hw2 MFMA (0..383)  UNION  nf fill (384..1535) =================
__global__ __launch_bounds__(256) void k_hw2_nf(
    const unsigned short* __restrict__ Abf, const unsigned short* __restrict__ Wt,
    const unsigned short* __restrict__ hb, const unsigned short* __restrict__ raw1b,
    const unsigned short* __restrict__ raw2b, const int* __restrict__ nodes,
    unsigned short* __restrict__ nfb)
{
  __shared__ __align__(16) char smem[23040];
  const int t = threadIdx.x;
  if (blockIdx.x < 3*128){
    short (*As)[72] = (short(*)[72])smem;                  // 4608 B
    short (*Bs)[72] = (short(*)[72])(smem + 4608);         // 18432 B
    const int r = blockIdx.x / 128;
    const int bm = (blockIdx.x - r*128)*32;
    const unsigned short* Ar = Abf + (size_t)r*NSEL*H3;
    const unsigned short* W  = Wt + (size_t)r*HID*H3;
    const int wid = t >> 6, lane = t & 63;
    const int fr = lane & 15, fq = lane >> 4;
    f4 acc[2][2];
    #pragma unroll
    for (int mi=0;mi<2;mi++)
      #pragma unroll
      for (int ni=0;ni<2;ni++) acc[mi][ni] = (f4){0.f,0.f,0.f,0.f};
    for (int kc=0; kc<6; kc++){
      for (int q = t; q < 32*8; q += 256){
        int row = q >> 3, c8 = q & 7;
        *(us8*)&As[row][c8*8] = *(const us8*)&Ar[(size_t)(bm+row)*H3 + kc*64 + c8*8];
      }
      for (int q = t; q < 128*8; q += 256){
        int n = q >> 3, c8 = q & 7;
        *(us8*)&Bs[n][c8*8] = *(const us8*)&W[(size_t)n*H3 + kc*64 + c8*8];
      }
      __syncthreads();
      #pragma unroll
      for (int ks=0; ks<2; ks++){
        int kb = ks*32 + fq*8;
        bfrag a[2], b[2];
        #pragma unroll
        for (int mi=0;mi<2;mi++) a[mi] = *(const bfrag*)&As[mi*16 + fr][kb];
        #pragma unroll
        for (int ni=0;ni<2;ni++) b[ni] = *(const bfrag*)&Bs[wid*32 + ni*16 + fr][kb];
        #pragma unroll
        for (int mi=0;mi<2;mi++)
          #pragma unroll
          for (int ni=0;ni<2;ni++)
            acc[mi][ni] = __builtin_amdgcn_mfma_f32_16x16x32_bf16(a[mi], b[ni], acc[mi][ni], 0, 0, 0);
      }
      __syncthreads();
    }
    #pragma unroll
    for (int mi=0;mi<2;mi++){
      int row0 = bm + mi*16 + fq*4;
      #pragma unroll
      for (int j=0;j<4;j++){
        int i = row0 + j;
        #pragma unroll
        for (int ni=0;ni<2;ni++){
          int col = wid*32 + ni*16 + fr;
          nfb[(size_t)i*FDIM + r*HID + col] = f2b(leaky1(acc[mi][ni][j]));
        }
      }
    }
  } else {
    int g = (blockIdx.x - 3*128)*256 + t;
    if (g < NSEL*72){
      int i = g/72, c = g - i*72;
      int n = nodes[i];
      us8 v; int col;
      if (c < 8)       { v = *(const us8*)&hb[(size_t)n*IND + c*8];           col = 384 + c*8; }
      else if (c < 24) { int q=c-8;  v = *(const us8*)&raw1b[(size_t)n*HID + q*8]; col = 448 + q*8; }
      else             { int q=c-24; v = *(const us8*)&raw2b[(size_t)n*H3  + q*8]; col = 576 + q*8; }
      *(us8*)&nfb[(size_t)i*FDIM + col] = v;
    }
  }
}

// ================= kT2F: t2 MFMA (K=960) + fused bias/leaky/t3 epilogue =================
__global__ __launch_bounds__(256) void k_t2_final(
    const unsigned short* __restrict__ Abf, const unsigned short* __restrict__ W,
    const float* __restrict__ t2b, const float* __restrict__ t3w,
    const float* __restrict__ t3b, float* __restrict__ outp)
{
  __shared__ __align__(16) char smem[13824];
  short (*As)[72] = (short(*)[72])smem;                  // 4608
  short (*Bs)[72] = (short(*)[72])(smem + 4608);         // 9216
  float (*sb)[64] = (float(*)[64])smem;                  // 8192, aliases As/Bs after last use
  const int t = threadIdx.x;
  const int bm = blockIdx.x*32;
  const int wid = t >> 6, lane = t & 63;
  const int fr = lane & 15, fq = lane >> 4;
  f4 acc[2];
  acc[0] = (f4){0.f,0.f,0.f,0.f};
  acc[1] = (f4){0.f,0.f,0.f,0.f};

  for (int kc=0; kc<15; kc++){
    for (int q = t; q < 32*8; q += 256){
      int row = q >> 3, c8 = q & 7;
      *(us8*)&As[row][c8*8] = *(const us8*)&Abf[(size_t)(bm+row)*FDIM + kc*64 + c8*8];
    }
    for (int q = t; q < 64*8; q += 256){
      int n = q >> 3, c8 = q & 7;
      *(us8*)&Bs[n][c8*8] = *(const us8*)&W[(size_t)n*FDIM + kc*64 + c8*8];
    }
    __syncthreads();
    #pragma unroll
    for (int ks=0; ks<2; ks++){
      int kb = ks*32 + fq*8;
      bfrag a[2], b;
      a[0] = *(const bfrag*)&As[fr][kb];
      a[1] = *(const bfrag*)&As[16 + fr][kb];
      b = *(const bfrag*)&Bs[wid*16 + fr][kb];
      acc[0] = __builtin_amdgcn_mfma_f32_16x16x32_bf16(a[0], b, acc[0], 0, 0, 0);
      acc[1] = __builtin_amdgcn_mfma_f32_16x16x32_bf16(a[1], b, acc[1], 0, 0, 0);
    }
    __syncthreads();
  }

  // write s rows to LDS (alias of As/Bs — all reads complete)
  #pragma unroll
  for (int mi=0;mi<2;mi++){
    int rloc = mi*16 + fq*4;
    #pragma unroll
    for (int j=0;j<4;j++){
      sb[rloc+j][wid*16 + fr] = acc[mi][j];
    }
  }
  __syncthreads();
  // fused bias + leaky + t3: each wave handles 8 rows
  for (int rr = wid*8; rr < wid*8+8; rr++){
    float v = leaky1(sb[rr][lane] + t2b[lane]);
    float a0 = v*t3w[lane], a1 = v*t3w[64+lane];
    #pragma unroll
    for (int sft=32;sft>0;sft>>=1){
      a0 += __shfl_down(a0,(unsigned)sft);
      a1 += __shfl_down(a1,(unsigned)sft);
    }
    if (lane==0){
      int w = bm + rr;
      outp[2*w+0] = a0 + t3b[0];
      outp[2*w+1] = a1 + t3b[1];
    }
  }
}

// ---------- per-node gate scores: group(16)-per-node, us8 loads ----------
template<int D>
__global__ __launch_bounds__(256) void k_scores_g(const unsigned short* __restrict__ X,
    const float* __restrict__ g0, const float* __restrict__ g1, const float* __restrict__ g2,
    float* __restrict__ sd, float* __restrict__ ss){
  const int tid = threadIdx.x;
  const int p = tid & 15;
  const int n = blockIdx.x*16 + (tid >> 4);
  const unsigned short* x = X + (size_t)n*D;
  float a0=0,a1=0,a2=0,a3=0,a4=0,a5=0;
  #pragma unroll
  for (int it=0; it<D/128; it++){
    int k = it*128 + p*8;
    us8 u = *(const us8*)&x[k];
    #pragma unroll
    for (int e=0;e<8;e++){
      float v = b2f(u[e]);
      a0 = fmaf(v, g0[k+e],   a0);  a1 = fmaf(v, g0[D+k+e], a1);
      a2 = fmaf(v, g1[k+e],   a2);  a3 = fmaf(v, g1[D+k+e], a3);
      a4 = fmaf(v, g2[k+e],   a4);  a5 = fmaf(v, g2[D+k+e], a5);
    }
  }
  #pragma unroll
  for (int s=8;s>0;s>>=1){
    a0 += __shfl_xor(a0,(unsigned)s); a1 += __shfl_xor(a1,(unsigned)s);
    a2 += __shfl_xor(a2,(unsigned)s); a3 += __shfl_xor(a3,(unsigned)s);
    a4 += __shfl_xor(a4,(unsigned)s); a5 += __shfl_xor(a5,(unsigned)s);
  }
  if (p==0){
    sd[0*NN+n]=a0; ss[0*NN+n]=a1;
    sd[1*NN+n]=a2; ss[1*NN+n]=a3;
    sd[2*NN+n]=a4; ss[2*NN+n]=a5;
  }
}

// ---------- layer-1 aggregation: group(16)-per-node, 3 rels fused, 1-ahead pipeline ----------
__global__ __launch_bounds__(256) void k_gather_f3z(
    const unsigned short* __restrict__ Xb,
    const int* __restrict__ off, const unsigned short* __restrict__ csrc,
    const float* __restrict__ sd, const float* __restrict__ ss,
    const float* __restrict__ dnv,
    const float* __restrict__ gb0, const float* __restrict__ gb1, const float* __restrict__ gb2,
    unsigned short* __restrict__ outp){
  const int tid = threadIdx.x;
  const int lane = tid & 63;
  const int wg = lane >> 4;
  const int p  = lane & 15;
  const int n = blockIdx.x*16 + (tid >> 4);
  us8 rv = *(const us8*)&Xb[(size_t)n*HID + p*8];
  int p0a[3], p1a[3];
  #pragma unroll
  for (int r=0;r<3;r++){
    p0a[r] = off[r*(NN+1) + n];
    p1a[r] = off[r*(NN+1) + n + 1];
  }
  float resid[8];
  #pragma unroll
  for (int i=0;i<8;i++) resid[i] = EPSF * b2f(rv[i]);

  for (int r=0;r<3;r++){
    const unsigned short* csr = csrc + (size_t)r*NE;
    const float* ssr = ss + r*NN;
    const float* dnr = dnv + r*NN;
    float gbv = ((r==0)?gb0:((r==1)?gb1:gb2))[0];
    float sd_n = sd[r*NN + n], dn_n = dnr[n];
    float acc[8];
    #pragma unroll
    for (int i=0;i<8;i++) acc[i] = resid[i];
    int p0 = p0a[r], p1 = p1a[r];
    for (int pc=p0; pc<p1; pc+=16){
      int m = min(16, p1-pc);
      int s = 0; float c = 0.f;
      if (p < m){
        s = csr[pc+p];
        c = tanhf(sd_n + ssr[s] + gbv) * dn_n * dnr[s];
      }
      int   sj = __shfl(s, wg*16);
      float cj = __shfl(c, wg*16);
      us8 v = *(const us8*)&Xb[(size_t)sj*HID + p*8];
      for (int j=1;j<=m;j++){
        us8 vn; float cn = 0.f;
        if (j < m){
          int sn = __shfl(s, wg*16+j);
          cn = __shfl(c, wg*16+j);
          vn = *(const us8*)&Xb[(size_t)sn*HID + p*8];
        }
        #pragma unroll
        for (int i=0;i<8;i++) acc[i] = fmaf(cj, b2f(v[i]), acc[i]);
        v = vn; cj = cn;
      }
    }
    us8 o;
    #pragma unroll
    for (int i=0;i<8;i++) o[i] = f2b(acc[i]);
    *(us8*)&outp[((size_t)r*NN + n)*HID + p*8] = o;
  }
}

// ---------- layer-2 selected aggregation: group-per-node, D=384, 1-ahead pipeline ----------
__global__ __launch_bounds__(256) void k_gather_sel3w2(const unsigned short* __restrict__ Xb,
    const int* __restrict__ nodes,
    const int* __restrict__ off, const unsigned short* __restrict__ csrc,
    const float* __restrict__ sd, const float* __restrict__ ss,
    const float* __restrict__ dnv,
    const float* __restrict__ gb0, const float* __restrict__ gb1, const float* __restrict__ gb2,
    unsigned short* __restrict__ outp){
  const int tid = threadIdx.x;
  const int lane = tid & 63;
  const int wg = lane >> 4;
  const int p  = lane & 15;
  const int i = blockIdx.x*16 + (tid >> 4);
  const int r = blockIdx.y;
  const int n = nodes[i];
  const int* offr = off + r*(NN+1);
  const unsigned short* csr = csrc + (size_t)r*NE;
  const float* ssr = ss + r*NN;
  const float* dnr = dnv + r*NN;
  float gbv = ((r==0)?gb0:((r==1)?gb1:gb2))[0];
  float sd_n = sd[r*NN + n], dn_n = dnr[n];
  float acc[3][8];
  #pragma unroll
  for (int cc=0;cc<3;cc++)
    #pragma unroll
    for (int q=0;q<8;q++) acc[cc][q]=0.f;
  int p0 = offr[n], p1 = offr[n+1];
  for (int pc=p0; pc<p1; pc+=16){
    int m = min(16, p1-pc);
    int s = 0; float c = 0.f;
    if (p < m){
      s = csr[pc+p];
      c = tanhf(sd_n + ssr[s] + gbv) * dn_n * dnr[s];
    }
    int   sj = __shfl(s, wg*16);
    float cj = __shfl(c, wg*16);
    const unsigned short* row = &Xb[(size_t)sj*H3];
    us8 v0 = *(const us8*)&row[0*HID + p*8];
    us8 v1 = *(const us8*)&row[1*HID + p*8];
    us8 v2 = *(const us8*)&row[2*HID + p*8];
    for (int j=1;j<=m;j++){
      us8 n0, n1, n2; float cn = 0.f;
      if (j < m){
        int sn = __shfl(s, wg*16+j);
        cn = __shfl(c, wg*16+j);
        const unsigned short* rw = &Xb[(size_t)sn*H3];
        n0 = *(const us8*)&rw[0*HID + p*8];
        n1 = *(const us8*)&rw[1*HID + p*8];
        n2 = *(const us8*)&rw[2*HID + p*8];
      }
      #pragma unroll
      for (int q=0;q<8;q++){
        acc[0][q] = fmaf(cj, b2f(v0[q]), acc[0][q]);
        acc[1][q] = fmaf(cj, b2f(v1[q]), acc[1][q]);
        acc[2][q] = fmaf(cj, b2f(v2[q]), acc[2][q]);
      }
      v0 = n0; v1 = n1; v2 = n2; cj = cn;
    }
  }
  const unsigned short* xrow = &Xb[(size_t)n*H3];
  unsigned short* orow = &outp[((size_t)r*NSEL + i)*H3];
  #pragma unroll
  for (int cc=0;cc<3;cc++){
    us8 v = *(const us8*)&xrow[cc*HID + p*8];
    us8 o;
    #pragma unroll
    for (int q=0;q<8;q++) o[q] = f2b(fmaf(EPSF, b2f(v[q]), acc[cc][q]));
    *(us8*)&orow[cc*HID + p*8] = o;
  }
}

extern "C" void kernel_launch(void* const* d_in, const int* in_sizes, int n_in,
                              void* d_out, int out_size, void* d_ws, size_t ws_size,
                              hipStream_t stream){
  if (n_in < 32) return;
  const float* h = (const float*)d_in[0];
  const int* src[3] = {(const int*)d_in[1], (const int*)d_in[3], (const int*)d_in[5]};
  const int* dst[3] = {(const int*)d_in[2], (const int*)d_in[4], (const int*)d_in[6]};
  const int* nodes = (const int*)d_in[7];
  const float* t1w = (const float*)d_in[8];
  const float* t1b = (const float*)d_in[9];

  bool dictOrder = (in_sizes[12] == 768);
  const float *g1w[3],*g1b[3],*g2w[3],*g2b[3],*hw1[3],*hw2[3];
  for (int r=0;r<3;r++){
    if (dictOrder){
      int base = 10 + r*6;
      g1w[r]=(const float*)d_in[base+0]; g1b[r]=(const float*)d_in[base+1];
      g2w[r]=(const float*)d_in[base+2]; g2b[r]=(const float*)d_in[base+3];
      hw1[r]=(const float*)d_in[base+4]; hw2[r]=(const float*)d_in[base+5];
    } else {
      g1w[r]=(const float*)d_in[10+2*r]; g1b[r]=(const float*)d_in[11+2*r];
      g2w[r]=(const float*)d_in[16+2*r]; g2b[r]=(const float*)d_in[17+2*r];
      hw1[r]=(const float*)d_in[22+r];   hw2[r]=(const float*)d_in[25+r];
    }
  }
  const float* t2w = (const float*)d_in[28];
  const float* t2b = (const float*)d_in[29];
  const float* t3w = (const float*)d_in[30];
  const float* t3b = (const float*)d_in[31];
  float* outp = (float*)d_out;

  // workspace carve (~115 MB)
  char* w = (char*)d_ws;
  auto carve = [&](size_t bytes)->void*{
    void* p = (void*)w;
    w += ((bytes + 255) & ~size_t(255));
    return p;
  };
  int*   bcnt = (int*)  carve((size_t)1024*4);
  int*   off  = (int*)  carve((size_t)3*(NN+1)*4);
  float* dnv  = (float*)carve((size_t)3*NN*4);
  unsigned short* csrc = (unsigned short*)carve((size_t)3*NE*2);
  float* sd1  = (float*)carve((size_t)3*NN*4);
  float* ss1  = (float*)carve((size_t)3*NN*4);
  float* sd2  = (float*)carve((size_t)3*NN*4);
  float* ss2  = (float*)carve((size_t)3*NN*4);
  unsigned short* wt1 = (unsigned short*)carve((size_t)HID*IND*2);
  unsigned short* w1t = (unsigned short*)carve((size_t)3*HID*HID*2);
  unsigned short* w2t = (unsigned short*)carve((size_t)3*HID*H3*2);
  unsigned short* wt2 = (unsigned short*)carve((size_t)64*FDIM*2);
  unsigned short* hb  = (unsigned short*)carve((size_t)NN*IND*2);
  unsigned short* raw1b = (unsigned short*)carve((size_t)NN*HID*2);
  unsigned short* raw2b = (unsigned short*)carve((size_t)NN*H3*2);
  // union region (38.4MB): pairbuf u32 [3*NBK*BCAP] (9.6MB) | pre1b [3][NN][HID] | pre2b [3][NSEL][H3]
  size_t ubytes = (size_t)3*NN*HID*2;
  float* ureg = (float*)carve(ubytes);
  unsigned int* pairbuf = (unsigned int*)ureg;
  unsigned short* pre1b = (unsigned short*)ureg;
  unsigned short* pre2b = (unsigned short*)ureg;
  unsigned short* nfb = (unsigned short*)carve((size_t)NSEL*FDIM*2);

  hipMemsetAsync(bcnt, 0, (size_t)1024*4, stream);
  // kA: fill + weight-prep (independent, one dispatch)
  k_fill_prep<<<3*NBF + 2603, 256, 0, stream>>>(
      src[0],dst[0],src[1],dst[1],src[2],dst[2], bcnt, pairbuf,
      t1w, hw1[0], hw1[1], hw1[2], hw2[0], hw2[1], hw2[2], t2w, h,
      wt1, w1t, w2t, wt2, hb);
  // kB: bucket-sort/off/dnv + t1 MFMA (both depend only on kA)
  k_sort_t1<<<3*NBK + (NN+63)/64, 256, 0, stream>>>(
      pairbuf, bcnt, off, dnv, csrc, hb, wt1, t1b, raw1b);

  k_scores_g<HID><<<NN/16, 256, 0, stream>>>(raw1b, g1w[0], g1w[1], g1w[2], sd1, ss1);

  k_gather_f3z<<<NN/16, 256, 0, stream>>>(raw1b, off, csrc,
      sd1, ss1, dnv, g1b[0], g1b[1], g1b[2], pre1b);
  k_mfma128<<<dim3((NN+63)/64, 3), 256, 0, stream>>>(pre1b, w1t, raw2b, NN);

  k_scores_g<H3><<<NN/16, 256, 0, stream>>>(raw2b, g2w[0], g2w[1], g2w[2], sd2, ss2);

  k_gather_sel3w2<<<dim3(NSEL/16, 3), 256, 0, stream>>>(raw2b, nodes, off, csrc,
      sd2, ss2, dnv, g2b[0], g2b[1], g2b[2], pre2b);

  // kH: hw2 MFMA + nf fill (one dispatch)
  k_hw2_nf<<<3*128 + (NSEL*72+255)/256, 256, 0, stream>>>(
      pre2b, w2t, hb, raw1b, raw2b, nodes, nfb);

  // kT2F: t2 MFMA with fused bias/leaky/t3 epilogue
  k_t2_final<<<NSEL/32, 256, 0, stream>>>(nfb, wt2, t2b, t3w, t3b, outp);
}